// Round 4
// baseline (837.689 us; speedup 1.0000x reference)
//
#include <hip/hip_runtime.h>

typedef unsigned short u16;
typedef unsigned int   u32;
typedef unsigned long long u64;
typedef __attribute__((ext_vector_type(4))) float f4;

#define DEV __device__ __forceinline__

// ---------------- workspace layout (bytes) ----------------
#define OFF_STATS 0L
#define OFF_WEAB  16384L
#define OFF_IDX   1048576L
#define OFF_Y1    4194304L      /* 16.78 MB ; later H3 */
#define OFF_H1    20971520L     /* 16.78 MB ; later Y4 */
#define OFF_Y2    37748736L     /* 33.55 MB ; later H2 + Y3 */
#define OFF_EMAX  4194304L      /* over dead Y1 */
#define OFF_EMIN  20971520L     /* over dead H1 */
#define OFF_H2    37748736L     /* over dead Y2 head */
#define OFF_Y3    54525952L     /* over dead Y2 tail */
#define OFF_H3    4194304L      /* over dead EMAX */
#define OFF_Y4    20971520L     /* over dead EMIN */
#define OFF_H4    29360128L     /* after Y4 */
#define WS_NEED   71303168L

// ---------------- weAB build: [0:256)=weA, [256:512)=weB-weA ----------------
__global__ __launch_bounds__(256) void k_wedge(const float* __restrict__ we, float* __restrict__ weAB)
{
  int i = blockIdx.x * 256 + threadIdx.x;
  if (i >= 131072) return;
  int o = i >> 8, c = i & 255;
  float v = (o < 256) ? we[o * 512 + c]
                      : we[(o - 256) * 512 + 256 + c] - we[(o - 256) * 512 + c];
  weAB[i] = v;
}

// ---------------- exact KNN top-20 (f64 re-rank matches f64 gold) ----------------
__global__ __launch_bounds__(512, 1) void k_knn(const float* __restrict__ p, int* __restrict__ idxOut)
{
  __shared__ f4 pq[8192];        // 128 KB: (x,y,z,sq_f32)
  __shared__ int cii[8][256];    // 8 KB
  const int tid = threadIdx.x, lane = tid & 63, w = tid >> 6;
  const int blk = blockIdx.x;
  const int b = blk >> 10;
  const float* px = p + (long)b * 24576;
  const float* py = px + 8192;
  const float* pz = px + 16384;
  for (int t4 = tid; t4 < 2048; t4 += 512) {
    f4 x4 = *(const f4*)(px + t4 * 4);
    f4 y4 = *(const f4*)(py + t4 * 4);
    f4 z4 = *(const f4*)(pz + t4 * 4);
#pragma unroll
    for (int j = 0; j < 4; ++j) {
      float X = x4[j], Yv = y4[j], Z = z4[j];
      float s = fmaf(X, X, fmaf(Yv, Yv, Z * Z));
      f4 v; v[0] = X; v[1] = Yv; v[2] = Z; v[3] = s;
      pq[t4 * 4 + j] = v;
    }
  }
  __syncthreads();
  const int q = ((blk & 1023) << 3) + w;
  const f4 Q = pq[q];
  const float qx2 = Q[0] + Q[0], qy2 = Q[1] + Q[1], qz2 = Q[2] + Q[2];
  // phase A: per-lane max of fast metric over 128 candidates
  float mx = -3.0e38f;
#pragma unroll 4
  for (int t = 0; t < 128; ++t) {
    f4 c = pq[(t << 6) + lane];
    float v = fmaf(qx2, c[0], fmaf(qy2, c[1], fmaf(qz2, c[2], -c[3])));
    mx = fmaxf(mx, v);
  }
  // bitonic ascending sort of the 64 chunk maxima
  float sv = mx;
#pragma unroll
  for (int k = 2; k <= 64; k <<= 1) {
#pragma unroll
    for (int j = k >> 1; j > 0; j >>= 1) {
      float o = __shfl_xor(sv, j);
      bool takeMin = (((lane & k) == 0) == ((lane & j) == 0));
      sv = takeMin ? fminf(sv, o) : fmaxf(sv, o);
    }
  }
  float T = __shfl(sv, 44) - 1e-3f;   // 20th-largest chunk max, guard >> f32-vs-f64 skew
  // phase B: collect candidates
  int cnt = 0;
#pragma unroll 2
  for (int t = 0; t < 128; ++t) {
    f4 c = pq[(t << 6) + lane];
    float v = fmaf(qx2, c[0], fmaf(qy2, c[1], fmaf(qz2, c[2], -c[3])));
    bool pr = (v >= T);
    u64 ball = __ballot(pr);
    if (ball) {
      int ofs = (int)__popcll(ball & ((1ull << lane) - 1ull));
      int pos = cnt + ofs;
      if (pr && pos < 256) cii[w][pos] = (t << 6) + lane;
      cnt += (int)__popcll(ball);
    }
  }
  if (cnt > 256) cnt = 256;
  __syncthreads();
  // phase C: f64-exact values (f32 inputs -> f64 = true ranking), 20 argmax rounds
  const double Qx = (double)Q[0], Qy = (double)Q[1], Qz = (double)Q[2];
  const double Qs = Qx * Qx + Qy * Qy + Qz * Qz;
  double svv[4]; int sii[4];
#pragma unroll
  for (int j = 0; j < 4; ++j) {
    int e = lane + (j << 6);
    if (e < cnt) {
      int cand = cii[w][e];
      f4 c = pq[cand];
      double cx = (double)c[0], cy = (double)c[1], cz = (double)c[2];
      double cs = cx * cx + cy * cy + cz * cz;
      double dot = Qx * cx + Qy * cy + Qz * cz;
      svv[j] = 2.0 * dot - Qs - cs;
      sii[j] = cand;
    } else { svv[j] = -1.0e300; sii[j] = 0x7FFFFFFF; }
  }
  int* orow = idxOut + (((long)b << 13) + q) * 20;
  for (int r = 0; r < 20; ++r) {
    double bv = svv[0]; int bi = sii[0];
#pragma unroll
    for (int j = 1; j < 4; ++j) {
      bool bet = (svv[j] > bv) || (svv[j] == bv && sii[j] < bi);
      if (bet) { bv = svv[j]; bi = sii[j]; }
    }
#pragma unroll
    for (int j = 1; j < 64; j <<= 1) {
      double ov = __shfl_xor(bv, j);
      int    oi = __shfl_xor(bi, j);
      bool bet = (ov > bv) || (ov == bv && oi < bi);
      if (bet) { bv = ov; bi = oi; }
    }
#pragma unroll
    for (int j = 0; j < 4; ++j)
      if (sii[j] == bi && svv[j] == bv) { svv[j] = -1.0e300; sii[j] = 0x7FFFFFFF; }
    if (lane == 0) orow[r] = bi;
  }
}

// ---------------- f32 tiled GEMM: Y[b][n][o] = sum_k A[o][k]*B[...] ----------------
// BT=0: B is [n][K] (row stride K). BT=1: B is [k][8192] (x layout).
template<int BT>
__global__ __launch_bounds__(256) void k_gemm_f32(
    const float* __restrict__ A, const float* __restrict__ Bm, float* __restrict__ Y,
    int M, int K, long bsB, long bsY)
{
  __shared__ __align__(16) float sH[128][33];   // column reads: bank (n+k)&31 -> 2-way free
  __shared__ __align__(16) float sW[32][68];
  const int b = blockIdx.z;
  const int n0 = blockIdx.x * 128, m0 = blockIdx.y * 64;
  const float* Bp = Bm + (long)b * bsB;
  float* Yp = Y + (long)b * bsY;
  const int tid = threadIdx.x, lane = tid & 63, wv = tid >> 6, wo = wv * 16;
  float acc0[16], acc1[16];
#pragma unroll
  for (int i = 0; i < 16; ++i) { acc0[i] = 0.f; acc1[i] = 0.f; }
  const int KT = K >> 5;
  for (int kk = 0; kk < KT; ++kk) {
#pragma unroll
    for (int it = 0; it < 2; ++it) {          // stage W: 64 o x 32 k
      int s = tid + it * 256;
      int o = s >> 3, kq = (s & 7) << 2;
      f4 v = *(const f4*)(A + (long)(m0 + o) * K + kk * 32 + kq);
      sW[kq][o] = v[0]; sW[kq + 1][o] = v[1]; sW[kq + 2][o] = v[2]; sW[kq + 3][o] = v[3];
    }
    if (BT == 0) {
#pragma unroll
      for (int it = 0; it < 4; ++it) {        // stage H: 128 n x 32 k from [n][K]
        int s = tid + it * 256;
        int n = s >> 3, kq = (s & 7) << 2;
        f4 v = *(const f4*)(Bp + (long)(n0 + n) * K + kk * 32 + kq);
        sH[n][kq] = v[0]; sH[n][kq + 1] = v[1]; sH[n][kq + 2] = v[2]; sH[n][kq + 3] = v[3];
      }
    } else {
#pragma unroll
      for (int it = 0; it < 4; ++it) {        // stage H from [k][8192]
        int s = tid + it * 256;
        int k = s >> 5, nq = (s & 31) << 2;
        f4 v = *(const f4*)(Bp + (long)(kk * 32 + k) * 8192 + n0 + nq);
        sH[nq][k] = v[0]; sH[nq + 1][k] = v[1]; sH[nq + 2][k] = v[2]; sH[nq + 3][k] = v[3];
      }
    }
    __syncthreads();
#pragma unroll
    for (int k = 0; k < 32; ++k) {
      float a0 = sH[lane][k], a1 = sH[lane + 64][k];
      f4 w0 = *(const f4*)&sW[k][wo];
      f4 w1 = *(const f4*)&sW[k][wo + 4];
      f4 w2 = *(const f4*)&sW[k][wo + 8];
      f4 w3 = *(const f4*)&sW[k][wo + 12];
#pragma unroll
      for (int i = 0; i < 4; ++i) {
        acc0[i]      = fmaf(a0, w0[i], acc0[i]);
        acc0[4 + i]  = fmaf(a0, w1[i], acc0[4 + i]);
        acc0[8 + i]  = fmaf(a0, w2[i], acc0[8 + i]);
        acc0[12 + i] = fmaf(a0, w3[i], acc0[12 + i]);
        acc1[i]      = fmaf(a1, w0[i], acc1[i]);
        acc1[4 + i]  = fmaf(a1, w1[i], acc1[4 + i]);
        acc1[8 + i]  = fmaf(a1, w2[i], acc1[8 + i]);
        acc1[12 + i] = fmaf(a1, w3[i], acc1[12 + i]);
      }
    }
    __syncthreads();
  }
  float* d0 = Yp + (long)(n0 + lane) * M + m0 + wo;
  float* d1 = Yp + (long)(n0 + lane + 64) * M + m0 + wo;
#pragma unroll
  for (int i = 0; i < 4; ++i) {
    f4 t0, t1;
#pragma unroll
    for (int j = 0; j < 4; ++j) { t0[j] = acc0[i * 4 + j]; t1[j] = acc1[i * 4 + j]; }
    *(f4*)(d0 + i * 4) = t0;
    *(f4*)(d1 + i * 4) = t1;
  }
}

// ---------------- per-channel sum/sumsq over rows (Y is [rows][C]) ----------------
__global__ __launch_bounds__(256) void k_colstats(
    const float* __restrict__ Y, float* __restrict__ sums, float* __restrict__ ssq, int C, int RPB)
{
  const int tid = threadIdx.x;
  const int c = tid & (C - 1);
  const int sub = tid / C;
  const int step = 256 / C;
  const int r0 = blockIdx.x * RPB;
  float s = 0.f, qv = 0.f;
  for (int r = r0 + sub; r < r0 + RPB; r += step) {
    float v = Y[(long)r * C + c];
    s += v; qv = fmaf(v, v, qv);
  }
  atomicAdd(&sums[c], s);
  atomicAdd(&ssq[c], qv);
}

__global__ void k_finalize(const float* __restrict__ sums, const float* __restrict__ ssq,
                           const float* __restrict__ g, const float* __restrict__ bt,
                           float* __restrict__ scale, float* __restrict__ shift,
                           int C, float invCount)
{
  int c = threadIdx.x;
  if (c < C) {
    float m = sums[c] * invCount;
    float v = ssq[c] * invCount - m * m;
    float s = g[c] / sqrtf(v + 1e-5f);
    scale[c] = s;
    shift[c] = bt[c] - m * s;
  }
}

// ---------------- normalize + leaky (f32 out) ----------------
__global__ __launch_bounds__(256) void k_apply(
    const float* __restrict__ Y, const float* __restrict__ scale, const float* __restrict__ shift,
    float* __restrict__ H, int Cmask)
{
  long i = (long)blockIdx.x * 256 + threadIdx.x;
  f4 y = ((const f4*)Y)[i];
  int c0 = (int)((i << 2) & Cmask);
  f4 r;
#pragma unroll
  for (int j = 0; j < 4; ++j) {
    float z = fmaf(scale[c0 + j], y[j], shift[c0 + j]);
    r[j] = z > 0.f ? z : 0.2f * z;
  }
  ((f4*)H)[i] = r;
}

__global__ __launch_bounds__(256) void k_apply_edge(
    const float* __restrict__ Emax, const float* __restrict__ Emin,
    const float* __restrict__ scale, const float* __restrict__ shift, float* __restrict__ H)
{
  long i = (long)blockIdx.x * 256 + threadIdx.x;
  f4 a = ((const f4*)Emax)[i];
  f4 bm = ((const f4*)Emin)[i];
  int c0 = (int)((i << 2) & 255);
  f4 r;
#pragma unroll
  for (int j = 0; j < 4; ++j) {
    float s = scale[c0 + j];
    float y = (s >= 0.f) ? a[j] : bm[j];   // max commutes with monotone affine+leaky
    float z = fmaf(s, y, shift[c0 + j]);
    r[j] = z > 0.f ? z : 0.2f * z;
  }
  ((f4*)H)[i] = r;
}

// ---------------- edgeconv gather: y = Anb[idx] + Cy; track max/min + stats ----------------
__global__ __launch_bounds__(256, 2) void k_edge_gather(
    const float* __restrict__ Y2, const int* __restrict__ idx,
    float* __restrict__ Emax, float* __restrict__ Emin,
    float* __restrict__ sums, float* __restrict__ ssq)
{
  __shared__ float s_sum[256], s_ssq[256];
  const int tid = threadIdx.x, lane = tid & 63, w = tid >> 6;
  s_sum[tid] = 0.f; s_ssq[tid] = 0.f;
  __syncthreads();
  const int ptBase = blockIdx.x * 64;
  f4 lsum = {0.f, 0.f, 0.f, 0.f}, lssq = {0.f, 0.f, 0.f, 0.f};
  for (int i = 0; i < 16; ++i) {
    const int pt = ptBase + w * 16 + i;
    const int b = pt >> 13;
    f4 ctr = *(const f4*)(Y2 + (long)pt * 512 + 256 + (lane << 2));
    const int* irow = idx + (long)pt * 20;
    f4 vmax = {-3.0e38f, -3.0e38f, -3.0e38f, -3.0e38f};
    f4 vmin = {3.0e38f, 3.0e38f, 3.0e38f, 3.0e38f};
#pragma unroll 4
    for (int k = 0; k < 20; ++k) {
      int m = irow[k];
      f4 nb = *(const f4*)(Y2 + (((long)b << 13) + m) * 512 + (lane << 2));
      f4 y = nb + ctr;
#pragma unroll
      for (int j = 0; j < 4; ++j) {
        vmax[j] = fmaxf(vmax[j], y[j]);
        vmin[j] = fminf(vmin[j], y[j]);
        lsum[j] += y[j];
        lssq[j] = fmaf(y[j], y[j], lssq[j]);
      }
    }
    *(f4*)(Emax + (long)pt * 256 + (lane << 2)) = vmax;
    *(f4*)(Emin + (long)pt * 256 + (lane << 2)) = vmin;
  }
#pragma unroll
  for (int j = 0; j < 4; ++j) {
    atomicAdd(&s_sum[(lane << 2) + j], lsum[j]);
    atomicAdd(&s_ssq[(lane << 2) + j], lssq[j]);
  }
  __syncthreads();
  atomicAdd(&sums[tid], s_sum[tid]);
  atomicAdd(&ssq[tid], s_ssq[tid]);
}

// ---------------- final 50x128 GEMM + bias, f32 out (B,50,8192) ----------------
__global__ __launch_bounds__(256) void k_final(
    const float* __restrict__ H4, const float* __restrict__ wf, const float* __restrict__ bf,
    float* __restrict__ out)
{
  __shared__ float swf[4][128];
  __shared__ float sbf[4];
  const int o0 = blockIdx.y * 4;
  const int tid = threadIdx.x;
  if (tid < 128) {
#pragma unroll
    for (int j = 0; j < 4; ++j)
      swf[j][tid] = (o0 + j < 50) ? wf[(o0 + j) * 128 + tid] : 0.f;
  }
  if (tid < 4) sbf[tid] = (o0 + tid < 50) ? bf[o0 + tid] : 0.f;
  __syncthreads();
  const int b = blockIdx.z;
  const int n = blockIdx.x * 256 + tid;
  const float* h = H4 + (long)(b * 8192 + n) * 128;
  float av[4] = {0.f, 0.f, 0.f, 0.f};
#pragma unroll
  for (int t = 0; t < 32; ++t) {
    f4 hv = *(const f4*)(h + t * 4);
    int cc = t * 4;
#pragma unroll
    for (int e = 0; e < 4; ++e)
#pragma unroll
      for (int j = 0; j < 4; ++j)
        av[j] = fmaf(hv[e], swf[j][cc + e], av[j]);
  }
#pragma unroll
  for (int j = 0; j < 4; ++j) {
    int o = o0 + j;
    if (o < 50) out[(((long)b * 50 + o) << 13) + n] = av[j] + sbf[j];
  }
}

// ---------------- launcher ----------------
extern "C" void kernel_launch(void* const* d_in, const int* in_sizes, int n_in,
                              void* d_out, int out_size, void* d_ws, size_t ws_size,
                              hipStream_t stream)
{
  if ((long)ws_size < WS_NEED) return;
  const float* x   = (const float*)d_in[0];
  const float* p   = (const float*)d_in[1];
  const float* w1  = (const float*)d_in[2];
  const float* g1  = (const float*)d_in[4];
  const float* bt1 = (const float*)d_in[5];
  const float* we  = (const float*)d_in[6];
  const float* ge  = (const float*)d_in[8];
  const float* bte = (const float*)d_in[9];
  const float* w2  = (const float*)d_in[10];
  const float* g2  = (const float*)d_in[12];
  const float* bt2 = (const float*)d_in[13];
  const float* w3  = (const float*)d_in[14];
  const float* g3  = (const float*)d_in[16];
  const float* bt3 = (const float*)d_in[17];
  const float* wf  = (const float*)d_in[18];
  const float* bfi = (const float*)d_in[19];

  char* ws = (char*)d_ws;
  float* weAB = (float*)(ws + OFF_WEAB);
  int*   idxb = (int*)(ws + OFF_IDX);
  float* Y1   = (float*)(ws + OFF_Y1);
  float* H1   = (float*)(ws + OFF_H1);
  float* Y2   = (float*)(ws + OFF_Y2);
  float* EMAX = (float*)(ws + OFF_EMAX);
  float* EMIN = (float*)(ws + OFF_EMIN);
  float* H2   = (float*)(ws + OFF_H2);
  float* Y3   = (float*)(ws + OFF_Y3);
  float* H3   = (float*)(ws + OFF_H3);
  float* Y4   = (float*)(ws + OFF_Y4);
  float* H4   = (float*)(ws + OFF_H4);
  float* st0 = (float*)(ws + OFF_STATS);
  float* st1 = (float*)(ws + OFF_STATS + 4096);
  float* st2 = (float*)(ws + OFF_STATS + 8192);
  float* st3 = (float*)(ws + OFF_STATS + 12288);

  hipMemsetAsync(ws + OFF_STATS, 0, 16384, stream);
  k_wedge<<<512, 256, 0, stream>>>(we, weAB);
  k_knn<<<2048, 512, 0, stream>>>(p, idxb);

  // stage 1: smlp1d(x, w1) — B from x [c][n] layout
  k_gemm_f32<1><<<dim3(64, 4, 2), 256, 0, stream>>>(w1, x, Y1, 256, 1216, (long)1216 * 8192, (long)8192 * 256);
  k_colstats<<<256, 256, 0, stream>>>(Y1, st0, st0 + 256, 256, 64);
  k_finalize<<<1, 256, 0, stream>>>(st0, st0 + 256, g1, bt1, st0 + 512, st0 + 768, 256, 1.0f / 16384.0f);
  k_apply<<<4096, 256, 0, stream>>>(Y1, st0 + 512, st0 + 768, H1, 255);

  // edgeconv: [Anb | Cy] GEMM, gather+max/min+stats, apply
  k_gemm_f32<0><<<dim3(64, 8, 2), 256, 0, stream>>>(weAB, H1, Y2, 512, 256, (long)8192 * 256, (long)8192 * 512);
  k_edge_gather<<<256, 256, 0, stream>>>(Y2, idxb, EMAX, EMIN, st1, st1 + 256);
  k_finalize<<<1, 256, 0, stream>>>(st1, st1 + 256, ge, bte, st1 + 512, st1 + 768, 256, 1.0f / 327680.0f);
  k_apply_edge<<<4096, 256, 0, stream>>>(EMAX, EMIN, st1 + 512, st1 + 768, H2);

  // stage 2: smlp1d(h, w2)
  k_gemm_f32<0><<<dim3(64, 4, 2), 256, 0, stream>>>(w2, H2, Y3, 256, 256, (long)8192 * 256, (long)8192 * 256);
  k_colstats<<<256, 256, 0, stream>>>(Y3, st2, st2 + 256, 256, 64);
  k_finalize<<<1, 256, 0, stream>>>(st2, st2 + 256, g2, bt2, st2 + 512, st2 + 768, 256, 1.0f / 16384.0f);
  k_apply<<<4096, 256, 0, stream>>>(Y3, st2 + 512, st2 + 768, H3, 255);

  // stage 3: smlp1d(h, w3)
  k_gemm_f32<0><<<dim3(64, 2, 2), 256, 0, stream>>>(w3, H3, Y4, 128, 256, (long)8192 * 256, (long)8192 * 128);
  k_colstats<<<128, 256, 0, stream>>>(Y4, st3, st3 + 256, 128, 128);
  k_finalize<<<1, 256, 0, stream>>>(st3, st3 + 256, g3, bt3, st3 + 512, st3 + 768, 128, 1.0f / 16384.0f);
  k_apply<<<2048, 256, 0, stream>>>(Y4, st3 + 512, st3 + 768, H4, 127);

  // final projection
  k_final<<<dim3(32, 13, 2), 256, 0, stream>>>(H4, wf, bfi, (float*)d_out);
}

// Round 5
// 527.337 us; speedup vs baseline: 1.5885x; 1.5885x over previous
//
#include <hip/hip_runtime.h>

typedef unsigned short u16;
typedef unsigned int   u32;
typedef unsigned long long u64;
typedef __attribute__((ext_vector_type(4))) float f4;
typedef __attribute__((ext_vector_type(8))) short s8;
typedef __attribute__((ext_vector_type(4))) int   i4v;

#define DEV __device__ __forceinline__

DEV u16 f2b(float f) {
  u32 u = __float_as_uint(f);
  return (u16)((u + 0x7FFFu + ((u >> 16) & 1u)) >> 16);
}
DEV float b2f(u16 h) { return __uint_as_float(((u32)h) << 16); }

// ---------------- workspace layout (bytes) ----------------
#define OFF_STATS 0L
#define OFF_W1B   65536L
#define OFF_WEAB  688128L
#define OFF_W2B   950272L
#define OFF_W3B   1081344L
#define OFF_IDX   1146880L
#define OFF_XT    4194304L      /* 38 MiB, dead after GEMM1 */
#define OFF_Y1    44040192L     /* 16 MiB */
#define OFF_H1    60817408L     /* 8 MiB bf16 */
#define OFF_Y2    4194304L      /* 32 MiB over dead XT */
#define OFF_EMAX  37748736L     /* 16 MiB over dead XT tail + Y1 */
#define OFF_EMIN  54525952L     /* 16 MiB over dead Y1 tail + H1 */
#define OFF_H2    4194304L      /* 8 MiB over dead Y2 head */
#define OFF_Y3    12582912L     /* 16 MiB */
#define OFF_H3    29360128L     /* 8 MiB */
#define OFF_Y4    37748736L     /* 8 MiB over dead EMAX */
#define OFF_H4    46137344L     /* 4 MiB */
#define WS_NEED   71303168L

// ---------------- weight convert -> bf16 (w1 | weA,weB-weA | w2 | w3) ----------------
__global__ __launch_bounds__(256) void k_convw(
    const float* __restrict__ w1, const float* __restrict__ we,
    const float* __restrict__ w2, const float* __restrict__ w3,
    u16* __restrict__ w1b, u16* __restrict__ weABb,
    u16* __restrict__ w2b, u16* __restrict__ w3b)
{
  int i = blockIdx.x * 256 + threadIdx.x;
  if (i < 311296) { w1b[i] = f2b(w1[i]); return; }
  i -= 311296;
  if (i < 131072) {
    int o = i >> 8, c = i & 255;
    float v = (o < 256) ? we[o * 512 + c]
                        : we[(o - 256) * 512 + 256 + c] - we[(o - 256) * 512 + c];
    weABb[i] = f2b(v); return;
  }
  i -= 131072;
  if (i < 65536) { w2b[i] = f2b(w2[i]); return; }
  i -= 65536;
  if (i < 32768) { w3b[i] = f2b(w3[i]); }
}

// ---------------- x transpose + bf16: (B,1216,8192)f32 -> (B,8192,1216)bf16 ----------------
__global__ __launch_bounds__(256) void k_xt(const float* __restrict__ x, u16* __restrict__ xt)
{
  __shared__ float t[64][65];
  const int b = blockIdx.z, ct = blockIdx.y, nt = blockIdx.x;
  const int tx = threadIdx.x & 63, ty = threadIdx.x >> 6;
  const float* xb = x + (long)b * 1216 * 8192;
#pragma unroll
  for (int i = 0; i < 16; ++i) {
    int c = ct * 64 + ty + i * 4;
    t[ty + i * 4][tx] = xb[(long)c * 8192 + nt * 64 + tx];
  }
  __syncthreads();
  u16* xtb = xt + (long)b * 8192 * 1216;
#pragma unroll
  for (int i = 0; i < 16; ++i) {
    int n = nt * 64 + ty + i * 4;
    xtb[(long)n * 1216 + ct * 64 + tx] = f2b(t[tx][ty + i * 4]);
  }
}

// ---------------- exact KNN top-20 (f64 re-rank matches f64 gold) ----------------
__global__ __launch_bounds__(512, 1) void k_knn(const float* __restrict__ p, int* __restrict__ idxOut)
{
  __shared__ f4 pq[8192];        // 128 KB: (x,y,z,sq_f32)
  __shared__ int cii[8][256];    // 8 KB
  const int tid = threadIdx.x, lane = tid & 63, w = tid >> 6;
  const int blk = blockIdx.x;
  const int b = blk >> 10;
  const float* px = p + (long)b * 24576;
  const float* py = px + 8192;
  const float* pz = px + 16384;
  for (int t4 = tid; t4 < 2048; t4 += 512) {
    f4 x4 = *(const f4*)(px + t4 * 4);
    f4 y4 = *(const f4*)(py + t4 * 4);
    f4 z4 = *(const f4*)(pz + t4 * 4);
#pragma unroll
    for (int j = 0; j < 4; ++j) {
      float X = x4[j], Yv = y4[j], Z = z4[j];
      float s = fmaf(X, X, fmaf(Yv, Yv, Z * Z));
      f4 v; v[0] = X; v[1] = Yv; v[2] = Z; v[3] = s;
      pq[t4 * 4 + j] = v;
    }
  }
  __syncthreads();
  const int q = ((blk & 1023) << 3) + w;
  const f4 Q = pq[q];
  const float qx2 = Q[0] + Q[0], qy2 = Q[1] + Q[1], qz2 = Q[2] + Q[2];
  float mx = -3.0e38f;
#pragma unroll 4
  for (int t = 0; t < 128; ++t) {
    f4 c = pq[(t << 6) + lane];
    float v = fmaf(qx2, c[0], fmaf(qy2, c[1], fmaf(qz2, c[2], -c[3])));
    mx = fmaxf(mx, v);
  }
  float sv = mx;
#pragma unroll
  for (int k = 2; k <= 64; k <<= 1) {
#pragma unroll
    for (int j = k >> 1; j > 0; j >>= 1) {
      float o = __shfl_xor(sv, j);
      bool takeMin = (((lane & k) == 0) == ((lane & j) == 0));
      sv = takeMin ? fminf(sv, o) : fmaxf(sv, o);
    }
  }
  float T = __shfl(sv, 44) - 1e-3f;
  int cnt = 0;
#pragma unroll 2
  for (int t = 0; t < 128; ++t) {
    f4 c = pq[(t << 6) + lane];
    float v = fmaf(qx2, c[0], fmaf(qy2, c[1], fmaf(qz2, c[2], -c[3])));
    bool pr = (v >= T);
    u64 ball = __ballot(pr);
    if (ball) {
      int ofs = (int)__popcll(ball & ((1ull << lane) - 1ull));
      int pos = cnt + ofs;
      if (pr && pos < 256) cii[w][pos] = (t << 6) + lane;
      cnt += (int)__popcll(ball);
    }
  }
  if (cnt > 256) cnt = 256;
  __syncthreads();
  const double Qx = (double)Q[0], Qy = (double)Q[1], Qz = (double)Q[2];
  const double Qs = Qx * Qx + Qy * Qy + Qz * Qz;
  double svv[4]; int sii[4];
#pragma unroll
  for (int j = 0; j < 4; ++j) {
    int e = lane + (j << 6);
    if (e < cnt) {
      int cand = cii[w][e];
      f4 c = pq[cand];
      double cx = (double)c[0], cy = (double)c[1], cz = (double)c[2];
      double cs = cx * cx + cy * cy + cz * cz;
      double dot = Qx * cx + Qy * cy + Qz * cz;
      svv[j] = 2.0 * dot - Qs - cs;
      sii[j] = cand;
    } else { svv[j] = -1.0e300; sii[j] = 0x7FFFFFFF; }
  }
  int* orow = idxOut + (((long)b << 13) + q) * 20;
  for (int r = 0; r < 20; ++r) {
    double bv = svv[0]; int bi = sii[0];
#pragma unroll
    for (int j = 1; j < 4; ++j) {
      bool bet = (svv[j] > bv) || (svv[j] == bv && sii[j] < bi);
      if (bet) { bv = svv[j]; bi = sii[j]; }
    }
#pragma unroll
    for (int j = 1; j < 64; j <<= 1) {
      double ov = __shfl_xor(bv, j);
      int    oi = __shfl_xor(bi, j);
      bool bet = (ov > bv) || (ov == bv && oi < bi);
      if (bet) { bv = ov; bi = oi; }
    }
#pragma unroll
    for (int j = 0; j < 4; ++j)
      if (sii[j] == bi && svv[j] == bv) { svv[j] = -1.0e300; sii[j] = 0x7FFFFFFF; }
    if (lane == 0) orow[r] = bi;
  }
}

// ---------------- bf16 MFMA GEMM: Y[b][n][o] = sum_k A[o][k]*B[b][n][k] ----------------
// 128x128 tile, 4 waves, BK=32, reg-staged double buffer, mfma_f32_16x16x32_bf16
__global__ __launch_bounds__(256, 2) void k_gemm(
    const u16* __restrict__ A, const u16* __restrict__ Bm, float* __restrict__ Y,
    int M, int K, long strideB, long strideY)
{
  __shared__ u16 sA[2][4096];
  __shared__ u16 sB[2][4096];
  const int b = blockIdx.z;
  const int m0 = blockIdx.y * 128;
  const int n0 = blockIdx.x * 128;
  const u16* Bp = Bm + (long)b * strideB;
  float* Yp = Y + (long)b * strideY;
  const int tid = threadIdx.x, lane = tid & 63, w = tid >> 6;
  const int wr = w >> 1, wc = w & 1;
  const int r15 = lane & 15, g8 = (lane >> 4) * 8;

  f4 acc[4][4];
#pragma unroll
  for (int i = 0; i < 4; ++i)
#pragma unroll
    for (int j = 0; j < 4; ++j) { f4 z = {0.f, 0.f, 0.f, 0.f}; acc[i][j] = z; }

  const int row0 = tid >> 2;            // 0..63
  const int kp0 = (tid & 3) << 3;       // 0,8,16,24
  const u16* gA0 = A + (long)(m0 + row0) * K + kp0;
  const u16* gA1 = A + (long)(m0 + row0 + 64) * K + kp0;
  const u16* gB0 = Bp + (long)(n0 + row0) * K + kp0;
  const u16* gB1 = Bp + (long)(n0 + row0 + 64) * K + kp0;
  const int ch0 = tid, ch1 = tid + 256;

  ((i4v*)sA[0])[ch0] = *(const i4v*)gA0;
  ((i4v*)sA[0])[ch1] = *(const i4v*)gA1;
  ((i4v*)sB[0])[ch0] = *(const i4v*)gB0;
  ((i4v*)sB[0])[ch1] = *(const i4v*)gB1;
  __syncthreads();

  const int KT = K >> 5;
  int cur = 0;
  for (int kk = 0; kk < KT; ++kk) {
    i4v ra0, ra1, rb0, rb1;
    const bool more = (kk + 1 < KT);
    if (more) {
      long ko = (long)(kk + 1) * 32;
      ra0 = *(const i4v*)(gA0 + ko); ra1 = *(const i4v*)(gA1 + ko);
      rb0 = *(const i4v*)(gB0 + ko); rb1 = *(const i4v*)(gB1 + ko);
    }
    const u16* la = sA[cur];
    const u16* lb = sB[cur];
    s8 af[4], bfr[4];
#pragma unroll
    for (int mi = 0; mi < 4; ++mi)
      af[mi] = *(const s8*)(la + (wr * 64 + mi * 16 + r15) * 32 + g8);
#pragma unroll
    for (int ni = 0; ni < 4; ++ni)
      bfr[ni] = *(const s8*)(lb + (wc * 64 + ni * 16 + r15) * 32 + g8);
#pragma unroll
    for (int mi = 0; mi < 4; ++mi)
#pragma unroll
      for (int ni = 0; ni < 4; ++ni)
        acc[mi][ni] = __builtin_amdgcn_mfma_f32_16x16x32_bf16(af[mi], bfr[ni], acc[mi][ni], 0, 0, 0);
    if (more) {
      ((i4v*)sA[cur ^ 1])[ch0] = ra0; ((i4v*)sA[cur ^ 1])[ch1] = ra1;
      ((i4v*)sB[cur ^ 1])[ch0] = rb0; ((i4v*)sB[cur ^ 1])[ch1] = rb1;
    }
    __syncthreads();
    cur ^= 1;
  }
  // epilogue: D col(n)=lane&15, row(o)=(lane>>4)*4+reg
  const int og = m0 + wr * 64 + (lane >> 4) * 4;
  const int ng = n0 + wc * 64 + r15;
#pragma unroll
  for (int mi = 0; mi < 4; ++mi)
#pragma unroll
    for (int ni = 0; ni < 4; ++ni)
      *(f4*)(Yp + (long)(ng + ni * 16) * M + og + mi * 16) = acc[mi][ni];
}

// ---------------- per-channel sum/sumsq over rows (Y is [rows][C]) ----------------
__global__ __launch_bounds__(256) void k_colstats(
    const float* __restrict__ Y, float* __restrict__ sums, float* __restrict__ ssq, int C, int RPB)
{
  const int tid = threadIdx.x;
  const int c = tid & (C - 1);
  const int sub = tid / C;
  const int step = 256 / C;
  const int r0 = blockIdx.x * RPB;
  float s = 0.f, qv = 0.f;
  for (int r = r0 + sub; r < r0 + RPB; r += step) {
    float v = Y[(long)r * C + c];
    s += v; qv = fmaf(v, v, qv);
  }
  atomicAdd(&sums[c], s);
  atomicAdd(&ssq[c], qv);
}

__global__ void k_finalize(const float* __restrict__ sums, const float* __restrict__ ssq,
                           const float* __restrict__ g, const float* __restrict__ bt,
                           float* __restrict__ scale, float* __restrict__ shift,
                           int C, float invCount)
{
  int c = threadIdx.x;
  if (c < C) {
    float m = sums[c] * invCount;
    float v = ssq[c] * invCount - m * m;
    float s = g[c] / sqrtf(v + 1e-5f);
    scale[c] = s;
    shift[c] = bt[c] - m * s;
  }
}

// ---------------- normalize + leaky -> bf16 ----------------
__global__ __launch_bounds__(256) void k_apply(
    const float* __restrict__ Y, const float* __restrict__ scale, const float* __restrict__ shift,
    u16* __restrict__ H, int Cmask)
{
  long i = (long)blockIdx.x * 256 + threadIdx.x;
  f4 y = ((const f4*)Y)[i];
  int c0 = (int)((i << 2) & Cmask);
  float r[4];
#pragma unroll
  for (int j = 0; j < 4; ++j) {
    float z = fmaf(scale[c0 + j], y[j], shift[c0 + j]);
    r[j] = z > 0.f ? z : 0.2f * z;
  }
  u32 lo = (u32)f2b(r[0]) | ((u32)f2b(r[1]) << 16);
  u32 hi = (u32)f2b(r[2]) | ((u32)f2b(r[3]) << 16);
  *(uint2*)(H + i * 4) = make_uint2(lo, hi);
}

__global__ __launch_bounds__(256) void k_apply_edge(
    const float* __restrict__ Emax, const float* __restrict__ Emin,
    const float* __restrict__ scale, const float* __restrict__ shift, u16* __restrict__ H)
{
  long i = (long)blockIdx.x * 256 + threadIdx.x;
  f4 a = ((const f4*)Emax)[i];
  f4 bm = ((const f4*)Emin)[i];
  int c0 = (int)((i << 2) & 255);
  float r[4];
#pragma unroll
  for (int j = 0; j < 4; ++j) {
    float s = scale[c0 + j];
    float y = (s >= 0.f) ? a[j] : bm[j];   // max commutes with monotone affine+leaky
    float z = fmaf(s, y, shift[c0 + j]);
    r[j] = z > 0.f ? z : 0.2f * z;
  }
  u32 lo = (u32)f2b(r[0]) | ((u32)f2b(r[1]) << 16);
  u32 hi = (u32)f2b(r[2]) | ((u32)f2b(r[3]) << 16);
  *(uint2*)(H + i * 4) = make_uint2(lo, hi);
}

// ---------------- edgeconv gather: y = Anb[idx] + Cy; track max/min + stats ----------------
__global__ __launch_bounds__(256, 2) void k_edge_gather(
    const float* __restrict__ Y2, const int* __restrict__ idx,
    float* __restrict__ Emax, float* __restrict__ Emin,
    float* __restrict__ sums, float* __restrict__ ssq)
{
  __shared__ float s_sum[256], s_ssq[256];
  const int tid = threadIdx.x, lane = tid & 63, w = tid >> 6;
  s_sum[tid] = 0.f; s_ssq[tid] = 0.f;
  __syncthreads();
  const int ptBase = blockIdx.x * 64;
  f4 lsum = {0.f, 0.f, 0.f, 0.f}, lssq = {0.f, 0.f, 0.f, 0.f};
  for (int i = 0; i < 16; ++i) {
    const int pt = ptBase + w * 16 + i;
    const int b = pt >> 13;
    f4 ctr = *(const f4*)(Y2 + (long)pt * 512 + 256 + (lane << 2));
    const int* irow = idx + (long)pt * 20;
    f4 vmax = {-3.0e38f, -3.0e38f, -3.0e38f, -3.0e38f};
    f4 vmin = {3.0e38f, 3.0e38f, 3.0e38f, 3.0e38f};
#pragma unroll 4
    for (int k = 0; k < 20; ++k) {
      int m = irow[k];
      f4 nb = *(const f4*)(Y2 + (((long)b << 13) + m) * 512 + (lane << 2));
      f4 y = nb + ctr;
#pragma unroll
      for (int j = 0; j < 4; ++j) {
        vmax[j] = fmaxf(vmax[j], y[j]);
        vmin[j] = fminf(vmin[j], y[j]);
        lsum[j] += y[j];
        lssq[j] = fmaf(y[j], y[j], lssq[j]);
      }
    }
    *(f4*)(Emax + (long)pt * 256 + (lane << 2)) = vmax;
    *(f4*)(Emin + (long)pt * 256 + (lane << 2)) = vmin;
  }
#pragma unroll
  for (int j = 0; j < 4; ++j) {
    atomicAdd(&s_sum[(lane << 2) + j], lsum[j]);
    atomicAdd(&s_ssq[(lane << 2) + j], lssq[j]);
  }
  __syncthreads();
  atomicAdd(&sums[tid], s_sum[tid]);
  atomicAdd(&ssq[tid], s_ssq[tid]);
}

// ---------------- final 50x128 GEMM + bias, f32 out (B,50,8192); H4 is bf16 ----------------
__global__ __launch_bounds__(256) void k_final(
    const u16* __restrict__ H4, const float* __restrict__ wf, const float* __restrict__ bf,
    float* __restrict__ out)
{
  __shared__ float swf[4][128];
  __shared__ float sbf[4];
  const int o0 = blockIdx.y * 4;
  const int tid = threadIdx.x;
  if (tid < 128) {
#pragma unroll
    for (int j = 0; j < 4; ++j)
      swf[j][tid] = (o0 + j < 50) ? wf[(o0 + j) * 128 + tid] : 0.f;
  }
  if (tid < 4) sbf[tid] = (o0 + tid < 50) ? bf[o0 + tid] : 0.f;
  __syncthreads();
  const int b = blockIdx.z;
  const int n = blockIdx.x * 256 + tid;
  const u16* h = H4 + (long)(b * 8192 + n) * 128;
  float av[4] = {0.f, 0.f, 0.f, 0.f};
#pragma unroll
  for (int t = 0; t < 16; ++t) {
    i4v raw = *(const i4v*)(h + t * 8);
#pragma unroll
    for (int e = 0; e < 4; ++e) {
      u32 dw = (u32)raw[e];
      float f0 = b2f((u16)(dw & 0xFFFFu));
      float f1 = b2f((u16)(dw >> 16));
      int cc = t * 8 + e * 2;
#pragma unroll
      for (int j = 0; j < 4; ++j) {
        av[j] = fmaf(f0, swf[j][cc], av[j]);
        av[j] = fmaf(f1, swf[j][cc + 1], av[j]);
      }
    }
  }
#pragma unroll
  for (int j = 0; j < 4; ++j) {
    int o = o0 + j;
    if (o < 50) out[(((long)b * 50 + o) << 13) + n] = av[j] + sbf[j];
  }
}

// ---------------- launcher ----------------
extern "C" void kernel_launch(void* const* d_in, const int* in_sizes, int n_in,
                              void* d_out, int out_size, void* d_ws, size_t ws_size,
                              hipStream_t stream)
{
  if ((long)ws_size < WS_NEED) return;
  const float* x   = (const float*)d_in[0];
  const float* p   = (const float*)d_in[1];
  const float* w1  = (const float*)d_in[2];
  const float* g1  = (const float*)d_in[4];
  const float* bt1 = (const float*)d_in[5];
  const float* we  = (const float*)d_in[6];
  const float* ge  = (const float*)d_in[8];
  const float* bte = (const float*)d_in[9];
  const float* w2  = (const float*)d_in[10];
  const float* g2  = (const float*)d_in[12];
  const float* bt2 = (const float*)d_in[13];
  const float* w3  = (const float*)d_in[14];
  const float* g3  = (const float*)d_in[16];
  const float* bt3 = (const float*)d_in[17];
  const float* wf  = (const float*)d_in[18];
  const float* bfi = (const float*)d_in[19];

  char* ws = (char*)d_ws;
  u16* w1b   = (u16*)(ws + OFF_W1B);
  u16* weABb = (u16*)(ws + OFF_WEAB);
  u16* w2b   = (u16*)(ws + OFF_W2B);
  u16* w3b   = (u16*)(ws + OFF_W3B);
  int* idxb  = (int*)(ws + OFF_IDX);
  u16*   XT   = (u16*)(ws + OFF_XT);
  float* Y1   = (float*)(ws + OFF_Y1);
  u16*   H1   = (u16*)(ws + OFF_H1);
  float* Y2   = (float*)(ws + OFF_Y2);
  float* EMAX = (float*)(ws + OFF_EMAX);
  float* EMIN = (float*)(ws + OFF_EMIN);
  u16*   H2   = (u16*)(ws + OFF_H2);
  float* Y3   = (float*)(ws + OFF_Y3);
  u16*   H3   = (u16*)(ws + OFF_H3);
  float* Y4   = (float*)(ws + OFF_Y4);
  u16*   H4   = (u16*)(ws + OFF_H4);
  float* st0 = (float*)(ws + OFF_STATS);
  float* st1 = (float*)(ws + OFF_STATS + 4096);
  float* st2 = (float*)(ws + OFF_STATS + 8192);
  float* st3 = (float*)(ws + OFF_STATS + 12288);

  hipMemsetAsync(ws + OFF_STATS, 0, 16384, stream);
  k_convw<<<2112, 256, 0, stream>>>(w1, we, w2, w3, w1b, weABb, w2b, w3b);
  k_knn<<<2048, 512, 0, stream>>>(p, idxb);
  k_xt<<<dim3(128, 19, 2), 256, 0, stream>>>(x, XT);

  // stage 1: smlp1d(x, w1)
  k_gemm<<<dim3(64, 2, 2), 256, 0, stream>>>(w1b, XT, Y1, 256, 1216, (long)8192 * 1216, (long)8192 * 256);
  k_colstats<<<256, 256, 0, stream>>>(Y1, st0, st0 + 256, 256, 64);
  k_finalize<<<1, 256, 0, stream>>>(st0, st0 + 256, g1, bt1, st0 + 512, st0 + 768, 256, 1.0f / 16384.0f);
  k_apply<<<4096, 256, 0, stream>>>(Y1, st0 + 512, st0 + 768, H1, 255);

  // edgeconv: [Anb | Cy] GEMM, gather+max/min+stats, apply
  k_gemm<<<dim3(64, 4, 2), 256, 0, stream>>>(weABb, H1, Y2, 512, 256, (long)8192 * 256, (long)8192 * 512);
  k_edge_gather<<<256, 256, 0, stream>>>(Y2, idxb, EMAX, EMIN, st1, st1 + 256);
  k_finalize<<<1, 256, 0, stream>>>(st1, st1 + 256, ge, bte, st1 + 512, st1 + 768, 256, 1.0f / 327680.0f);
  k_apply_edge<<<4096, 256, 0, stream>>>(EMAX, EMIN, st1 + 512, st1 + 768, H2);

  // stage 2: smlp1d(h, w2)
  k_gemm<<<dim3(64, 2, 2), 256, 0, stream>>>(w2b, H2, Y3, 256, 256, (long)8192 * 256, (long)8192 * 256);
  k_colstats<<<256, 256, 0, stream>>>(Y3, st2, st2 + 256, 256, 64);
  k_finalize<<<1, 256, 0, stream>>>(st2, st2 + 256, g2, bt2, st2 + 512, st2 + 768, 256, 1.0f / 16384.0f);
  k_apply<<<4096, 256, 0, stream>>>(Y3, st2 + 512, st2 + 768, H3, 255);

  // stage 3: smlp1d(h, w3)
  k_gemm<<<dim3(64, 1, 2), 256, 0, stream>>>(w3b, H3, Y4, 128, 256, (long)8192 * 256, (long)8192 * 128);
  k_colstats<<<128, 256, 0, stream>>>(Y4, st3, st3 + 256, 128, 128);
  k_finalize<<<1, 256, 0, stream>>>(st3, st3 + 256, g3, bt3, st3 + 512, st3 + 768, 128, 1.0f / 16384.0f);
  k_apply<<<2048, 256, 0, stream>>>(Y4, st3 + 512, st3 + 768, H4, 127);

  // final projection
  k_final<<<dim3(32, 13, 2), 256, 0, stream>>>(H4, wf, bfi, (float*)d_out);
}

// Round 6
// 452.573 us; speedup vs baseline: 1.8509x; 1.1652x over previous
//
#include <hip/hip_runtime.h>

typedef unsigned short u16;
typedef unsigned int   u32;
typedef unsigned long long u64;
typedef __attribute__((ext_vector_type(4))) float f4;
typedef __attribute__((ext_vector_type(8))) short s8;
typedef __attribute__((ext_vector_type(4))) int   i4v;

#define DEV __device__ __forceinline__

DEV u16 f2b(float f) {
  u32 u = __float_as_uint(f);
  return (u16)((u + 0x7FFFu + ((u >> 16) & 1u)) >> 16);
}
DEV float b2f(u16 h) { return __uint_as_float(((u32)h) << 16); }

// ---------------- workspace layout (bytes) ----------------
#define OFF_STATS 0L
#define OFF_W1B   65536L
#define OFF_WEAB  688128L
#define OFF_W2B   950272L
#define OFF_W3B   1081344L
#define OFF_IDX   1146880L
#define OFF_XT    4194304L      /* 38 MiB, dead after GEMM1 */
#define OFF_Y1    44040192L     /* 16 MiB */
#define OFF_H1    60817408L     /* 8 MiB bf16 */
#define OFF_Y2    4194304L      /* 32 MiB over dead XT */
#define OFF_EMAX  37748736L     /* 16 MiB over dead XT tail + Y1 */
#define OFF_EMIN  54525952L     /* 16 MiB over dead Y1 tail + H1 */
#define OFF_H2    4194304L      /* 8 MiB over dead Y2 head */
#define OFF_Y3    12582912L     /* 16 MiB */
#define OFF_H3    29360128L     /* 8 MiB */
#define OFF_Y4    37748736L     /* 8 MiB over dead EMAX */
#define OFF_H4    46137344L     /* 4 MiB */
#define WS_NEED   71303168L

// ---------------- weight convert -> bf16 (w1 | weA,weB-weA | w2 | w3) ----------------
__global__ __launch_bounds__(256) void k_convw(
    const float* __restrict__ w1, const float* __restrict__ we,
    const float* __restrict__ w2, const float* __restrict__ w3,
    u16* __restrict__ w1b, u16* __restrict__ weABb,
    u16* __restrict__ w2b, u16* __restrict__ w3b)
{
  int i = blockIdx.x * 256 + threadIdx.x;
  if (i < 311296) { w1b[i] = f2b(w1[i]); return; }
  i -= 311296;
  if (i < 131072) {
    int o = i >> 8, c = i & 255;
    float v = (o < 256) ? we[o * 512 + c]
                        : we[(o - 256) * 512 + 256 + c] - we[(o - 256) * 512 + c];
    weABb[i] = f2b(v); return;
  }
  i -= 131072;
  if (i < 65536) { w2b[i] = f2b(w2[i]); return; }
  i -= 65536;
  if (i < 32768) { w3b[i] = f2b(w3[i]); }
}

// ---------------- x transpose + bf16: (B,1216,8192)f32 -> (B,8192,1216)bf16 ----------------
__global__ __launch_bounds__(256) void k_xt(const float* __restrict__ x, u16* __restrict__ xt)
{
  __shared__ float t[64][65];
  const int b = blockIdx.z, ct = blockIdx.y, nt = blockIdx.x;
  const int tx = threadIdx.x & 63, ty = threadIdx.x >> 6;
  const float* xb = x + (long)b * 1216 * 8192;
#pragma unroll
  for (int i = 0; i < 16; ++i) {
    int c = ct * 64 + ty + i * 4;
    t[ty + i * 4][tx] = xb[(long)c * 8192 + nt * 64 + tx];
  }
  __syncthreads();
  u16* xtb = xt + (long)b * 8192 * 1216;
#pragma unroll
  for (int i = 0; i < 16; ++i) {
    int n = nt * 64 + ty + i * 4;
    xtb[(long)n * 1216 + ct * 64 + tx] = f2b(t[tx][ty + i * 4]);
  }
}

// ---------------- exact KNN top-20, 8 queries/wave (f64 re-rank matches f64 gold) ----------------
// 256 blocks x 512 thr. Block = 64 queries (8 waves x 8). All 8192 points staged in LDS once;
// each ds_read_b128 feeds 8 queries -> LDS traffic /8 vs 1-query-per-wave version.
__global__ __launch_bounds__(512, 1) void k_knn(const float* __restrict__ p, int* __restrict__ idxOut)
{
  __shared__ f4 pq[8192];            // 128 KB: (x,y,z,|c|^2)
  __shared__ int cand[8][8][120];    // 30 KB: per (wave, query) candidate indices
  const int tid = threadIdx.x, lane = tid & 63, w = tid >> 6;
  const int blk = blockIdx.x;        // 256 blocks
  const int b = blk >> 7;            // batch
  const int qbase = ((blk & 127) << 6) + (w << 3);
  const float* px = p + (long)b * 24576;
  const float* py = px + 8192;
  const float* pz = px + 16384;
  for (int t4 = tid; t4 < 2048; t4 += 512) {
    f4 x4 = *(const f4*)(px + t4 * 4);
    f4 y4 = *(const f4*)(py + t4 * 4);
    f4 z4 = *(const f4*)(pz + t4 * 4);
#pragma unroll
    for (int j = 0; j < 4; ++j) {
      float X = x4[j], Yv = y4[j], Z = z4[j];
      float s = fmaf(X, X, fmaf(Yv, Yv, Z * Z));
      f4 v; v[0] = X; v[1] = Yv; v[2] = Z; v[3] = s;
      pq[t4 * 4 + j] = v;
    }
  }
  __syncthreads();
  // query coefficients (uniform per wave; broadcast LDS reads)
  float qx2[8], qy2[8], qz2[8];
#pragma unroll
  for (int j = 0; j < 8; ++j) {
    f4 Q = pq[qbase + j];
    qx2[j] = Q[0] + Q[0]; qy2[j] = Q[1] + Q[1]; qz2[j] = Q[2] + Q[2];
  }
  // phase A: per-lane max of fast metric over this lane's 128 strided points, x8 queries
  float mx[8];
#pragma unroll
  for (int j = 0; j < 8; ++j) mx[j] = -3.0e38f;
  for (int t = 0; t < 128; ++t) {
    f4 c = pq[(t << 6) + lane];
#pragma unroll
    for (int j = 0; j < 8; ++j) {
      float v = fmaf(qx2[j], c[0], fmaf(qy2[j], c[1], fmaf(qz2[j], c[2], -c[3])));
      mx[j] = fmaxf(mx[j], v);
    }
  }
  // per-query threshold: 20th-largest of the 64 lane-maxima (valid lower bound), minus guard
  float T[8];
#pragma unroll
  for (int j = 0; j < 8; ++j) {
    float sv = mx[j];
#pragma unroll
    for (int k = 2; k <= 64; k <<= 1) {
#pragma unroll
      for (int s = k >> 1; s > 0; s >>= 1) {
        float o = __shfl_xor(sv, s);
        bool takeMin = (((lane & k) == 0) == ((lane & s) == 0));
        sv = takeMin ? fminf(sv, o) : fmaxf(sv, o);
      }
    }
    T[j] = __shfl(sv, 44) - 1e-3f;
  }
  // phase B: collect candidate indices per query
  int cnt[8];
#pragma unroll
  for (int j = 0; j < 8; ++j) cnt[j] = 0;
  for (int t = 0; t < 128; ++t) {
    f4 c = pq[(t << 6) + lane];
#pragma unroll
    for (int j = 0; j < 8; ++j) {
      float v = fmaf(qx2[j], c[0], fmaf(qy2[j], c[1], fmaf(qz2[j], c[2], -c[3])));
      bool pr = (v >= T[j]);
      u64 ball = __ballot(pr);
      if (ball) {
        int ofs = (int)__popcll(ball & ((1ull << lane) - 1ull));
        int pos = cnt[j] + ofs;
        if (pr && pos < 120) cand[w][j][pos] = (t << 6) + lane;
        cnt[j] += (int)__popcll(ball);
      }
    }
  }
  // phase C: f64-exact re-rank per query (matches f64 gold incl. tie-break), 20 argmax rounds
  for (int j = 0; j < 8; ++j) {
    int cn = cnt[j] > 120 ? 120 : cnt[j];
    f4 Q = pq[qbase + j];
    const double Qx = (double)Q[0], Qy = (double)Q[1], Qz = (double)Q[2];
    const double Qs = Qx * Qx + Qy * Qy + Qz * Qz;
    double svv[2]; int sii[2];
#pragma unroll
    for (int jj = 0; jj < 2; ++jj) {
      int e = lane + (jj << 6);
      if (e < cn) {
        int ci = cand[w][j][e];
        f4 c = pq[ci];
        double cx = (double)c[0], cy = (double)c[1], cz = (double)c[2];
        double cs = cx * cx + cy * cy + cz * cz;
        double dot = Qx * cx + Qy * cy + Qz * cz;
        svv[jj] = 2.0 * dot - Qs - cs;
        sii[jj] = ci;
      } else { svv[jj] = -1.0e300; sii[jj] = 0x7FFFFFFF; }
    }
    int* orow = idxOut + (((long)b << 13) + qbase + j) * 20;
    for (int r = 0; r < 20; ++r) {
      double bv = svv[0]; int bi = sii[0];
      bool bet0 = (svv[1] > bv) || (svv[1] == bv && sii[1] < bi);
      if (bet0) { bv = svv[1]; bi = sii[1]; }
#pragma unroll
      for (int s = 1; s < 64; s <<= 1) {
        double ov = __shfl_xor(bv, s);
        int    oi = __shfl_xor(bi, s);
        bool bet = (ov > bv) || (ov == bv && oi < bi);
        if (bet) { bv = ov; bi = oi; }
      }
#pragma unroll
      for (int jj = 0; jj < 2; ++jj)
        if (sii[jj] == bi && svv[jj] == bv) { svv[jj] = -1.0e300; sii[jj] = 0x7FFFFFFF; }
      if (lane == 0) orow[r] = bi;
    }
  }
}

// ---------------- bf16 MFMA GEMM: Y[b][n][o] = sum_k A[o][k]*B[b][n][k] ----------------
// 128x128 tile, 4 waves, BK=32, reg-staged double buffer, mfma_f32_16x16x32_bf16
__global__ __launch_bounds__(256, 2) void k_gemm(
    const u16* __restrict__ A, const u16* __restrict__ Bm, float* __restrict__ Y,
    int M, int K, long strideB, long strideY)
{
  __shared__ u16 sA[2][4096];
  __shared__ u16 sB[2][4096];
  const int b = blockIdx.z;
  const int m0 = blockIdx.y * 128;
  const int n0 = blockIdx.x * 128;
  const u16* Bp = Bm + (long)b * strideB;
  float* Yp = Y + (long)b * strideY;
  const int tid = threadIdx.x, lane = tid & 63, w = tid >> 6;
  const int wr = w >> 1, wc = w & 1;
  const int r15 = lane & 15, g8 = (lane >> 4) * 8;

  f4 acc[4][4];
#pragma unroll
  for (int i = 0; i < 4; ++i)
#pragma unroll
    for (int j = 0; j < 4; ++j) { f4 z = {0.f, 0.f, 0.f, 0.f}; acc[i][j] = z; }

  const int row0 = tid >> 2;
  const int kp0 = (tid & 3) << 3;
  const u16* gA0 = A + (long)(m0 + row0) * K + kp0;
  const u16* gA1 = A + (long)(m0 + row0 + 64) * K + kp0;
  const u16* gB0 = Bp + (long)(n0 + row0) * K + kp0;
  const u16* gB1 = Bp + (long)(n0 + row0 + 64) * K + kp0;
  const int ch0 = tid, ch1 = tid + 256;

  ((i4v*)sA[0])[ch0] = *(const i4v*)gA0;
  ((i4v*)sA[0])[ch1] = *(const i4v*)gA1;
  ((i4v*)sB[0])[ch0] = *(const i4v*)gB0;
  ((i4v*)sB[0])[ch1] = *(const i4v*)gB1;
  __syncthreads();

  const int KT = K >> 5;
  int cur = 0;
  for (int kk = 0; kk < KT; ++kk) {
    i4v ra0, ra1, rb0, rb1;
    const bool more = (kk + 1 < KT);
    if (more) {
      long ko = (long)(kk + 1) * 32;
      ra0 = *(const i4v*)(gA0 + ko); ra1 = *(const i4v*)(gA1 + ko);
      rb0 = *(const i4v*)(gB0 + ko); rb1 = *(const i4v*)(gB1 + ko);
    }
    const u16* la = sA[cur];
    const u16* lb = sB[cur];
    s8 af[4], bfr[4];
#pragma unroll
    for (int mi = 0; mi < 4; ++mi)
      af[mi] = *(const s8*)(la + (wr * 64 + mi * 16 + r15) * 32 + g8);
#pragma unroll
    for (int ni = 0; ni < 4; ++ni)
      bfr[ni] = *(const s8*)(lb + (wc * 64 + ni * 16 + r15) * 32 + g8);
#pragma unroll
    for (int mi = 0; mi < 4; ++mi)
#pragma unroll
      for (int ni = 0; ni < 4; ++ni)
        acc[mi][ni] = __builtin_amdgcn_mfma_f32_16x16x32_bf16(af[mi], bfr[ni], acc[mi][ni], 0, 0, 0);
    if (more) {
      ((i4v*)sA[cur ^ 1])[ch0] = ra0; ((i4v*)sA[cur ^ 1])[ch1] = ra1;
      ((i4v*)sB[cur ^ 1])[ch0] = rb0; ((i4v*)sB[cur ^ 1])[ch1] = rb1;
    }
    __syncthreads();
    cur ^= 1;
  }
  const int og = m0 + wr * 64 + (lane >> 4) * 4;
  const int ng = n0 + wc * 64 + r15;
#pragma unroll
  for (int mi = 0; mi < 4; ++mi)
#pragma unroll
    for (int ni = 0; ni < 4; ++ni)
      *(f4*)(Yp + (long)(ng + ni * 16) * M + og + mi * 16) = acc[mi][ni];
}

// ---------------- per-channel sum/sumsq over rows (Y is [rows][C]) ----------------
__global__ __launch_bounds__(256) void k_colstats(
    const float* __restrict__ Y, float* __restrict__ sums, float* __restrict__ ssq, int C, int RPB)
{
  const int tid = threadIdx.x;
  const int c = tid & (C - 1);
  const int sub = tid / C;
  const int step = 256 / C;
  const int r0 = blockIdx.x * RPB;
  float s = 0.f, qv = 0.f;
  for (int r = r0 + sub; r < r0 + RPB; r += step) {
    float v = Y[(long)r * C + c];
    s += v; qv = fmaf(v, v, qv);
  }
  atomicAdd(&sums[c], s);
  atomicAdd(&ssq[c], qv);
}

__global__ void k_finalize(const float* __restrict__ sums, const float* __restrict__ ssq,
                           const float* __restrict__ g, const float* __restrict__ bt,
                           float* __restrict__ scale, float* __restrict__ shift,
                           int C, float invCount)
{
  int c = threadIdx.x;
  if (c < C) {
    float m = sums[c] * invCount;
    float v = ssq[c] * invCount - m * m;
    float s = g[c] / sqrtf(v + 1e-5f);
    scale[c] = s;
    shift[c] = bt[c] - m * s;
  }
}

// ---------------- normalize + leaky -> bf16 ----------------
__global__ __launch_bounds__(256) void k_apply(
    const float* __restrict__ Y, const float* __restrict__ scale, const float* __restrict__ shift,
    u16* __restrict__ H, int Cmask)
{
  long i = (long)blockIdx.x * 256 + threadIdx.x;
  f4 y = ((const f4*)Y)[i];
  int c0 = (int)((i << 2) & Cmask);
  float r[4];
#pragma unroll
  for (int j = 0; j < 4; ++j) {
    float z = fmaf(scale[c0 + j], y[j], shift[c0 + j]);
    r[j] = z > 0.f ? z : 0.2f * z;
  }
  u32 lo = (u32)f2b(r[0]) | ((u32)f2b(r[1]) << 16);
  u32 hi = (u32)f2b(r[2]) | ((u32)f2b(r[3]) << 16);
  *(uint2*)(H + i * 4) = make_uint2(lo, hi);
}

__global__ __launch_bounds__(256) void k_apply_edge(
    const float* __restrict__ Emax, const float* __restrict__ Emin,
    const float* __restrict__ scale, const float* __restrict__ shift, u16* __restrict__ H)
{
  long i = (long)blockIdx.x * 256 + threadIdx.x;
  f4 a = ((const f4*)Emax)[i];
  f4 bm = ((const f4*)Emin)[i];
  int c0 = (int)((i << 2) & 255);
  float r[4];
#pragma unroll
  for (int j = 0; j < 4; ++j) {
    float s = scale[c0 + j];
    float y = (s >= 0.f) ? a[j] : bm[j];   // max commutes with monotone affine+leaky
    float z = fmaf(s, y, shift[c0 + j]);
    r[j] = z > 0.f ? z : 0.2f * z;
  }
  u32 lo = (u32)f2b(r[0]) | ((u32)f2b(r[1]) << 16);
  u32 hi = (u32)f2b(r[2]) | ((u32)f2b(r[3]) << 16);
  *(uint2*)(H + i * 4) = make_uint2(lo, hi);
}

// ---------------- edgeconv gather: y = Anb[idx] + Cy; track max/min + stats ----------------
__global__ __launch_bounds__(256, 2) void k_edge_gather(
    const float* __restrict__ Y2, const int* __restrict__ idx,
    float* __restrict__ Emax, float* __restrict__ Emin,
    float* __restrict__ sums, float* __restrict__ ssq)
{
  __shared__ float s_sum[256], s_ssq[256];
  const int tid = threadIdx.x, lane = tid & 63, w = tid >> 6;
  s_sum[tid] = 0.f; s_ssq[tid] = 0.f;
  __syncthreads();
  const int ptBase = blockIdx.x * 64;
  f4 lsum = {0.f, 0.f, 0.f, 0.f}, lssq = {0.f, 0.f, 0.f, 0.f};
  for (int i = 0; i < 16; ++i) {
    const int pt = ptBase + w * 16 + i;
    const int b = pt >> 13;
    f4 ctr = *(const f4*)(Y2 + (long)pt * 512 + 256 + (lane << 2));
    const int* irow = idx + (long)pt * 20;
    f4 vmax = {-3.0e38f, -3.0e38f, -3.0e38f, -3.0e38f};
    f4 vmin = {3.0e38f, 3.0e38f, 3.0e38f, 3.0e38f};
#pragma unroll 4
    for (int k = 0; k < 20; ++k) {
      int m = irow[k];
      f4 nb = *(const f4*)(Y2 + (((long)b << 13) + m) * 512 + (lane << 2));
      f4 y = nb + ctr;
#pragma unroll
      for (int j = 0; j < 4; ++j) {
        vmax[j] = fmaxf(vmax[j], y[j]);
        vmin[j] = fminf(vmin[j], y[j]);
        lsum[j] += y[j];
        lssq[j] = fmaf(y[j], y[j], lssq[j]);
      }
    }
    *(f4*)(Emax + (long)pt * 256 + (lane << 2)) = vmax;
    *(f4*)(Emin + (long)pt * 256 + (lane << 2)) = vmin;
  }
#pragma unroll
  for (int j = 0; j < 4; ++j) {
    atomicAdd(&s_sum[(lane << 2) + j], lsum[j]);
    atomicAdd(&s_ssq[(lane << 2) + j], lssq[j]);
  }
  __syncthreads();
  atomicAdd(&sums[tid], s_sum[tid]);
  atomicAdd(&ssq[tid], s_ssq[tid]);
}

// ---------------- final 50x128 GEMM + bias, f32 out (B,50,8192); H4 is bf16 ----------------
__global__ __launch_bounds__(256) void k_final(
    const u16* __restrict__ H4, const float* __restrict__ wf, const float* __restrict__ bf,
    float* __restrict__ out)
{
  __shared__ float swf[4][128];
  __shared__ float sbf[4];
  const int o0 = blockIdx.y * 4;
  const int tid = threadIdx.x;
  if (tid < 128) {
#pragma unroll
    for (int j = 0; j < 4; ++j)
      swf[j][tid] = (o0 + j < 50) ? wf[(o0 + j) * 128 + tid] : 0.f;
  }
  if (tid < 4) sbf[tid] = (o0 + tid < 50) ? bf[o0 + tid] : 0.f;
  __syncthreads();
  const int b = blockIdx.z;
  const int n = blockIdx.x * 256 + tid;
  const u16* h = H4 + (long)(b * 8192 + n) * 128;
  float av[4] = {0.f, 0.f, 0.f, 0.f};
#pragma unroll
  for (int t = 0; t < 16; ++t) {
    i4v raw = *(const i4v*)(h + t * 8);
#pragma unroll
    for (int e = 0; e < 4; ++e) {
      u32 dw = (u32)raw[e];
      float f0 = b2f((u16)(dw & 0xFFFFu));
      float f1 = b2f((u16)(dw >> 16));
      int cc = t * 8 + e * 2;
#pragma unroll
      for (int j = 0; j < 4; ++j) {
        av[j] = fmaf(f0, swf[j][cc], av[j]);
        av[j] = fmaf(f1, swf[j][cc + 1], av[j]);
      }
    }
  }
#pragma unroll
  for (int j = 0; j < 4; ++j) {
    int o = o0 + j;
    if (o < 50) out[(((long)b * 50 + o) << 13) + n] = av[j] + sbf[j];
  }
}

// ---------------- launcher ----------------
extern "C" void kernel_launch(void* const* d_in, const int* in_sizes, int n_in,
                              void* d_out, int out_size, void* d_ws, size_t ws_size,
                              hipStream_t stream)
{
  if ((long)ws_size < WS_NEED) return;
  const float* x   = (const float*)d_in[0];
  const float* p   = (const float*)d_in[1];
  const float* w1  = (const float*)d_in[2];
  const float* g1  = (const float*)d_in[4];
  const float* bt1 = (const float*)d_in[5];
  const float* we  = (const float*)d_in[6];
  const float* ge  = (const float*)d_in[8];
  const float* bte = (const float*)d_in[9];
  const float* w2  = (const float*)d_in[10];
  const float* g2  = (const float*)d_in[12];
  const float* bt2 = (const float*)d_in[13];
  const float* w3  = (const float*)d_in[14];
  const float* g3  = (const float*)d_in[16];
  const float* bt3 = (const float*)d_in[17];
  const float* wf  = (const float*)d_in[18];
  const float* bfi = (const float*)d_in[19];

  char* ws = (char*)d_ws;
  u16* w1b   = (u16*)(ws + OFF_W1B);
  u16* weABb = (u16*)(ws + OFF_WEAB);
  u16* w2b   = (u16*)(ws + OFF_W2B);
  u16* w3b   = (u16*)(ws + OFF_W3B);
  int* idxb  = (int*)(ws + OFF_IDX);
  u16*   XT   = (u16*)(ws + OFF_XT);
  float* Y1   = (float*)(ws + OFF_Y1);
  u16*   H1   = (u16*)(ws + OFF_H1);
  float* Y2   = (float*)(ws + OFF_Y2);
  float* EMAX = (float*)(ws + OFF_EMAX);
  float* EMIN = (float*)(ws + OFF_EMIN);
  u16*   H2   = (u16*)(ws + OFF_H2);
  float* Y3   = (float*)(ws + OFF_Y3);
  u16*   H3   = (u16*)(ws + OFF_H3);
  float* Y4   = (float*)(ws + OFF_Y4);
  u16*   H4   = (u16*)(ws + OFF_H4);
  float* st0 = (float*)(ws + OFF_STATS);
  float* st1 = (float*)(ws + OFF_STATS + 4096);
  float* st2 = (float*)(ws + OFF_STATS + 8192);
  float* st3 = (float*)(ws + OFF_STATS + 12288);

  hipMemsetAsync(ws + OFF_STATS, 0, 16384, stream);
  k_convw<<<2112, 256, 0, stream>>>(w1, we, w2, w3, w1b, weABb, w2b, w3b);
  k_knn<<<256, 512, 0, stream>>>(p, idxb);
  k_xt<<<dim3(128, 19, 2), 256, 0, stream>>>(x, XT);

  // stage 1: smlp1d(x, w1)
  k_gemm<<<dim3(64, 2, 2), 256, 0, stream>>>(w1b, XT, Y1, 256, 1216, (long)8192 * 1216, (long)8192 * 256);
  k_colstats<<<256, 256, 0, stream>>>(Y1, st0, st0 + 256, 256, 64);
  k_finalize<<<1, 256, 0, stream>>>(st0, st0 + 256, g1, bt1, st0 + 512, st0 + 768, 256, 1.0f / 16384.0f);
  k_apply<<<4096, 256, 0, stream>>>(Y1, st0 + 512, st0 + 768, H1, 255);

  // edgeconv: [Anb | Cy] GEMM, gather+max/min+stats, apply
  k_gemm<<<dim3(64, 4, 2), 256, 0, stream>>>(weABb, H1, Y2, 512, 256, (long)8192 * 256, (long)8192 * 512);
  k_edge_gather<<<256, 256, 0, stream>>>(Y2, idxb, EMAX, EMIN, st1, st1 + 256);
  k_finalize<<<1, 256, 0, stream>>>(st1, st1 + 256, ge, bte, st1 + 512, st1 + 768, 256, 1.0f / 327680.0f);
  k_apply_edge<<<4096, 256, 0, stream>>>(EMAX, EMIN, st1 + 512, st1 + 768, H2);

  // stage 2: smlp1d(h, w2)
  k_gemm<<<dim3(64, 2, 2), 256, 0, stream>>>(w2b, H2, Y3, 256, 256, (long)8192 * 256, (long)8192 * 256);
  k_colstats<<<256, 256, 0, stream>>>(Y3, st2, st2 + 256, 256, 64);
  k_finalize<<<1, 256, 0, stream>>>(st2, st2 + 256, g2, bt2, st2 + 512, st2 + 768, 256, 1.0f / 16384.0f);
  k_apply<<<4096, 256, 0, stream>>>(Y3, st2 + 512, st2 + 768, H3, 255);

  // stage 3: smlp1d(h, w3)
  k_gemm<<<dim3(64, 1, 2), 256, 0, stream>>>(w3b, H3, Y4, 128, 256, (long)8192 * 256, (long)8192 * 128);
  k_colstats<<<128, 256, 0, stream>>>(Y4, st3, st3 + 256, 128, 128);
  k_finalize<<<1, 256, 0, stream>>>(st3, st3 + 256, g3, bt3, st3 + 512, st3 + 768, 128, 1.0f / 16384.0f);
  k_apply<<<2048, 256, 0, stream>>>(Y4, st3 + 512, st3 + 768, H4, 127);

  // final projection
  k_final<<<dim3(32, 13, 2), 256, 0, stream>>>(H4, wf, bfi, (float*)d_out);
}

// Round 7
// 366.841 us; speedup vs baseline: 2.2835x; 1.2337x over previous
//
#include <hip/hip_runtime.h>

typedef unsigned short u16;
typedef unsigned int   u32;
typedef unsigned long long u64;
typedef __attribute__((ext_vector_type(4))) float f4;
typedef __attribute__((ext_vector_type(8))) short s8;
typedef __attribute__((ext_vector_type(4))) int   i4v;

#define DEV __device__ __forceinline__

DEV u16 f2b(float f) {
  u32 u = __float_as_uint(f);
  return (u16)((u + 0x7FFFu + ((u >> 16) & 1u)) >> 16);
}
DEV float b2f(u16 h) { return __uint_as_float(((u32)h) << 16); }

// ---------------- workspace layout (bytes) ----------------
#define OFF_STATS 0L
#define OFF_W1B   65536L
#define OFF_WEAB  688128L
#define OFF_W2B   950272L
#define OFF_W3B   1081344L
#define OFF_IDX   1146880L
#define OFF_XT    4194304L      /* 38 MiB, dead after GEMM1 */
#define OFF_Y1    44040192L     /* 16 MiB */
#define OFF_H1    60817408L     /* 8 MiB bf16 */
#define OFF_Y2    4194304L      /* 32 MiB over dead XT */
#define OFF_EMAX  37748736L     /* 16 MiB over dead XT tail + Y1 */
#define OFF_EMIN  54525952L     /* 16 MiB over dead Y1 tail + H1 */
#define OFF_H2    4194304L      /* 8 MiB over dead Y2 head */
#define OFF_Y3    12582912L     /* 16 MiB */
#define OFF_H3    29360128L     /* 8 MiB */
#define OFF_Y4    37748736L     /* 8 MiB over dead EMAX */
#define OFF_H4    46137344L     /* 4 MiB */
#define WS_NEED   71303168L

// ---------------- weight convert -> bf16 (w1 | weA,weB-weA | w2 | w3) ----------------
__global__ __launch_bounds__(256) void k_convw(
    const float* __restrict__ w1, const float* __restrict__ we,
    const float* __restrict__ w2, const float* __restrict__ w3,
    u16* __restrict__ w1b, u16* __restrict__ weABb,
    u16* __restrict__ w2b, u16* __restrict__ w3b)
{
  int i = blockIdx.x * 256 + threadIdx.x;
  if (i < 311296) { w1b[i] = f2b(w1[i]); return; }
  i -= 311296;
  if (i < 131072) {
    int o = i >> 8, c = i & 255;
    float v = (o < 256) ? we[o * 512 + c]
                        : we[(o - 256) * 512 + 256 + c] - we[(o - 256) * 512 + c];
    weABb[i] = f2b(v); return;
  }
  i -= 131072;
  if (i < 65536) { w2b[i] = f2b(w2[i]); return; }
  i -= 65536;
  if (i < 32768) { w3b[i] = f2b(w3[i]); }
}

// ---------------- x transpose + bf16: (B,1216,8192)f32 -> (B,8192,1216)bf16 ----------------
__global__ __launch_bounds__(256) void k_xt(const float* __restrict__ x, u16* __restrict__ xt)
{
  __shared__ float t[64][65];
  const int b = blockIdx.z, ct = blockIdx.y, nt = blockIdx.x;
  const int tx = threadIdx.x & 63, ty = threadIdx.x >> 6;
  const float* xb = x + (long)b * 1216 * 8192;
#pragma unroll
  for (int i = 0; i < 16; ++i) {
    int c = ct * 64 + ty + i * 4;
    t[ty + i * 4][tx] = xb[(long)c * 8192 + nt * 64 + tx];
  }
  __syncthreads();
  u16* xtb = xt + (long)b * 8192 * 1216;
#pragma unroll
  for (int i = 0; i < 16; ++i) {
    int n = nt * 64 + ty + i * 4;
    xtb[(long)n * 1216 + ct * 64 + tx] = f2b(t[tx][ty + i * 4]);
  }
}

// ---------------- exact KNN top-20, 8 queries/wave; rank-based f64 re-rank (no shuffles) ----------------
// 256 blocks x 512 thr. Block = 64 queries (8 waves x 8). All 8192 points staged in LDS once.
__global__ __launch_bounds__(512, 1) void k_knn(const float* __restrict__ p, int* __restrict__ idxOut)
{
  __shared__ f4 pq[8192];                       // 128 KB: (x,y,z,|c|^2)
  __shared__ u16 cand[8][8][120];               // 15 KB: per (wave, query) candidate idx
  __shared__ __align__(16) double ckey[8][120][2];  // 15 KB: per-wave (value, idx) stage
  const int tid = threadIdx.x, lane = tid & 63, w = tid >> 6;
  const int blk = blockIdx.x;
  const int b = blk >> 7;
  const int qbase = ((blk & 127) << 6) + (w << 3);
  const float* px = p + (long)b * 24576;
  const float* py = px + 8192;
  const float* pz = px + 16384;
  for (int t4 = tid; t4 < 2048; t4 += 512) {
    f4 x4 = *(const f4*)(px + t4 * 4);
    f4 y4 = *(const f4*)(py + t4 * 4);
    f4 z4 = *(const f4*)(pz + t4 * 4);
#pragma unroll
    for (int j = 0; j < 4; ++j) {
      float X = x4[j], Yv = y4[j], Z = z4[j];
      float s = fmaf(X, X, fmaf(Yv, Yv, Z * Z));
      f4 v; v[0] = X; v[1] = Yv; v[2] = Z; v[3] = s;
      pq[t4 * 4 + j] = v;
    }
  }
  __syncthreads();
  // query coefficients (uniform per wave)
  float qx2[8], qy2[8], qz2[8];
#pragma unroll
  for (int j = 0; j < 8; ++j) {
    f4 Q = pq[qbase + j];
    qx2[j] = Q[0] + Q[0]; qy2[j] = Q[1] + Q[1]; qz2[j] = Q[2] + Q[2];
  }
  // phase A: per-lane max of fast metric over this lane's 128 strided points, x8 queries
  float mx[8];
#pragma unroll
  for (int j = 0; j < 8; ++j) mx[j] = -3.0e38f;
#pragma unroll 2
  for (int t = 0; t < 128; ++t) {
    f4 c = pq[(t << 6) + lane];
#pragma unroll
    for (int j = 0; j < 8; ++j) {
      float v = fmaf(qx2[j], c[0], fmaf(qy2[j], c[1], fmaf(qz2[j], c[2], -c[3])));
      mx[j] = fmaxf(mx[j], v);
    }
  }
  // per-query threshold: 20th-largest of the 64 lane-maxima (provable lower bound), minus guard
  float T[8];
#pragma unroll
  for (int j = 0; j < 8; ++j) {
    float sv = mx[j];
#pragma unroll
    for (int k = 2; k <= 64; k <<= 1) {
#pragma unroll
      for (int s = k >> 1; s > 0; s >>= 1) {
        float o = __shfl_xor(sv, s);
        bool takeMin = (((lane & k) == 0) == ((lane & s) == 0));
        sv = takeMin ? fminf(sv, o) : fmaxf(sv, o);
      }
    }
    T[j] = __shfl(sv, 44) - 1e-3f;
  }
  // phase B: ballot-compact candidate indices per query (deterministic order)
  int cnt[8];
#pragma unroll
  for (int j = 0; j < 8; ++j) cnt[j] = 0;
#pragma unroll 2
  for (int t = 0; t < 128; ++t) {
    f4 c = pq[(t << 6) + lane];
#pragma unroll
    for (int j = 0; j < 8; ++j) {
      float v = fmaf(qx2[j], c[0], fmaf(qy2[j], c[1], fmaf(qz2[j], c[2], -c[3])));
      bool pr = (v >= T[j]);
      u64 ball = __ballot(pr);
      if (ball) {
        int ofs = (int)__popcll(ball & ((1ull << lane) - 1ull));
        int pos = cnt[j] + ofs;
        if (pr && pos < 120) cand[w][j][pos] = (u16)((t << 6) + lane);
        cnt[j] += (int)__popcll(ball);
      }
    }
  }
  asm volatile("s_waitcnt lgkmcnt(0)" ::: "memory");
  // phase C: f64-exact rank-based selection (matches f64 gold incl. (v desc, idx asc) ties)
  for (int j = 0; j < 8; ++j) {
    const int cn = cnt[j] > 120 ? 120 : cnt[j];
    f4 Q = pq[qbase + j];
    const double Qx = (double)Q[0], Qy = (double)Q[1], Qz = (double)Q[2];
    const double Qs = Qx * Qx + Qy * Qy + Qz * Qz;
    double myV[2]; int myI[2];
#pragma unroll
    for (int jj = 0; jj < 2; ++jj) {
      const int e = lane + (jj << 6);
      myV[jj] = -1.0e300; myI[jj] = 0x7FFFFFFF;
      if (e < cn) {
        const int ci = cand[w][j][e];
        f4 c = pq[ci];
        double cx = (double)c[0], cy = (double)c[1], cz = (double)c[2];
        double v = 2.0 * (Qx * cx + Qy * cy + Qz * cz) - Qs - (cx * cx + cy * cy + cz * cz);
        myV[jj] = v; myI[jj] = ci;
        *(double2*)&ckey[w][e][0] = make_double2(v, (double)ci);
      }
    }
    asm volatile("s_waitcnt lgkmcnt(0)" ::: "memory");
    int rk0 = 0, rk1 = 0;
    const double myI0 = (double)myI[0], myI1 = (double)myI[1];
    for (int e2 = 0; e2 < cn; ++e2) {
      double2 o = *(const double2*)&ckey[w][e2][0];   // broadcast read
      rk0 += ((o.x > myV[0]) || (o.x == myV[0] && o.y < myI0)) ? 1 : 0;
      rk1 += ((o.x > myV[1]) || (o.x == myV[1] && o.y < myI1)) ? 1 : 0;
    }
    int* orow = idxOut + (((long)b << 13) + qbase + j) * 20;
    if (lane < cn && rk0 < 20) orow[rk0] = myI[0];
    if (lane + 64 < cn && rk1 < 20) orow[rk1] = myI[1];
    asm volatile("s_waitcnt lgkmcnt(0)" ::: "memory");
  }
}

// ---------------- bf16 MFMA GEMM: Y[b][n][o] = sum_k A[o][k]*B[b][n][k] ----------------
__global__ __launch_bounds__(256, 2) void k_gemm(
    const u16* __restrict__ A, const u16* __restrict__ Bm, float* __restrict__ Y,
    int M, int K, long strideB, long strideY)
{
  __shared__ u16 sA[2][4096];
  __shared__ u16 sB[2][4096];
  const int b = blockIdx.z;
  const int m0 = blockIdx.y * 128;
  const int n0 = blockIdx.x * 128;
  const u16* Bp = Bm + (long)b * strideB;
  float* Yp = Y + (long)b * strideY;
  const int tid = threadIdx.x, lane = tid & 63, w = tid >> 6;
  const int wr = w >> 1, wc = w & 1;
  const int r15 = lane & 15, g8 = (lane >> 4) * 8;

  f4 acc[4][4];
#pragma unroll
  for (int i = 0; i < 4; ++i)
#pragma unroll
    for (int j = 0; j < 4; ++j) { f4 z = {0.f, 0.f, 0.f, 0.f}; acc[i][j] = z; }

  const int row0 = tid >> 2;
  const int kp0 = (tid & 3) << 3;
  const u16* gA0 = A + (long)(m0 + row0) * K + kp0;
  const u16* gA1 = A + (long)(m0 + row0 + 64) * K + kp0;
  const u16* gB0 = Bp + (long)(n0 + row0) * K + kp0;
  const u16* gB1 = Bp + (long)(n0 + row0 + 64) * K + kp0;
  const int ch0 = tid, ch1 = tid + 256;

  ((i4v*)sA[0])[ch0] = *(const i4v*)gA0;
  ((i4v*)sA[0])[ch1] = *(const i4v*)gA1;
  ((i4v*)sB[0])[ch0] = *(const i4v*)gB0;
  ((i4v*)sB[0])[ch1] = *(const i4v*)gB1;
  __syncthreads();

  const int KT = K >> 5;
  int cur = 0;
  for (int kk = 0; kk < KT; ++kk) {
    i4v ra0, ra1, rb0, rb1;
    const bool more = (kk + 1 < KT);
    if (more) {
      long ko = (long)(kk + 1) * 32;
      ra0 = *(const i4v*)(gA0 + ko); ra1 = *(const i4v*)(gA1 + ko);
      rb0 = *(const i4v*)(gB0 + ko); rb1 = *(const i4v*)(gB1 + ko);
    }
    const u16* la = sA[cur];
    const u16* lb = sB[cur];
    s8 af[4], bfr[4];
#pragma unroll
    for (int mi = 0; mi < 4; ++mi)
      af[mi] = *(const s8*)(la + (wr * 64 + mi * 16 + r15) * 32 + g8);
#pragma unroll
    for (int ni = 0; ni < 4; ++ni)
      bfr[ni] = *(const s8*)(lb + (wc * 64 + ni * 16 + r15) * 32 + g8);
#pragma unroll
    for (int mi = 0; mi < 4; ++mi)
#pragma unroll
      for (int ni = 0; ni < 4; ++ni)
        acc[mi][ni] = __builtin_amdgcn_mfma_f32_16x16x32_bf16(af[mi], bfr[ni], acc[mi][ni], 0, 0, 0);
    if (more) {
      ((i4v*)sA[cur ^ 1])[ch0] = ra0; ((i4v*)sA[cur ^ 1])[ch1] = ra1;
      ((i4v*)sB[cur ^ 1])[ch0] = rb0; ((i4v*)sB[cur ^ 1])[ch1] = rb1;
    }
    __syncthreads();
    cur ^= 1;
  }
  const int og = m0 + wr * 64 + (lane >> 4) * 4;
  const int ng = n0 + wc * 64 + r15;
#pragma unroll
  for (int mi = 0; mi < 4; ++mi)
#pragma unroll
    for (int ni = 0; ni < 4; ++ni)
      *(f4*)(Yp + (long)(ng + ni * 16) * M + og + mi * 16) = acc[mi][ni];
}

// ---------------- per-channel sum/sumsq over rows (Y is [rows][C]) ----------------
__global__ __launch_bounds__(256) void k_colstats(
    const float* __restrict__ Y, float* __restrict__ sums, float* __restrict__ ssq, int C, int RPB)
{
  const int tid = threadIdx.x;
  const int c = tid & (C - 1);
  const int sub = tid / C;
  const int step = 256 / C;
  const int r0 = blockIdx.x * RPB;
  float s = 0.f, qv = 0.f;
  for (int r = r0 + sub; r < r0 + RPB; r += step) {
    float v = Y[(long)r * C + c];
    s += v; qv = fmaf(v, v, qv);
  }
  atomicAdd(&sums[c], s);
  atomicAdd(&ssq[c], qv);
}

// ---------------- normalize + leaky -> bf16 (finalize fused per-block) ----------------
__global__ __launch_bounds__(256) void k_apply(
    const float* __restrict__ Y, const float* __restrict__ sums, const float* __restrict__ ssq,
    const float* __restrict__ g, const float* __restrict__ bt,
    u16* __restrict__ H, int Cmask, float invCount)
{
  __shared__ float sc[256], sh[256];
  const int tid = threadIdx.x;
  {
    int c = tid & Cmask;
    float m = sums[c] * invCount;
    float v = ssq[c] * invCount - m * m;
    float s = g[c] / sqrtf(v + 1e-5f);
    sc[tid] = s;
    sh[tid] = bt[c] - m * s;
  }
  __syncthreads();
  long i = (long)blockIdx.x * 256 + tid;
  f4 y = ((const f4*)Y)[i];
  int c0 = (int)((i << 2) & Cmask);
  float r[4];
#pragma unroll
  for (int j = 0; j < 4; ++j) {
    float z = fmaf(sc[c0 + j], y[j], sh[c0 + j]);
    r[j] = z > 0.f ? z : 0.2f * z;
  }
  u32 lo = (u32)f2b(r[0]) | ((u32)f2b(r[1]) << 16);
  u32 hi = (u32)f2b(r[2]) | ((u32)f2b(r[3]) << 16);
  *(uint2*)(H + i * 4) = make_uint2(lo, hi);
}

__global__ __launch_bounds__(256) void k_apply_edge(
    const float* __restrict__ Emax, const float* __restrict__ Emin,
    const float* __restrict__ sums, const float* __restrict__ ssq,
    const float* __restrict__ g, const float* __restrict__ bt,
    u16* __restrict__ H, float invCount)
{
  __shared__ float sc[256], sh[256];
  const int tid = threadIdx.x;
  {
    float m = sums[tid] * invCount;
    float v = ssq[tid] * invCount - m * m;
    float s = g[tid] / sqrtf(v + 1e-5f);
    sc[tid] = s;
    sh[tid] = bt[tid] - m * s;
  }
  __syncthreads();
  long i = (long)blockIdx.x * 256 + tid;
  f4 a = ((const f4*)Emax)[i];
  f4 bm = ((const f4*)Emin)[i];
  int c0 = (int)((i << 2) & 255);
  float r[4];
#pragma unroll
  for (int j = 0; j < 4; ++j) {
    float s = sc[c0 + j];
    float y = (s >= 0.f) ? a[j] : bm[j];   // max commutes with monotone affine+leaky
    float z = fmaf(s, y, sh[c0 + j]);
    r[j] = z > 0.f ? z : 0.2f * z;
  }
  u32 lo = (u32)f2b(r[0]) | ((u32)f2b(r[1]) << 16);
  u32 hi = (u32)f2b(r[2]) | ((u32)f2b(r[3]) << 16);
  *(uint2*)(H + i * 4) = make_uint2(lo, hi);
}

// ---------------- edgeconv gather: y = Anb[idx] + Cy; track max/min + stats ----------------
__global__ __launch_bounds__(256, 2) void k_edge_gather(
    const float* __restrict__ Y2, const int* __restrict__ idx,
    float* __restrict__ Emax, float* __restrict__ Emin,
    float* __restrict__ sums, float* __restrict__ ssq)
{
  __shared__ float s_sum[256], s_ssq[256];
  const int tid = threadIdx.x, lane = tid & 63, w = tid >> 6;
  s_sum[tid] = 0.f; s_ssq[tid] = 0.f;
  __syncthreads();
  const int ptBase = blockIdx.x * 64;
  f4 lsum = {0.f, 0.f, 0.f, 0.f}, lssq = {0.f, 0.f, 0.f, 0.f};
  for (int i = 0; i < 16; ++i) {
    const int pt = ptBase + w * 16 + i;
    const int b = pt >> 13;
    f4 ctr = *(const f4*)(Y2 + (long)pt * 512 + 256 + (lane << 2));
    const int* irow = idx + (long)pt * 20;
    f4 vmax = {-3.0e38f, -3.0e38f, -3.0e38f, -3.0e38f};
    f4 vmin = {3.0e38f, 3.0e38f, 3.0e38f, 3.0e38f};
#pragma unroll 4
    for (int k = 0; k < 20; ++k) {
      int m = irow[k];
      f4 nb = *(const f4*)(Y2 + (((long)b << 13) + m) * 512 + (lane << 2));
      f4 y = nb + ctr;
#pragma unroll
      for (int j = 0; j < 4; ++j) {
        vmax[j] = fmaxf(vmax[j], y[j]);
        vmin[j] = fminf(vmin[j], y[j]);
        lsum[j] += y[j];
        lssq[j] = fmaf(y[j], y[j], lssq[j]);
      }
    }
    *(f4*)(Emax + (long)pt * 256 + (lane << 2)) = vmax;
    *(f4*)(Emin + (long)pt * 256 + (lane << 2)) = vmin;
  }
#pragma unroll
  for (int j = 0; j < 4; ++j) {
    atomicAdd(&s_sum[(lane << 2) + j], lsum[j]);
    atomicAdd(&s_ssq[(lane << 2) + j], lssq[j]);
  }
  __syncthreads();
  atomicAdd(&sums[tid], s_sum[tid]);
  atomicAdd(&ssq[tid], s_ssq[tid]);
}

// ---------------- final 50x128 GEMM + bias, f32 out (B,50,8192); H4 is bf16 ----------------
__global__ __launch_bounds__(256) void k_final(
    const u16* __restrict__ H4, const float* __restrict__ wf, const float* __restrict__ bf,
    float* __restrict__ out)
{
  __shared__ float swf[4][128];
  __shared__ float sbf[4];
  const int o0 = blockIdx.y * 4;
  const int tid = threadIdx.x;
  if (tid < 128) {
#pragma unroll
    for (int j = 0; j < 4; ++j)
      swf[j][tid] = (o0 + j < 50) ? wf[(o0 + j) * 128 + tid] : 0.f;
  }
  if (tid < 4) sbf[tid] = (o0 + tid < 50) ? bf[o0 + tid] : 0.f;
  __syncthreads();
  const int b = blockIdx.z;
  const int n = blockIdx.x * 256 + tid;
  const u16* h = H4 + (long)(b * 8192 + n) * 128;
  float av[4] = {0.f, 0.f, 0.f, 0.f};
#pragma unroll
  for (int t = 0; t < 16; ++t) {
    i4v raw = *(const i4v*)(h + t * 8);
#pragma unroll
    for (int e = 0; e < 4; ++e) {
      u32 dw = (u32)raw[e];
      float f0 = b2f((u16)(dw & 0xFFFFu));
      float f1 = b2f((u16)(dw >> 16));
      int cc = t * 8 + e * 2;
#pragma unroll
      for (int j = 0; j < 4; ++j) {
        av[j] = fmaf(f0, swf[j][cc], av[j]);
        av[j] = fmaf(f1, swf[j][cc + 1], av[j]);
      }
    }
  }
#pragma unroll
  for (int j = 0; j < 4; ++j) {
    int o = o0 + j;
    if (o < 50) out[(((long)b * 50 + o) << 13) + n] = av[j] + sbf[j];
  }
}

// ---------------- launcher ----------------
extern "C" void kernel_launch(void* const* d_in, const int* in_sizes, int n_in,
                              void* d_out, int out_size, void* d_ws, size_t ws_size,
                              hipStream_t stream)
{
  if ((long)ws_size < WS_NEED) return;
  const float* x   = (const float*)d_in[0];
  const float* p   = (const float*)d_in[1];
  const float* w1  = (const float*)d_in[2];
  const float* g1  = (const float*)d_in[4];
  const float* bt1 = (const float*)d_in[5];
  const float* we  = (const float*)d_in[6];
  const float* ge  = (const float*)d_in[8];
  const float* bte = (const float*)d_in[9];
  const float* w2  = (const float*)d_in[10];
  const float* g2  = (const float*)d_in[12];
  const float* bt2 = (const float*)d_in[13];
  const float* w3  = (const float*)d_in[14];
  const float* g3  = (const float*)d_in[16];
  const float* bt3 = (const float*)d_in[17];
  const float* wf  = (const float*)d_in[18];
  const float* bfi = (const float*)d_in[19];

  char* ws = (char*)d_ws;
  u16* w1b   = (u16*)(ws + OFF_W1B);
  u16* weABb = (u16*)(ws + OFF_WEAB);
  u16* w2b   = (u16*)(ws + OFF_W2B);
  u16* w3b   = (u16*)(ws + OFF_W3B);
  int* idxb  = (int*)(ws + OFF_IDX);
  u16*   XT   = (u16*)(ws + OFF_XT);
  float* Y1   = (float*)(ws + OFF_Y1);
  u16*   H1   = (u16*)(ws + OFF_H1);
  float* Y2   = (float*)(ws + OFF_Y2);
  float* EMAX = (float*)(ws + OFF_EMAX);
  float* EMIN = (float*)(ws + OFF_EMIN);
  u16*   H2   = (u16*)(ws + OFF_H2);
  float* Y3   = (float*)(ws + OFF_Y3);
  u16*   H3   = (u16*)(ws + OFF_H3);
  float* Y4   = (float*)(ws + OFF_Y4);
  u16*   H4   = (u16*)(ws + OFF_H4);
  float* st0 = (float*)(ws + OFF_STATS);
  float* st1 = (float*)(ws + OFF_STATS + 4096);
  float* st2 = (float*)(ws + OFF_STATS + 8192);
  float* st3 = (float*)(ws + OFF_STATS + 12288);

  hipMemsetAsync(ws + OFF_STATS, 0, 16384, stream);
  k_convw<<<2112, 256, 0, stream>>>(w1, we, w2, w3, w1b, weABb, w2b, w3b);
  k_knn<<<256, 512, 0, stream>>>(p, idxb);
  k_xt<<<dim3(128, 19, 2), 256, 0, stream>>>(x, XT);

  // stage 1: smlp1d(x, w1)
  k_gemm<<<dim3(64, 2, 2), 256, 0, stream>>>(w1b, XT, Y1, 256, 1216, (long)8192 * 1216, (long)8192 * 256);
  k_colstats<<<256, 256, 0, stream>>>(Y1, st0, st0 + 256, 256, 64);
  k_apply<<<4096, 256, 0, stream>>>(Y1, st0, st0 + 256, g1, bt1, H1, 255, 1.0f / 16384.0f);

  // edgeconv: [Anb | Cy] GEMM, gather+max/min+stats, apply
  k_gemm<<<dim3(64, 4, 2), 256, 0, stream>>>(weABb, H1, Y2, 512, 256, (long)8192 * 256, (long)8192 * 512);
  k_edge_gather<<<256, 256, 0, stream>>>(Y2, idxb, EMAX, EMIN, st1, st1 + 256);
  k_apply_edge<<<4096, 256, 0, stream>>>(EMAX, EMIN, st1, st1 + 256, ge, bte, H2, 1.0f / 327680.0f);

  // stage 2: smlp1d(h, w2)
  k_gemm<<<dim3(64, 2, 2), 256, 0, stream>>>(w2b, H2, Y3, 256, 256, (long)8192 * 256, (long)8192 * 256);
  k_colstats<<<256, 256, 0, stream>>>(Y3, st2, st2 + 256, 256, 64);
  k_apply<<<4096, 256, 0, stream>>>(Y3, st2, st2 + 256, g2, bt2, H3, 255, 1.0f / 16384.0f);

  // stage 3: smlp1d(h, w3)
  k_gemm<<<dim3(64, 1, 2), 256, 0, stream>>>(w3b, H3, Y4, 128, 256, (long)8192 * 256, (long)8192 * 128);
  k_colstats<<<128, 256, 0, stream>>>(Y4, st3, st3 + 256, 128, 128);
  k_apply<<<2048, 256, 0, stream>>>(Y4, st3, st3 + 256, g3, bt3, H4, 127, 1.0f / 16384.0f);

  // final projection
  k_final<<<dim3(32, 13, 2), 256, 0, stream>>>(H4, wf, bfi, (float*)d_out);
}

// Round 8
// 363.067 us; speedup vs baseline: 2.3073x; 1.0104x over previous
//
#include <hip/hip_runtime.h>

typedef unsigned short u16;
typedef unsigned int   u32;
typedef unsigned long long u64;
typedef __attribute__((ext_vector_type(4))) float f4;
typedef __attribute__((ext_vector_type(8))) short s8;
typedef __attribute__((ext_vector_type(4))) int   i4v;
typedef __attribute__((ext_vector_type(4))) unsigned short u16x4;

#define DEV __device__ __forceinline__

DEV u16 f2b(float f) {
  u32 u = __float_as_uint(f);
  return (u16)((u + 0x7FFFu + ((u >> 16) & 1u)) >> 16);
}
DEV float b2f(u16 h) { return __uint_as_float(((u32)h) << 16); }

// ---------------- workspace layout (bytes) ----------------
#define OFF_STATS 0L
#define OFF_W1B   65536L
#define OFF_WEAB  688128L
#define OFF_W2B   950272L
#define OFF_W3B   1081344L
#define OFF_IDX   1146880L
#define OFF_XT    4194304L      /* 38 MiB, dead after GEMM1 */
#define OFF_Y1    44040192L     /* 16 MiB f32 */
#define OFF_H1    60817408L     /* 8 MiB bf16 */
#define OFF_Y2    4194304L      /* 16 MiB bf16 over dead XT head */
#define OFF_EMAX  20971520L     /* 16 MiB f32 over dead XT */
#define OFF_EMIN  37748736L     /* 16 MiB f32 over dead XT tail + dead Y1 head */
#define OFF_H2    54525952L     /* 8 MiB bf16 over dead Y1 tail + dead H1 head */
#define OFF_Y3    4194304L      /* 16 MiB f32 over dead Y2 */
#define OFF_H3    20971520L     /* 8 MiB over dead EMAX */
#define OFF_Y4    29360128L     /* 8 MiB over dead EMAX tail */
#define OFF_H4    37748736L     /* 4 MiB over dead EMIN */
#define WS_NEED   71303168L

// ---------------- weight convert -> bf16 (w1 | weA,weB-weA | w2 | w3) ----------------
__global__ __launch_bounds__(256) void k_convw(
    const float* __restrict__ w1, const float* __restrict__ we,
    const float* __restrict__ w2, const float* __restrict__ w3,
    u16* __restrict__ w1b, u16* __restrict__ weABb,
    u16* __restrict__ w2b, u16* __restrict__ w3b)
{
  int i = blockIdx.x * 256 + threadIdx.x;
  if (i < 311296) { w1b[i] = f2b(w1[i]); return; }
  i -= 311296;
  if (i < 131072) {
    int o = i >> 8, c = i & 255;
    float v = (o < 256) ? we[o * 512 + c]
                        : we[(o - 256) * 512 + 256 + c] - we[(o - 256) * 512 + c];
    weABb[i] = f2b(v); return;
  }
  i -= 131072;
  if (i < 65536) { w2b[i] = f2b(w2[i]); return; }
  i -= 65536;
  if (i < 32768) { w3b[i] = f2b(w3[i]); }
}

// ---------------- x transpose + bf16: (B,1216,8192)f32 -> (B,8192,1216)bf16 ----------------
__global__ __launch_bounds__(256) void k_xt(const float* __restrict__ x, u16* __restrict__ xt)
{
  __shared__ float t[64][65];
  const int b = blockIdx.z, ct = blockIdx.y, nt = blockIdx.x;
  const int tx = threadIdx.x & 63, ty = threadIdx.x >> 6;
  const float* xb = x + (long)b * 1216 * 8192;
#pragma unroll
  for (int i = 0; i < 16; ++i) {
    int c = ct * 64 + ty + i * 4;
    t[ty + i * 4][tx] = xb[(long)c * 8192 + nt * 64 + tx];
  }
  __syncthreads();
  u16* xtb = xt + (long)b * 8192 * 1216;
#pragma unroll
  for (int i = 0; i < 16; ++i) {
    int n = nt * 64 + ty + i * 4;
    xtb[(long)n * 1216 + ct * 64 + tx] = f2b(t[tx][ty + i * 4]);
  }
}

// ---------------- exact KNN top-20, 8 queries/wave; rank-based f64 re-rank ----------------
__global__ __launch_bounds__(512, 1) void k_knn(const float* __restrict__ p, int* __restrict__ idxOut)
{
  __shared__ f4 pq[8192];                 // 128 KB: (x,y,z,|c|^2)
  __shared__ u16 cand[8][8][120];         // 15 KB
  __shared__ double ckeyv[8][120];        // 7.5 KB: exact values, idx lives in cand
  const int tid = threadIdx.x, lane = tid & 63, w = tid >> 6;
  const int blk = blockIdx.x;
  const int b = blk >> 7;
  const int qbase = ((blk & 127) << 6) + (w << 3);
  const float* px = p + (long)b * 24576;
  const float* py = px + 8192;
  const float* pz = px + 16384;
  for (int t4 = tid; t4 < 2048; t4 += 512) {
    f4 x4 = *(const f4*)(px + t4 * 4);
    f4 y4 = *(const f4*)(py + t4 * 4);
    f4 z4 = *(const f4*)(pz + t4 * 4);
#pragma unroll
    for (int j = 0; j < 4; ++j) {
      float X = x4[j], Yv = y4[j], Z = z4[j];
      float s = fmaf(X, X, fmaf(Yv, Yv, Z * Z));
      f4 v; v[0] = X; v[1] = Yv; v[2] = Z; v[3] = s;
      pq[t4 * 4 + j] = v;
    }
  }
  __syncthreads();
  float qx2[8], qy2[8], qz2[8];
#pragma unroll
  for (int j = 0; j < 8; ++j) {
    f4 Q = pq[qbase + j];
    qx2[j] = Q[0] + Q[0]; qy2[j] = Q[1] + Q[1]; qz2[j] = Q[2] + Q[2];
  }
  // phase A: per-lane max over 128 strided points x 8 queries (unroll 4 -> 4 b128 in flight)
  float mx[8];
#pragma unroll
  for (int j = 0; j < 8; ++j) mx[j] = -3.0e38f;
#pragma unroll 4
  for (int t = 0; t < 128; ++t) {
    f4 c = pq[(t << 6) + lane];
#pragma unroll
    for (int j = 0; j < 8; ++j) {
      float v = fmaf(qx2[j], c[0], fmaf(qy2[j], c[1], fmaf(qz2[j], c[2], -c[3])));
      mx[j] = fmaxf(mx[j], v);
    }
  }
  // 8 interleaved bitonic sorts (stage-outer, query-inner -> 8-way shuffle ILP)
  float sv[8];
#pragma unroll
  for (int j = 0; j < 8; ++j) sv[j] = mx[j];
#pragma unroll
  for (int k = 2; k <= 64; k <<= 1) {
#pragma unroll
    for (int s = k >> 1; s > 0; s >>= 1) {
      const bool takeMin = (((lane & k) == 0) == ((lane & s) == 0));
#pragma unroll
      for (int j = 0; j < 8; ++j) {
        float o = __shfl_xor(sv[j], s);
        sv[j] = takeMin ? fminf(sv[j], o) : fmaxf(sv[j], o);
      }
    }
  }
  float T[8];
#pragma unroll
  for (int j = 0; j < 8; ++j) T[j] = __shfl(sv[j], 44) - 1e-3f;
  // phase B: ballot-compact candidates per query (deterministic order)
  int cnt[8];
#pragma unroll
  for (int j = 0; j < 8; ++j) cnt[j] = 0;
#pragma unroll 4
  for (int t = 0; t < 128; ++t) {
    f4 c = pq[(t << 6) + lane];
#pragma unroll
    for (int j = 0; j < 8; ++j) {
      float v = fmaf(qx2[j], c[0], fmaf(qy2[j], c[1], fmaf(qz2[j], c[2], -c[3])));
      bool pr = (v >= T[j]);
      u64 ball = __ballot(pr);
      if (ball) {
        int ofs = (int)__popcll(ball & ((1ull << lane) - 1ull));
        int pos = cnt[j] + ofs;
        if (pr && pos < 120) cand[w][j][pos] = (u16)((t << 6) + lane);
        cnt[j] += (int)__popcll(ball);
      }
    }
  }
  asm volatile("s_waitcnt lgkmcnt(0)" ::: "memory");
  // phase C: f64-exact rank selection (matches f64 gold incl. (v desc, idx asc) ties)
  for (int j = 0; j < 8; ++j) {
    const int cn = cnt[j] > 120 ? 120 : cnt[j];
    f4 Q = pq[qbase + j];
    const double Qx = (double)Q[0], Qy = (double)Q[1], Qz = (double)Q[2];
    const double Qs = Qx * Qx + Qy * Qy + Qz * Qz;
    double myV[2]; int myI[2];
#pragma unroll
    for (int jj = 0; jj < 2; ++jj) {
      const int e = lane + (jj << 6);
      myV[jj] = -1.0e300; myI[jj] = 0x7FFFFFFF;
      if (e < cn) {
        const int ci = cand[w][j][e];
        f4 c = pq[ci];
        double cx = (double)c[0], cy = (double)c[1], cz = (double)c[2];
        double v = 2.0 * (Qx * cx + Qy * cy + Qz * cz) - Qs - (cx * cx + cy * cy + cz * cz);
        myV[jj] = v; myI[jj] = ci;
        ckeyv[w][e] = v;
      }
    }
    asm volatile("s_waitcnt lgkmcnt(0)" ::: "memory");
    int rk0 = 0, rk1 = 0;
#pragma unroll 4
    for (int e2 = 0; e2 < cn; ++e2) {
      double ov = ckeyv[w][e2];
      int oi = (int)cand[w][j][e2];
      rk0 += ((ov > myV[0]) || (ov == myV[0] && oi < myI[0])) ? 1 : 0;
      rk1 += ((ov > myV[1]) || (ov == myV[1] && oi < myI[1])) ? 1 : 0;
    }
    int* orow = idxOut + (((long)b << 13) + qbase + j) * 20;
    if (lane < cn && rk0 < 20) orow[rk0] = myI[0];
    if (lane + 64 < cn && rk1 < 20) orow[rk1] = myI[1];
  }
}

// ---------------- bf16 MFMA GEMM: Y[b][n][o] = sum_k A[o][k]*B[b][n][k] ----------------
// BF16OUT=0: f32 out; BF16OUT=1: bf16 out.
template<int BF16OUT>
__global__ __launch_bounds__(256, 2) void k_gemm(
    const u16* __restrict__ A, const u16* __restrict__ Bm, void* __restrict__ Yv,
    int M, int K, long strideB, long strideY)
{
  __shared__ u16 sA[2][4096];
  __shared__ u16 sB[2][4096];
  const int b = blockIdx.z;
  const int m0 = blockIdx.y * 128;
  const int n0 = blockIdx.x * 128;
  const u16* Bp = Bm + (long)b * strideB;
  const int tid = threadIdx.x, lane = tid & 63, w = tid >> 6;
  const int wr = w >> 1, wc = w & 1;
  const int r15 = lane & 15, g8 = (lane >> 4) * 8;

  f4 acc[4][4];
#pragma unroll
  for (int i = 0; i < 4; ++i)
#pragma unroll
    for (int j = 0; j < 4; ++j) { f4 z = {0.f, 0.f, 0.f, 0.f}; acc[i][j] = z; }

  const int row0 = tid >> 2;
  const int kp0 = (tid & 3) << 3;
  const u16* gA0 = A + (long)(m0 + row0) * K + kp0;
  const u16* gA1 = A + (long)(m0 + row0 + 64) * K + kp0;
  const u16* gB0 = Bp + (long)(n0 + row0) * K + kp0;
  const u16* gB1 = Bp + (long)(n0 + row0 + 64) * K + kp0;
  const int ch0 = tid, ch1 = tid + 256;

  ((i4v*)sA[0])[ch0] = *(const i4v*)gA0;
  ((i4v*)sA[0])[ch1] = *(const i4v*)gA1;
  ((i4v*)sB[0])[ch0] = *(const i4v*)gB0;
  ((i4v*)sB[0])[ch1] = *(const i4v*)gB1;
  __syncthreads();

  const int KT = K >> 5;
  int cur = 0;
  for (int kk = 0; kk < KT; ++kk) {
    i4v ra0, ra1, rb0, rb1;
    const bool more = (kk + 1 < KT);
    if (more) {
      long ko = (long)(kk + 1) * 32;
      ra0 = *(const i4v*)(gA0 + ko); ra1 = *(const i4v*)(gA1 + ko);
      rb0 = *(const i4v*)(gB0 + ko); rb1 = *(const i4v*)(gB1 + ko);
    }
    const u16* la = sA[cur];
    const u16* lb = sB[cur];
    s8 af[4], bfr[4];
#pragma unroll
    for (int mi = 0; mi < 4; ++mi)
      af[mi] = *(const s8*)(la + (wr * 64 + mi * 16 + r15) * 32 + g8);
#pragma unroll
    for (int ni = 0; ni < 4; ++ni)
      bfr[ni] = *(const s8*)(lb + (wc * 64 + ni * 16 + r15) * 32 + g8);
#pragma unroll
    for (int mi = 0; mi < 4; ++mi)
#pragma unroll
      for (int ni = 0; ni < 4; ++ni)
        acc[mi][ni] = __builtin_amdgcn_mfma_f32_16x16x32_bf16(af[mi], bfr[ni], acc[mi][ni], 0, 0, 0);
    if (more) {
      ((i4v*)sA[cur ^ 1])[ch0] = ra0; ((i4v*)sA[cur ^ 1])[ch1] = ra1;
      ((i4v*)sB[cur ^ 1])[ch0] = rb0; ((i4v*)sB[cur ^ 1])[ch1] = rb1;
    }
    __syncthreads();
    cur ^= 1;
  }
  const int og = m0 + wr * 64 + (lane >> 4) * 4;
  const int ng = n0 + wc * 64 + r15;
  if (BF16OUT) {
    u16* Yp = (u16*)Yv + (long)b * strideY;
#pragma unroll
    for (int mi = 0; mi < 4; ++mi)
#pragma unroll
      for (int ni = 0; ni < 4; ++ni) {
        f4 a = acc[mi][ni];
        u16x4 r;
#pragma unroll
        for (int q = 0; q < 4; ++q) r[q] = f2b(a[q]);
        *(u16x4*)(Yp + (long)(ng + ni * 16) * M + og + mi * 16) = r;
      }
  } else {
    float* Yp = (float*)Yv + (long)b * strideY;
#pragma unroll
    for (int mi = 0; mi < 4; ++mi)
#pragma unroll
      for (int ni = 0; ni < 4; ++ni)
        *(f4*)(Yp + (long)(ng + ni * 16) * M + og + mi * 16) = acc[mi][ni];
  }
}

// ---------------- per-channel sum/sumsq over rows (Y is [rows][C]) ----------------
__global__ __launch_bounds__(256) void k_colstats(
    const float* __restrict__ Y, float* __restrict__ sums, float* __restrict__ ssq, int C, int RPB)
{
  const int tid = threadIdx.x;
  const int c = tid & (C - 1);
  const int sub = tid / C;
  const int step = 256 / C;
  const int r0 = blockIdx.x * RPB;
  float s = 0.f, qv = 0.f;
  for (int r = r0 + sub; r < r0 + RPB; r += step) {
    float v = Y[(long)r * C + c];
    s += v; qv = fmaf(v, v, qv);
  }
  atomicAdd(&sums[c], s);
  atomicAdd(&ssq[c], qv);
}

// ---------------- normalize + leaky -> bf16 (finalize fused per-block) ----------------
__global__ __launch_bounds__(256) void k_apply(
    const float* __restrict__ Y, const float* __restrict__ sums, const float* __restrict__ ssq,
    const float* __restrict__ g, const float* __restrict__ bt,
    u16* __restrict__ H, int Cmask, float invCount)
{
  __shared__ float sc[256], sh[256];
  const int tid = threadIdx.x;
  {
    int c = tid & Cmask;
    float m = sums[c] * invCount;
    float v = ssq[c] * invCount - m * m;
    float s = g[c] / sqrtf(v + 1e-5f);
    sc[tid] = s;
    sh[tid] = bt[c] - m * s;
  }
  __syncthreads();
  long i = (long)blockIdx.x * 256 + tid;
  f4 y = ((const f4*)Y)[i];
  int c0 = (int)((i << 2) & Cmask);
  float r[4];
#pragma unroll
  for (int j = 0; j < 4; ++j) {
    float z = fmaf(sc[c0 + j], y[j], sh[c0 + j]);
    r[j] = z > 0.f ? z : 0.2f * z;
  }
  u32 lo = (u32)f2b(r[0]) | ((u32)f2b(r[1]) << 16);
  u32 hi = (u32)f2b(r[2]) | ((u32)f2b(r[3]) << 16);
  *(uint2*)(H + i * 4) = make_uint2(lo, hi);
}

__global__ __launch_bounds__(256) void k_apply_edge(
    const float* __restrict__ Emax, const float* __restrict__ Emin,
    const float* __restrict__ sums, const float* __restrict__ ssq,
    const float* __restrict__ g, const float* __restrict__ bt,
    u16* __restrict__ H, float invCount)
{
  __shared__ float sc[256], sh[256];
  const int tid = threadIdx.x;
  {
    float m = sums[tid] * invCount;
    float v = ssq[tid] * invCount - m * m;
    float s = g[tid] / sqrtf(v + 1e-5f);
    sc[tid] = s;
    sh[tid] = bt[tid] - m * s;
  }
  __syncthreads();
  long i = (long)blockIdx.x * 256 + tid;
  f4 a = ((const f4*)Emax)[i];
  f4 bm = ((const f4*)Emin)[i];
  int c0 = (int)((i << 2) & 255);
  float r[4];
#pragma unroll
  for (int j = 0; j < 4; ++j) {
    float s = sc[c0 + j];
    float y = (s >= 0.f) ? a[j] : bm[j];   // max commutes with monotone affine+leaky
    float z = fmaf(s, y, sh[c0 + j]);
    r[j] = z > 0.f ? z : 0.2f * z;
  }
  u32 lo = (u32)f2b(r[0]) | ((u32)f2b(r[1]) << 16);
  u32 hi = (u32)f2b(r[2]) | ((u32)f2b(r[3]) << 16);
  *(uint2*)(H + i * 4) = make_uint2(lo, hi);
}

// ---------------- edgeconv gather (bf16 Y2): y = Anb[idx] + Cy; max/min + stats ----------------
__global__ __launch_bounds__(256, 2) void k_edge_gather(
    const u16* __restrict__ Y2, const int* __restrict__ idx,
    float* __restrict__ Emax, float* __restrict__ Emin,
    float* __restrict__ sums, float* __restrict__ ssq)
{
  __shared__ float s_sum[256], s_ssq[256];
  const int tid = threadIdx.x, lane = tid & 63, w = tid >> 6;
  s_sum[tid] = 0.f; s_ssq[tid] = 0.f;
  __syncthreads();
  const int ptBase = blockIdx.x * 64;
  f4 lsum = {0.f, 0.f, 0.f, 0.f}, lssq = {0.f, 0.f, 0.f, 0.f};
  for (int i = 0; i < 16; ++i) {
    const int pt = ptBase + w * 16 + i;
    const int b = pt >> 13;
    u16x4 cr = *(const u16x4*)(Y2 + (long)pt * 512 + 256 + (lane << 2));
    f4 ctr; ctr[0] = b2f(cr[0]); ctr[1] = b2f(cr[1]); ctr[2] = b2f(cr[2]); ctr[3] = b2f(cr[3]);
    const int* irow = idx + (long)pt * 20;
    f4 vmax = {-3.0e38f, -3.0e38f, -3.0e38f, -3.0e38f};
    f4 vmin = {3.0e38f, 3.0e38f, 3.0e38f, 3.0e38f};
#pragma unroll 4
    for (int k = 0; k < 20; ++k) {
      int m = irow[k];
      u16x4 nr = *(const u16x4*)(Y2 + (((long)b << 13) + m) * 512 + (lane << 2));
#pragma unroll
      for (int j = 0; j < 4; ++j) {
        float y = b2f(nr[j]) + ctr[j];
        vmax[j] = fmaxf(vmax[j], y);
        vmin[j] = fminf(vmin[j], y);
        lsum[j] += y;
        lssq[j] = fmaf(y, y, lssq[j]);
      }
    }
    *(f4*)(Emax + (long)pt * 256 + (lane << 2)) = vmax;
    *(f4*)(Emin + (long)pt * 256 + (lane << 2)) = vmin;
  }
#pragma unroll
  for (int j = 0; j < 4; ++j) {
    atomicAdd(&s_sum[(lane << 2) + j], lsum[j]);
    atomicAdd(&s_ssq[(lane << 2) + j], lssq[j]);
  }
  __syncthreads();
  atomicAdd(&sums[tid], s_sum[tid]);
  atomicAdd(&ssq[tid], s_ssq[tid]);
}

// ---------------- final 50x128 GEMM + bias, f32 out (B,50,8192); H4 is bf16 ----------------
__global__ __launch_bounds__(256) void k_final(
    const u16* __restrict__ H4, const float* __restrict__ wf, const float* __restrict__ bf,
    float* __restrict__ out)
{
  __shared__ float swf[4][128];
  __shared__ float sbf[4];
  const int o0 = blockIdx.y * 4;
  const int tid = threadIdx.x;
  if (tid < 128) {
#pragma unroll
    for (int j = 0; j < 4; ++j)
      swf[j][tid] = (o0 + j < 50) ? wf[(o0 + j) * 128 + tid] : 0.f;
  }
  if (tid < 4) sbf[tid] = (o0 + tid < 50) ? bf[o0 + tid] : 0.f;
  __syncthreads();
  const int b = blockIdx.z;
  const int n = blockIdx.x * 256 + tid;
  const u16* h = H4 + (long)(b * 8192 + n) * 128;
  float av[4] = {0.f, 0.f, 0.f, 0.f};
#pragma unroll
  for (int t = 0; t < 16; ++t) {
    i4v raw = *(const i4v*)(h + t * 8);
#pragma unroll
    for (int e = 0; e < 4; ++e) {
      u32 dw = (u32)raw[e];
      float f0 = b2f((u16)(dw & 0xFFFFu));
      float f1 = b2f((u16)(dw >> 16));
      int cc = t * 8 + e * 2;
#pragma unroll
      for (int j = 0; j < 4; ++j) {
        av[j] = fmaf(f0, swf[j][cc], av[j]);
        av[j] = fmaf(f1, swf[j][cc + 1], av[j]);
      }
    }
  }
#pragma unroll
  for (int j = 0; j < 4; ++j) {
    int o = o0 + j;
    if (o < 50) out[(((long)b * 50 + o) << 13) + n] = av[j] + sbf[j];
  }
}

// ---------------- launcher ----------------
extern "C" void kernel_launch(void* const* d_in, const int* in_sizes, int n_in,
                              void* d_out, int out_size, void* d_ws, size_t ws_size,
                              hipStream_t stream)
{
  if ((long)ws_size < WS_NEED) return;
  const float* x   = (const float*)d_in[0];
  const float* p   = (const float*)d_in[1];
  const float* w1  = (const float*)d_in[2];
  const float* g1  = (const float*)d_in[4];
  const float* bt1 = (const float*)d_in[5];
  const float* we  = (const float*)d_in[6];
  const float* ge  = (const float*)d_in[8];
  const float* bte = (const float*)d_in[9];
  const float* w2  = (const float*)d_in[10];
  const float* g2  = (const float*)d_in[12];
  const float* bt2 = (const float*)d_in[13];
  const float* w3  = (const float*)d_in[14];
  const float* g3  = (const float*)d_in[16];
  const float* bt3 = (const float*)d_in[17];
  const float* wf  = (const float*)d_in[18];
  const float* bfi = (const float*)d_in[19];

  char* ws = (char*)d_ws;
  u16* w1b   = (u16*)(ws + OFF_W1B);
  u16* weABb = (u16*)(ws + OFF_WEAB);
  u16* w2b   = (u16*)(ws + OFF_W2B);
  u16* w3b   = (u16*)(ws + OFF_W3B);
  int* idxb  = (int*)(ws + OFF_IDX);
  u16*   XT   = (u16*)(ws + OFF_XT);
  float* Y1   = (float*)(ws + OFF_Y1);
  u16*   H1   = (u16*)(ws + OFF_H1);
  u16*   Y2b  = (u16*)(ws + OFF_Y2);
  float* EMAX = (float*)(ws + OFF_EMAX);
  float* EMIN = (float*)(ws + OFF_EMIN);
  u16*   H2   = (u16*)(ws + OFF_H2);
  float* Y3   = (float*)(ws + OFF_Y3);
  u16*   H3   = (u16*)(ws + OFF_H3);
  float* Y4   = (float*)(ws + OFF_Y4);
  u16*   H4   = (u16*)(ws + OFF_H4);
  float* st0 = (float*)(ws + OFF_STATS);
  float* st1 = (float*)(ws + OFF_STATS + 4096);
  float* st2 = (float*)(ws + OFF_STATS + 8192);
  float* st3 = (float*)(ws + OFF_STATS + 12288);

  hipMemsetAsync(ws + OFF_STATS, 0, 16384, stream);
  k_convw<<<2112, 256, 0, stream>>>(w1, we, w2, w3, w1b, weABb, w2b, w3b);
  k_knn<<<256, 512, 0, stream>>>(p, idxb);
  k_xt<<<dim3(128, 19, 2), 256, 0, stream>>>(x, XT);

  // stage 1: smlp1d(x, w1)
  k_gemm<0><<<dim3(64, 2, 2), 256, 0, stream>>>(w1b, XT, Y1, 256, 1216, (long)8192 * 1216, (long)8192 * 256);
  k_colstats<<<256, 256, 0, stream>>>(Y1, st0, st0 + 256, 256, 64);
  k_apply<<<4096, 256, 0, stream>>>(Y1, st0, st0 + 256, g1, bt1, H1, 255, 1.0f / 16384.0f);

  // edgeconv: [Anb | Cy] GEMM (bf16 out), gather+max/min+stats, apply
  k_gemm<1><<<dim3(64, 4, 2), 256, 0, stream>>>(weABb, H1, Y2b, 512, 256, (long)8192 * 256, (long)8192 * 512);
  k_edge_gather<<<256, 256, 0, stream>>>(Y2b, idxb, EMAX, EMIN, st1, st1 + 256);
  k_apply_edge<<<4096, 256, 0, stream>>>(EMAX, EMIN, st1, st1 + 256, ge, bte, H2, 1.0f / 327680.0f);

  // stage 2: smlp1d(h, w2)
  k_gemm<0><<<dim3(64, 2, 2), 256, 0, stream>>>(w2b, H2, Y3, 256, 256, (long)8192 * 256, (long)8192 * 256);
  k_colstats<<<256, 256, 0, stream>>>(Y3, st2, st2 + 256, 256, 64);
  k_apply<<<4096, 256, 0, stream>>>(Y3, st2, st2 + 256, g2, bt2, H3, 255, 1.0f / 16384.0f);

  // stage 3: smlp1d(h, w3)
  k_gemm<0><<<dim3(64, 1, 2), 256, 0, stream>>>(w3b, H3, Y4, 128, 256, (long)8192 * 256, (long)8192 * 128);
  k_colstats<<<128, 256, 0, stream>>>(Y4, st3, st3 + 256, 128, 128);
  k_apply<<<2048, 256, 0, stream>>>(Y4, st3, st3 + 256, g3, bt3, H4, 127, 1.0f / 16384.0f);

  // final projection
  k_final<<<dim3(32, 13, 2), 256, 0, stream>>>(H4, wf, bfi, (float*)d_out);
}

// Round 9
// 315.948 us; speedup vs baseline: 2.6514x; 1.1491x over previous
//
#include <hip/hip_runtime.h>

typedef unsigned short u16;
typedef unsigned int   u32;
typedef unsigned long long u64;
typedef __attribute__((ext_vector_type(4))) float f4;
typedef __attribute__((ext_vector_type(8))) short s8;
typedef __attribute__((ext_vector_type(4))) int   i4v;
typedef __attribute__((ext_vector_type(4))) unsigned short u16x4;

#define DEV __device__ __forceinline__

DEV u16 f2b(float f) {
  u32 u = __float_as_uint(f);
  return (u16)((u + 0x7FFFu + ((u >> 16) & 1u)) >> 16);
}
DEV float b2f(u16 h) { return __uint_as_float(((u32)h) << 16); }

// ---------------- workspace layout (bytes) ----------------
#define OFF_STATS 0L
#define OFF_W1B   65536L
#define OFF_WEAB  688128L
#define OFF_W2B   950272L
#define OFF_W3B   1081344L
#define OFF_IDX   1146880L
#define OFF_XT    4194304L      /* 39.8 MB bf16, dead after GEMM1 */
#define OFF_Y1    44040192L     /* 16.8 MB f32, dead after edge GEMM */
#define OFF_Y2    4194304L      /* 16.8 MB bf16 over dead XT, dead after gather */
#define OFF_EMAX  23068672L     /* 16.8 MB f32, dead after GEMM2 */
#define OFF_EMIN  41943040L     /* 16.8 MB f32 over dead Y1 tail */
#define OFF_Y3    4194304L      /* 16.8 MB f32 over dead Y2 */
#define OFF_Y4    23068672L     /* 8.4 MB f32 over dead EMAX */
#define WS_NEED   71303168L

// ---------------- weight convert -> bf16 (w1 | weA,weB-weA | w2 | w3) ----------------
__global__ __launch_bounds__(256) void k_convw(
    const float* __restrict__ w1, const float* __restrict__ we,
    const float* __restrict__ w2, const float* __restrict__ w3,
    u16* __restrict__ w1b, u16* __restrict__ weABb,
    u16* __restrict__ w2b, u16* __restrict__ w3b)
{
  int i = blockIdx.x * 256 + threadIdx.x;
  if (i < 311296) { w1b[i] = f2b(w1[i]); return; }
  i -= 311296;
  if (i < 131072) {
    int o = i >> 8, c = i & 255;
    float v = (o < 256) ? we[o * 512 + c]
                        : we[(o - 256) * 512 + 256 + c] - we[(o - 256) * 512 + c];
    weABb[i] = f2b(v); return;
  }
  i -= 131072;
  if (i < 65536) { w2b[i] = f2b(w2[i]); return; }
  i -= 65536;
  if (i < 32768) { w3b[i] = f2b(w3[i]); }
}

// ---------------- x transpose + bf16: (B,1216,8192)f32 -> (B,8192,1216)bf16 ----------------
__global__ __launch_bounds__(256) void k_xt(const float* __restrict__ x, u16* __restrict__ xt)
{
  __shared__ float t[64][65];
  const int b = blockIdx.z, ct = blockIdx.y, nt = blockIdx.x;
  const int tx = threadIdx.x & 63, ty = threadIdx.x >> 6;
  const float* xb = x + (long)b * 1216 * 8192;
#pragma unroll
  for (int i = 0; i < 16; ++i) {
    int c = ct * 64 + ty + i * 4;
    t[ty + i * 4][tx] = xb[(long)c * 8192 + nt * 64 + tx];
  }
  __syncthreads();
  u16* xtb = xt + (long)b * 8192 * 1216;
#pragma unroll
  for (int i = 0; i < 16; ++i) {
    int n = nt * 64 + ty + i * 4;
    xtb[(long)n * 1216 + ct * 64 + tx] = f2b(t[tx][ty + i * 4]);
  }
}

// ---------------- exact KNN top-20, 8 queries/wave; rank-based f64 re-rank ----------------
__global__ __launch_bounds__(512, 1) void k_knn(const float* __restrict__ p, int* __restrict__ idxOut)
{
  __shared__ f4 pq[8192];                 // 128 KB: (x,y,z,|c|^2)
  __shared__ u16 cand[8][8][120];         // 15 KB
  __shared__ double ckeyv[8][120];        // 7.5 KB
  const int tid = threadIdx.x, lane = tid & 63, w = tid >> 6;
  const int blk = blockIdx.x;
  const int b = blk >> 7;
  const int qbase = ((blk & 127) << 6) + (w << 3);
  const float* px = p + (long)b * 24576;
  const float* py = px + 8192;
  const float* pz = px + 16384;
  for (int t4 = tid; t4 < 2048; t4 += 512) {
    f4 x4 = *(const f4*)(px + t4 * 4);
    f4 y4 = *(const f4*)(py + t4 * 4);
    f4 z4 = *(const f4*)(pz + t4 * 4);
#pragma unroll
    for (int j = 0; j < 4; ++j) {
      float X = x4[j], Yv = y4[j], Z = z4[j];
      float s = fmaf(X, X, fmaf(Yv, Yv, Z * Z));
      f4 v; v[0] = X; v[1] = Yv; v[2] = Z; v[3] = s;
      pq[t4 * 4 + j] = v;
    }
  }
  __syncthreads();
  float qx2[8], qy2[8], qz2[8];
#pragma unroll
  for (int j = 0; j < 8; ++j) {
    f4 Q = pq[qbase + j];
    qx2[j] = Q[0] + Q[0]; qy2[j] = Q[1] + Q[1]; qz2[j] = Q[2] + Q[2];
  }
  float mx[8];
#pragma unroll
  for (int j = 0; j < 8; ++j) mx[j] = -3.0e38f;
#pragma unroll 4
  for (int t = 0; t < 128; ++t) {
    f4 c = pq[(t << 6) + lane];
#pragma unroll
    for (int j = 0; j < 8; ++j) {
      float v = fmaf(qx2[j], c[0], fmaf(qy2[j], c[1], fmaf(qz2[j], c[2], -c[3])));
      mx[j] = fmaxf(mx[j], v);
    }
  }
  float sv[8];
#pragma unroll
  for (int j = 0; j < 8; ++j) sv[j] = mx[j];
#pragma unroll
  for (int k = 2; k <= 64; k <<= 1) {
#pragma unroll
    for (int s = k >> 1; s > 0; s >>= 1) {
      const bool takeMin = (((lane & k) == 0) == ((lane & s) == 0));
#pragma unroll
      for (int j = 0; j < 8; ++j) {
        float o = __shfl_xor(sv[j], s);
        sv[j] = takeMin ? fminf(sv[j], o) : fmaxf(sv[j], o);
      }
    }
  }
  float T[8];
#pragma unroll
  for (int j = 0; j < 8; ++j) T[j] = __shfl(sv[j], 44) - 1e-3f;
  int cnt[8];
#pragma unroll
  for (int j = 0; j < 8; ++j) cnt[j] = 0;
#pragma unroll 4
  for (int t = 0; t < 128; ++t) {
    f4 c = pq[(t << 6) + lane];
#pragma unroll
    for (int j = 0; j < 8; ++j) {
      float v = fmaf(qx2[j], c[0], fmaf(qy2[j], c[1], fmaf(qz2[j], c[2], -c[3])));
      bool pr = (v >= T[j]);
      u64 ball = __ballot(pr);
      if (ball) {
        int ofs = (int)__popcll(ball & ((1ull << lane) - 1ull));
        int pos = cnt[j] + ofs;
        if (pr && pos < 120) cand[w][j][pos] = (u16)((t << 6) + lane);
        cnt[j] += (int)__popcll(ball);
      }
    }
  }
  asm volatile("s_waitcnt lgkmcnt(0)" ::: "memory");
  for (int j = 0; j < 8; ++j) {
    const int cn = cnt[j] > 120 ? 120 : cnt[j];
    f4 Q = pq[qbase + j];
    const double Qx = (double)Q[0], Qy = (double)Q[1], Qz = (double)Q[2];
    const double Qs = Qx * Qx + Qy * Qy + Qz * Qz;
    double myV[2]; int myI[2];
#pragma unroll
    for (int jj = 0; jj < 2; ++jj) {
      const int e = lane + (jj << 6);
      myV[jj] = -1.0e300; myI[jj] = 0x7FFFFFFF;
      if (e < cn) {
        const int ci = cand[w][j][e];
        f4 c = pq[ci];
        double cx = (double)c[0], cy = (double)c[1], cz = (double)c[2];
        double v = 2.0 * (Qx * cx + Qy * cy + Qz * cz) - Qs - (cx * cx + cy * cy + cz * cz);
        myV[jj] = v; myI[jj] = ci;
        ckeyv[w][e] = v;
      }
    }
    asm volatile("s_waitcnt lgkmcnt(0)" ::: "memory");
    int rk0 = 0, rk1 = 0;
#pragma unroll 4
    for (int e2 = 0; e2 < cn; ++e2) {
      double ov = ckeyv[w][e2];
      int oi = (int)cand[w][j][e2];
      rk0 += ((ov > myV[0]) || (ov == myV[0] && oi < myI[0])) ? 1 : 0;
      rk1 += ((ov > myV[1]) || (ov == myV[1] && oi < myI[1])) ? 1 : 0;
    }
    int* orow = idxOut + (((long)b << 13) + qbase + j) * 20;
    if (lane < cn && rk0 < 20) orow[rk0] = myI[0];
    if (lane + 64 < cn && rk1 < 20) orow[rk1] = myI[1];
  }
}

// ---------------- fused apply helpers ----------------
DEV float lky(float z) { return z > 0.f ? z : 0.2f * z; }

DEV i4v applyPack8(f4 a, f4 b4, const float* sc, const float* sh, int kb) {
  u16 r[8];
#pragma unroll
  for (int e = 0; e < 4; ++e) r[e] = f2b(lky(fmaf(sc[kb + e], a[e], sh[kb + e])));
#pragma unroll
  for (int e = 0; e < 4; ++e) r[4 + e] = f2b(lky(fmaf(sc[kb + 4 + e], b4[e], sh[kb + 4 + e])));
  i4v o;
#pragma unroll
  for (int e = 0; e < 4; ++e) o[e] = (int)((u32)r[2 * e] | ((u32)r[2 * e + 1] << 16));
  return o;
}

DEV i4v selPack8(f4 a, f4 b4, f4 a2, f4 b2, const float* sc, const float* sh, int kb) {
  u16 r[8];
#pragma unroll
  for (int e = 0; e < 4; ++e) {
    float s = sc[kb + e];
    float y = (s >= 0.f) ? a[e] : a2[e];
    r[e] = f2b(lky(fmaf(s, y, sh[kb + e])));
  }
#pragma unroll
  for (int e = 0; e < 4; ++e) {
    float s = sc[kb + 4 + e];
    float y = (s >= 0.f) ? b4[e] : b2[e];
    r[4 + e] = f2b(lky(fmaf(s, y, sh[kb + 4 + e])));
  }
  i4v o;
#pragma unroll
  for (int e = 0; e < 4; ++e) o[e] = (int)((u32)r[2 * e] | ((u32)r[2 * e + 1] << 16));
  return o;
}

// ---------------- bf16 MFMA GEMM: Y[b][n][o] = sum_k A[o][k]*Bapplied[b][n][k] ----------------
// BMODE 0: B0 is bf16 [n][K].  BMODE 1: B0 is f32 [n][K] + norm/leaky applied (K==256).
// BMODE 2: B0=EMAX,B1=EMIN f32 [n][K] + sign-select + norm/leaky (K==256).
// STATS: epilogue accumulates per-channel sum/sumsq of Y into gsums/gssq.
// BF16OUT: Y written as bf16 instead of f32.
template<int BMODE, int STATS, int BF16OUT>
__global__ __launch_bounds__(256, 2) void k_gemm(
    const u16* __restrict__ A, const void* __restrict__ B0v, const void* __restrict__ B1v,
    const float* __restrict__ sums, const float* __restrict__ ssq,
    const float* __restrict__ g, const float* __restrict__ bt, float invCount,
    float* __restrict__ gsums, float* __restrict__ gssq,
    void* __restrict__ Yv, int M, int K, long strideB, long strideY)
{
  __shared__ u16 sA[2][4096];
  __shared__ u16 sB[2][4096];
  __shared__ float scB[256], shB[256];
  __shared__ float s_sum[128], s_ssq[128];
  const int b = blockIdx.z;
  const int m0 = blockIdx.y * 128;
  const int n0 = blockIdx.x * 128;
  const int tid = threadIdx.x, lane = tid & 63, w = tid >> 6;
  const int wr = w >> 1, wc = w & 1;
  const int r15 = lane & 15, g8 = (lane >> 4) * 8;

  if (BMODE != 0) {
    float m = sums[tid] * invCount;
    float v = ssq[tid] * invCount - m * m;
    float s = g[tid] / sqrtf(v + 1e-5f);
    scB[tid] = s;
    shB[tid] = bt[tid] - m * s;
  }
  if (STATS) { if (tid < 128) { s_sum[tid] = 0.f; s_ssq[tid] = 0.f; } }
  if (BMODE != 0) __syncthreads();

  f4 acc[4][4];
#pragma unroll
  for (int i = 0; i < 4; ++i)
#pragma unroll
    for (int j = 0; j < 4; ++j) { f4 z = {0.f, 0.f, 0.f, 0.f}; acc[i][j] = z; }

  const int row0 = tid >> 2;            // 0..63
  const int kp0 = (tid & 3) << 3;       // 0,8,16,24
  const u16* gA0 = A + (long)(m0 + row0) * K + kp0;
  const u16* gA1 = A + (long)(m0 + row0 + 64) * K + kp0;
  const int ch0 = tid, ch1 = tid + 256;

  const u16* gB0 = (const u16*)B0v + (long)b * strideB + (long)(n0 + row0) * K + kp0;
  const u16* gB1 = gB0 + (long)64 * K;
  const float* fB0 = (const float*)B0v + (long)b * strideB + (long)(n0 + row0) * K + kp0;
  const float* fB1 = fB0 + (long)64 * K;
  const float* eB0 = (const float*)B1v + (long)b * strideB + (long)(n0 + row0) * K + kp0;
  const float* eB1 = eB0 + (long)64 * K;

  // prologue: stage k-tile 0
  ((i4v*)sA[0])[ch0] = *(const i4v*)gA0;
  ((i4v*)sA[0])[ch1] = *(const i4v*)gA1;
  if (BMODE == 0) {
    ((i4v*)sB[0])[ch0] = *(const i4v*)gB0;
    ((i4v*)sB[0])[ch1] = *(const i4v*)gB1;
  } else if (BMODE == 1) {
    ((i4v*)sB[0])[ch0] = applyPack8(*(const f4*)fB0, *(const f4*)(fB0 + 4), scB, shB, kp0);
    ((i4v*)sB[0])[ch1] = applyPack8(*(const f4*)fB1, *(const f4*)(fB1 + 4), scB, shB, kp0);
  } else {
    ((i4v*)sB[0])[ch0] = selPack8(*(const f4*)fB0, *(const f4*)(fB0 + 4),
                                  *(const f4*)eB0, *(const f4*)(eB0 + 4), scB, shB, kp0);
    ((i4v*)sB[0])[ch1] = selPack8(*(const f4*)fB1, *(const f4*)(fB1 + 4),
                                  *(const f4*)eB1, *(const f4*)(eB1 + 4), scB, shB, kp0);
  }
  __syncthreads();

  const int KT = K >> 5;
  int cur = 0;
  for (int kk = 0; kk < KT; ++kk) {
    const bool more = (kk + 1 < KT);
    i4v ra0, ra1, rb0, rb1;
    f4 p0a, p0b, p1a, p1b, q0a, q0b, q1a, q1b;
    if (more) {
      long ko = (long)(kk + 1) * 32;
      ra0 = *(const i4v*)(gA0 + ko); ra1 = *(const i4v*)(gA1 + ko);
      if (BMODE == 0) {
        rb0 = *(const i4v*)(gB0 + ko); rb1 = *(const i4v*)(gB1 + ko);
      } else {
        p0a = *(const f4*)(fB0 + ko); p0b = *(const f4*)(fB0 + ko + 4);
        p1a = *(const f4*)(fB1 + ko); p1b = *(const f4*)(fB1 + ko + 4);
        if (BMODE == 2) {
          q0a = *(const f4*)(eB0 + ko); q0b = *(const f4*)(eB0 + ko + 4);
          q1a = *(const f4*)(eB1 + ko); q1b = *(const f4*)(eB1 + ko + 4);
        }
      }
    }
    const u16* la = sA[cur];
    const u16* lb = sB[cur];
    s8 af[4], bfr[4];
#pragma unroll
    for (int mi = 0; mi < 4; ++mi)
      af[mi] = *(const s8*)(la + (wr * 64 + mi * 16 + r15) * 32 + g8);
#pragma unroll
    for (int ni = 0; ni < 4; ++ni)
      bfr[ni] = *(const s8*)(lb + (wc * 64 + ni * 16 + r15) * 32 + g8);
#pragma unroll
    for (int mi = 0; mi < 4; ++mi)
#pragma unroll
      for (int ni = 0; ni < 4; ++ni)
        acc[mi][ni] = __builtin_amdgcn_mfma_f32_16x16x32_bf16(af[mi], bfr[ni], acc[mi][ni], 0, 0, 0);
    if (more) {
      ((i4v*)sA[cur ^ 1])[ch0] = ra0; ((i4v*)sA[cur ^ 1])[ch1] = ra1;
      if (BMODE == 0) {
        ((i4v*)sB[cur ^ 1])[ch0] = rb0; ((i4v*)sB[cur ^ 1])[ch1] = rb1;
      } else {
        const int kb = (kk + 1) * 32 + kp0;
        if (BMODE == 1) {
          ((i4v*)sB[cur ^ 1])[ch0] = applyPack8(p0a, p0b, scB, shB, kb);
          ((i4v*)sB[cur ^ 1])[ch1] = applyPack8(p1a, p1b, scB, shB, kb);
        } else {
          ((i4v*)sB[cur ^ 1])[ch0] = selPack8(p0a, p0b, q0a, q0b, scB, shB, kb);
          ((i4v*)sB[cur ^ 1])[ch1] = selPack8(p1a, p1b, q1a, q1b, scB, shB, kb);
        }
      }
    }
    __syncthreads();
    cur ^= 1;
  }
  // epilogue: D col(n)=lane&15, row(o)=(lane>>4)*4+reg
  const int og = m0 + wr * 64 + (lane >> 4) * 4;
  const int ng = n0 + wc * 64 + r15;
  if (BF16OUT) {
    u16* Yp = (u16*)Yv + (long)b * strideY;
#pragma unroll
    for (int mi = 0; mi < 4; ++mi)
#pragma unroll
      for (int ni = 0; ni < 4; ++ni) {
        f4 a = acc[mi][ni];
        u16x4 r;
#pragma unroll
        for (int q = 0; q < 4; ++q) r[q] = f2b(a[q]);
        *(u16x4*)(Yp + (long)(ng + ni * 16) * M + og + mi * 16) = r;
      }
  } else {
    float* Yp = (float*)Yv + (long)b * strideY;
#pragma unroll
    for (int mi = 0; mi < 4; ++mi)
#pragma unroll
      for (int ni = 0; ni < 4; ++ni)
        *(f4*)(Yp + (long)(ng + ni * 16) * M + og + mi * 16) = acc[mi][ni];
  }
  if (STATS) {
#pragma unroll
    for (int mi = 0; mi < 4; ++mi)
#pragma unroll
      for (int j = 0; j < 4; ++j) {
        float s = 0.f, q = 0.f;
#pragma unroll
        for (int ni = 0; ni < 4; ++ni) {
          float v = acc[mi][ni][j];
          s += v; q = fmaf(v, v, q);
        }
#pragma unroll
        for (int off = 1; off < 16; off <<= 1) {
          s += __shfl_xor(s, off);
          q += __shfl_xor(q, off);
        }
        if ((lane & 15) == 0) {
          int lc = wr * 64 + (lane >> 4) * 4 + mi * 16 + j;
          atomicAdd(&s_sum[lc], s);
          atomicAdd(&s_ssq[lc], q);
        }
      }
    __syncthreads();
    if (tid < 128) {
      atomicAdd(&gsums[m0 + tid], s_sum[tid]);
      atomicAdd(&gssq[m0 + tid], s_ssq[tid]);
    }
  }
}

// ---------------- edgeconv gather (bf16 Y2): y = Anb[idx] + Cy; max/min + stats ----------------
__global__ __launch_bounds__(256, 2) void k_edge_gather(
    const u16* __restrict__ Y2, const int* __restrict__ idx,
    float* __restrict__ Emax, float* __restrict__ Emin,
    float* __restrict__ sums, float* __restrict__ ssq)
{
  __shared__ float s_sum[256], s_ssq[256];
  const int tid = threadIdx.x, lane = tid & 63, w = tid >> 6;
  s_sum[tid] = 0.f; s_ssq[tid] = 0.f;
  __syncthreads();
  const int ptBase = blockIdx.x * 64;
  f4 lsum = {0.f, 0.f, 0.f, 0.f}, lssq = {0.f, 0.f, 0.f, 0.f};
  for (int i = 0; i < 16; ++i) {
    const int pt = ptBase + w * 16 + i;
    const int b = pt >> 13;
    u16x4 cr = *(const u16x4*)(Y2 + (long)pt * 512 + 256 + (lane << 2));
    f4 ctr; ctr[0] = b2f(cr[0]); ctr[1] = b2f(cr[1]); ctr[2] = b2f(cr[2]); ctr[3] = b2f(cr[3]);
    const int* irow = idx + (long)pt * 20;
    f4 vmax = {-3.0e38f, -3.0e38f, -3.0e38f, -3.0e38f};
    f4 vmin = {3.0e38f, 3.0e38f, 3.0e38f, 3.0e38f};
#pragma unroll 4
    for (int k = 0; k < 20; ++k) {
      int m = irow[k];
      u16x4 nr = *(const u16x4*)(Y2 + (((long)b << 13) + m) * 512 + (lane << 2));
#pragma unroll
      for (int j = 0; j < 4; ++j) {
        float y = b2f(nr[j]) + ctr[j];
        vmax[j] = fmaxf(vmax[j], y);
        vmin[j] = fminf(vmin[j], y);
        lsum[j] += y;
        lssq[j] = fmaf(y, y, lssq[j]);
      }
    }
    *(f4*)(Emax + (long)pt * 256 + (lane << 2)) = vmax;
    *(f4*)(Emin + (long)pt * 256 + (lane << 2)) = vmin;
  }
#pragma unroll
  for (int j = 0; j < 4; ++j) {
    atomicAdd(&s_sum[(lane << 2) + j], lsum[j]);
    atomicAdd(&s_ssq[(lane << 2) + j], lssq[j]);
  }
  __syncthreads();
  atomicAdd(&sums[tid], s_sum[tid]);
  atomicAdd(&ssq[tid], s_ssq[tid]);
}

// ---------------- final: apply(norm3+leaky) + 50x128 GEMM + bias, f32 out ----------------
__global__ __launch_bounds__(256) void k_final(
    const float* __restrict__ Y4, const float* __restrict__ sums, const float* __restrict__ ssq,
    const float* __restrict__ g, const float* __restrict__ bt,
    const float* __restrict__ wf, const float* __restrict__ bf,
    float* __restrict__ out)
{
  __shared__ float swf[4][128];
  __shared__ float sbf[4];
  __shared__ float sc[128], sh[128];
  const int o0 = blockIdx.y * 4;
  const int tid = threadIdx.x;
  if (tid < 128) {
#pragma unroll
    for (int j = 0; j < 4; ++j)
      swf[j][tid] = (o0 + j < 50) ? wf[(o0 + j) * 128 + tid] : 0.f;
    float m = sums[tid] * (1.0f / 16384.0f);
    float v = ssq[tid] * (1.0f / 16384.0f) - m * m;
    float s = g[tid] / sqrtf(v + 1e-5f);
    sc[tid] = s;
    sh[tid] = bt[tid] - m * s;
  }
  if (tid < 4) sbf[tid] = (o0 + tid < 50) ? bf[o0 + tid] : 0.f;
  __syncthreads();
  const int b = blockIdx.z;
  const int n = blockIdx.x * 256 + tid;
  const float* h = Y4 + (long)(b * 8192 + n) * 128;
  float av[4] = {0.f, 0.f, 0.f, 0.f};
#pragma unroll
  for (int t = 0; t < 32; ++t) {
    f4 hv = *(const f4*)(h + t * 4);
#pragma unroll
    for (int e = 0; e < 4; ++e) {
      int ch = t * 4 + e;
      float z = lky(fmaf(sc[ch], hv[e], sh[ch]));
#pragma unroll
      for (int j = 0; j < 4; ++j)
        av[j] = fmaf(z, swf[j][ch], av[j]);
    }
  }
#pragma unroll
  for (int j = 0; j < 4; ++j) {
    int o = o0 + j;
    if (o < 50) out[(((long)b * 50 + o) << 13) + n] = av[j] + sbf[j];
  }
}

// ---------------- launcher ----------------
extern "C" void kernel_launch(void* const* d_in, const int* in_sizes, int n_in,
                              void* d_out, int out_size, void* d_ws, size_t ws_size,
                              hipStream_t stream)
{
  if ((long)ws_size < WS_NEED) return;
  const float* x   = (const float*)d_in[0];
  const float* p   = (const float*)d_in[1];
  const float* w1  = (const float*)d_in[2];
  const float* g1w = (const float*)d_in[4];
  const float* bt1 = (const float*)d_in[5];
  const float* we  = (const float*)d_in[6];
  const float* gew = (const float*)d_in[8];
  const float* bte = (const float*)d_in[9];
  const float* w2  = (const float*)d_in[10];
  const float* g2w = (const float*)d_in[12];
  const float* bt2 = (const float*)d_in[13];
  const float* w3  = (const float*)d_in[14];
  const float* g3w = (const float*)d_in[16];
  const float* bt3 = (const float*)d_in[17];
  const float* wf  = (const float*)d_in[18];
  const float* bfi = (const float*)d_in[19];

  char* ws = (char*)d_ws;
  u16* w1b   = (u16*)(ws + OFF_W1B);
  u16* weABb = (u16*)(ws + OFF_WEAB);
  u16* w2b   = (u16*)(ws + OFF_W2B);
  u16* w3b   = (u16*)(ws + OFF_W3B);
  int* idxb  = (int*)(ws + OFF_IDX);
  u16*   XT   = (u16*)(ws + OFF_XT);
  float* Y1   = (float*)(ws + OFF_Y1);
  u16*   Y2b  = (u16*)(ws + OFF_Y2);
  float* EMAX = (float*)(ws + OFF_EMAX);
  float* EMIN = (float*)(ws + OFF_EMIN);
  float* Y3   = (float*)(ws + OFF_Y3);
  float* Y4   = (float*)(ws + OFF_Y4);
  float* st0 = (float*)(ws + OFF_STATS);
  float* st1 = (float*)(ws + OFF_STATS + 4096);
  float* st2 = (float*)(ws + OFF_STATS + 8192);
  float* st3 = (float*)(ws + OFF_STATS + 12288);

  hipMemsetAsync(ws + OFF_STATS, 0, 16384, stream);
  k_convw<<<2112, 256, 0, stream>>>(w1, we, w2, w3, w1b, weABb, w2b, w3b);
  k_knn<<<256, 512, 0, stream>>>(p, idxb);
  k_xt<<<dim3(128, 19, 2), 256, 0, stream>>>(x, XT);

  // stage 1: smlp1d(x, w1) -> Y1 f32 + stats st0
  k_gemm<0, 1, 0><<<dim3(64, 2, 2), 256, 0, stream>>>(
      w1b, XT, nullptr, nullptr, nullptr, nullptr, nullptr, 0.f,
      st0, st0 + 256, Y1, 256, 1216, (long)8192 * 1216, (long)8192 * 256);

  // edge GEMM: B = apply1(Y1) fused -> Y2 bf16 [Anb | Cy]
  k_gemm<1, 0, 1><<<dim3(64, 4, 2), 256, 0, stream>>>(
      weABb, Y1, nullptr, st0, st0 + 256, g1w, bt1, 1.0f / 16384.0f,
      nullptr, nullptr, Y2b, 512, 256, (long)8192 * 256, (long)8192 * 512);

  // gather: max/min + stats st1
  k_edge_gather<<<256, 256, 0, stream>>>(Y2b, idxb, EMAX, EMIN, st1, st1 + 256);

  // stage 2: B = apply_edge(EMAX,EMIN) fused -> Y3 f32 + stats st2
  k_gemm<2, 1, 0><<<dim3(64, 2, 2), 256, 0, stream>>>(
      w2b, EMAX, EMIN, st1, st1 + 256, gew, bte, 1.0f / 327680.0f,
      st2, st2 + 256, Y3, 256, 256, (long)8192 * 256, (long)8192 * 256);

  // stage 3: B = apply2(Y3) fused -> Y4 f32 + stats st3
  k_gemm<1, 1, 0><<<dim3(64, 1, 2), 256, 0, stream>>>(
      w3b, Y3, nullptr, st2, st2 + 256, g2w, bt2, 1.0f / 16384.0f,
      st3, st3 + 256, Y4, 128, 256, (long)8192 * 256, (long)8192 * 128);

  // final: apply3 fused + projection
  k_final<<<dim3(32, 13, 2), 256, 0, stream>>>(Y4, st3, st3 + 256, g3w, bt3, wf, bfi, (float*)d_out);
}

// Round 10
// 263.424 us; speedup vs baseline: 3.1800x; 1.1994x over previous
//
#include <hip/hip_runtime.h>

typedef unsigned short u16;
typedef unsigned int   u32;
typedef unsigned long long u64;
typedef __attribute__((ext_vector_type(4))) float f4;
typedef __attribute__((ext_vector_type(8))) short s8;
typedef __attribute__((ext_vector_type(4))) int   i4v;
typedef __attribute__((ext_vector_type(4))) unsigned short u16x4;

#define DEV __device__ __forceinline__

DEV u16 f2b(float f) {
  u32 u = __float_as_uint(f);
  return (u16)((u + 0x7FFFu + ((u >> 16) & 1u)) >> 16);
}
DEV float b2f(u16 h) { return __uint_as_float(((u32)h) << 16); }

// ---------------- workspace layout (bytes) ----------------
#define OFF_STATS 0L
#define OFF_W1B   65536L
#define OFF_WEAB  688128L
#define OFF_W2B   950272L
#define OFF_W3B   1081344L
#define OFF_IDX   1146880L
#define OFF_XT    4194304L      /* 39.8 MB bf16, dead after GEMM1 */
#define OFF_Y1    44040192L     /* 16.8 MB f32, dead after edge GEMM */
#define OFF_Y2    4194304L      /* 16.8 MB bf16 over dead XT, dead after gather */
#define OFF_EMAX  23068672L     /* 16.8 MB f32, dead after GEMM2 */
#define OFF_EMIN  41943040L     /* 16.8 MB f32 over dead Y1 tail */
#define OFF_Y3    4194304L      /* 16.8 MB f32 over dead Y2 */
#define OFF_Y4    23068672L     /* 8.4 MB f32 over dead EMAX */
#define WS_NEED   71303168L

// ---------------- weight convert -> bf16 (w1 | weA,weB-weA | w2 | w3) ----------------
__global__ __launch_bounds__(256) void k_convw(
    const float* __restrict__ w1, const float* __restrict__ we,
    const float* __restrict__ w2, const float* __restrict__ w3,
    u16* __restrict__ w1b, u16* __restrict__ weABb,
    u16* __restrict__ w2b, u16* __restrict__ w3b)
{
  int i = blockIdx.x * 256 + threadIdx.x;
  if (i < 311296) { w1b[i] = f2b(w1[i]); return; }
  i -= 311296;
  if (i < 131072) {
    int o = i >> 8, c = i & 255;
    float v = (o < 256) ? we[o * 512 + c]
                        : we[(o - 256) * 512 + 256 + c] - we[(o - 256) * 512 + c];
    weABb[i] = f2b(v); return;
  }
  i -= 131072;
  if (i < 65536) { w2b[i] = f2b(w2[i]); return; }
  i -= 65536;
  if (i < 32768) { w3b[i] = f2b(w3[i]); }
}

// ---------------- x transpose + bf16: (B,1216,8192)f32 -> (B,8192,1216)bf16 ----------------
__global__ __launch_bounds__(256) void k_xt(const float* __restrict__ x, u16* __restrict__ xt)
{
  __shared__ float t[64][65];
  const int b = blockIdx.z, ct = blockIdx.y, nt = blockIdx.x;
  const int tx = threadIdx.x & 63, ty = threadIdx.x >> 6;
  const float* xb = x + (long)b * 1216 * 8192;
#pragma unroll
  for (int i = 0; i < 16; ++i) {
    int c = ct * 64 + ty + i * 4;
    t[ty + i * 4][tx] = xb[(long)c * 8192 + nt * 64 + tx];
  }
  __syncthreads();
  u16* xtb = xt + (long)b * 8192 * 1216;
#pragma unroll
  for (int i = 0; i < 16; ++i) {
    int n = nt * 64 + ty + i * 4;
    xtb[(long)n * 1216 + ct * 64 + tx] = f2b(t[tx][ty + i * 4]);
  }
}

// ---------------- exact KNN top-20, 8 queries/wave; rank-based f64 re-rank ----------------
__global__ __launch_bounds__(512, 1) void k_knn(const float* __restrict__ p, int* __restrict__ idxOut)
{
  __shared__ f4 pq[8192];                 // 128 KB: (x,y,z,|c|^2)
  __shared__ u16 cand[8][8][120];         // 15 KB
  __shared__ double ckeyv[8][120];        // 7.5 KB
  const int tid = threadIdx.x, lane = tid & 63, w = tid >> 6;
  const int blk = blockIdx.x;
  const int b = blk >> 7;
  const int qbase = ((blk & 127) << 6) + (w << 3);
  const float* px = p + (long)b * 24576;
  const float* py = px + 8192;
  const float* pz = px + 16384;
  for (int t4 = tid; t4 < 2048; t4 += 512) {
    f4 x4 = *(const f4*)(px + t4 * 4);
    f4 y4 = *(const f4*)(py + t4 * 4);
    f4 z4 = *(const f4*)(pz + t4 * 4);
#pragma unroll
    for (int j = 0; j < 4; ++j) {
      float X = x4[j], Yv = y4[j], Z = z4[j];
      float s = fmaf(X, X, fmaf(Yv, Yv, Z * Z));
      f4 v; v[0] = X; v[1] = Yv; v[2] = Z; v[3] = s;
      pq[t4 * 4 + j] = v;
    }
  }
  __syncthreads();
  float qx2[8], qy2[8], qz2[8];
#pragma unroll
  for (int j = 0; j < 8; ++j) {
    f4 Q = pq[qbase + j];
    qx2[j] = Q[0] + Q[0]; qy2[j] = Q[1] + Q[1]; qz2[j] = Q[2] + Q[2];
  }
  float mx[8];
#pragma unroll
  for (int j = 0; j < 8; ++j) mx[j] = -3.0e38f;
#pragma unroll 4
  for (int t = 0; t < 128; ++t) {
    f4 c = pq[(t << 6) + lane];
#pragma unroll
    for (int j = 0; j < 8; ++j) {
      float v = fmaf(qx2[j], c[0], fmaf(qy2[j], c[1], fmaf(qz2[j], c[2], -c[3])));
      mx[j] = fmaxf(mx[j], v);
    }
  }
  float sv[8];
#pragma unroll
  for (int j = 0; j < 8; ++j) sv[j] = mx[j];
#pragma unroll
  for (int k = 2; k <= 64; k <<= 1) {
#pragma unroll
    for (int s = k >> 1; s > 0; s >>= 1) {
      const bool takeMin = (((lane & k) == 0) == ((lane & s) == 0));
#pragma unroll
      for (int j = 0; j < 8; ++j) {
        float o = __shfl_xor(sv[j], s);
        sv[j] = takeMin ? fminf(sv[j], o) : fmaxf(sv[j], o);
      }
    }
  }
  float T[8];
#pragma unroll
  for (int j = 0; j < 8; ++j) T[j] = __shfl(sv[j], 44) - 1e-3f;
  int cnt[8];
#pragma unroll
  for (int j = 0; j < 8; ++j) cnt[j] = 0;
#pragma unroll 4
  for (int t = 0; t < 128; ++t) {
    f4 c = pq[(t << 6) + lane];
#pragma unroll
    for (int j = 0; j < 8; ++j) {
      float v = fmaf(qx2[j], c[0], fmaf(qy2[j], c[1], fmaf(qz2[j], c[2], -c[3])));
      bool pr = (v >= T[j]);
      u64 ball = __ballot(pr);
      if (ball) {
        int ofs = (int)__popcll(ball & ((1ull << lane) - 1ull));
        int pos = cnt[j] + ofs;
        if (pr && pos < 120) cand[w][j][pos] = (u16)((t << 6) + lane);
        cnt[j] += (int)__popcll(ball);
      }
    }
  }
  asm volatile("s_waitcnt lgkmcnt(0)" ::: "memory");
  for (int j = 0; j < 8; ++j) {
    const int cn = cnt[j] > 120 ? 120 : cnt[j];
    f4 Q = pq[qbase + j];
    const double Qx = (double)Q[0], Qy = (double)Q[1], Qz = (double)Q[2];
    const double Qs = Qx * Qx + Qy * Qy + Qz * Qz;
    double myV[2]; int myI[2];
#pragma unroll
    for (int jj = 0; jj < 2; ++jj) {
      const int e = lane + (jj << 6);
      myV[jj] = -1.0e300; myI[jj] = 0x7FFFFFFF;
      if (e < cn) {
        const int ci = cand[w][j][e];
        f4 c = pq[ci];
        double cx = (double)c[0], cy = (double)c[1], cz = (double)c[2];
        double v = 2.0 * (Qx * cx + Qy * cy + Qz * cz) - Qs - (cx * cx + cy * cy + cz * cz);
        myV[jj] = v; myI[jj] = ci;
        ckeyv[w][e] = v;
      }
    }
    asm volatile("s_waitcnt lgkmcnt(0)" ::: "memory");
    int rk0 = 0, rk1 = 0;
#pragma unroll 4
    for (int e2 = 0; e2 < cn; ++e2) {
      double ov = ckeyv[w][e2];
      int oi = (int)cand[w][j][e2];
      rk0 += ((ov > myV[0]) || (ov == myV[0] && oi < myI[0])) ? 1 : 0;
      rk1 += ((ov > myV[1]) || (ov == myV[1] && oi < myI[1])) ? 1 : 0;
    }
    int* orow = idxOut + (((long)b << 13) + qbase + j) * 20;
    if (lane < cn && rk0 < 20) orow[rk0] = myI[0];
    if (lane + 64 < cn && rk1 < 20) orow[rk1] = myI[1];
  }
}

// ---------------- fused apply helpers ----------------
DEV float lky(float z) { return z > 0.f ? z : 0.2f * z; }

DEV i4v applyPack8(f4 a, f4 b4, const float* sc, const float* sh, int kb) {
  u16 r[8];
#pragma unroll
  for (int e = 0; e < 4; ++e) r[e] = f2b(lky(fmaf(sc[kb + e], a[e], sh[kb + e])));
#pragma unroll
  for (int e = 0; e < 4; ++e) r[4 + e] = f2b(lky(fmaf(sc[kb + 4 + e], b4[e], sh[kb + 4 + e])));
  i4v o;
#pragma unroll
  for (int e = 0; e < 4; ++e) o[e] = (int)((u32)r[2 * e] | ((u32)r[2 * e + 1] << 16));
  return o;
}

DEV i4v selPack8(f4 a, f4 b4, f4 a2, f4 b2, const float* sc, const float* sh, int kb) {
  u16 r[8];
#pragma unroll
  for (int e = 0; e < 4; ++e) {
    float s = sc[kb + e];
    float y = (s >= 0.f) ? a[e] : a2[e];
    r[e] = f2b(lky(fmaf(s, y, sh[kb + e])));
  }
#pragma unroll
  for (int e = 0; e < 4; ++e) {
    float s = sc[kb + 4 + e];
    float y = (s >= 0.f) ? b4[e] : b2[e];
    r[4 + e] = f2b(lky(fmaf(s, y, sh[kb + 4 + e])));
  }
  i4v o;
#pragma unroll
  for (int e = 0; e < 4; ++e) o[e] = (int)((u32)r[2 * e] | ((u32)r[2 * e + 1] << 16));
  return o;
}

// ---------------- bf16 MFMA GEMM: Y[b][n][o] = sum_k A[o][k]*Bapplied[b][n][k] ----------------
// BMODE 0: B0 is bf16 [n][K].  BMODE 1: B0 is f32 [n][K] + norm/leaky applied (K==256).
// BMODE 2: B0=EMAX,B1=EMIN f32 [n][K] + sign-select + norm/leaky (K==256).
// STATS: epilogue accumulates per-channel sum/sumsq of Y into gsums/gssq.
// BF16OUT: Y written as bf16 instead of f32.
template<int BMODE, int STATS, int BF16OUT>
__global__ __launch_bounds__(256, 2) void k_gemm(
    const u16* __restrict__ A, const void* __restrict__ B0v, const void* __restrict__ B1v,
    const float* __restrict__ sums, const float* __restrict__ ssq,
    const float* __restrict__ g, const float* __restrict__ bt, float invCount,
    float* __restrict__ gsums, float* __restrict__ gssq,
    void* __restrict__ Yv, int M, int K, long strideB, long strideY)
{
  __shared__ u16 sA[2][4096];
  __shared__ u16 sB[2][4096];
  __shared__ float scB[256], shB[256];
  __shared__ float s_sum[128], s_ssq[128];
  const int b = blockIdx.z;
  const int m0 = blockIdx.y * 128;
  const int n0 = blockIdx.x * 128;
  const int tid = threadIdx.x, lane = tid & 63, w = tid >> 6;
  const int wr = w >> 1, wc = w & 1;
  const int r15 = lane & 15, g8 = (lane >> 4) * 8;

  if (BMODE != 0) {
    float m = sums[tid] * invCount;
    float v = ssq[tid] * invCount - m * m;
    float s = g[tid] / sqrtf(v + 1e-5f);
    scB[tid] = s;
    shB[tid] = bt[tid] - m * s;
  }
  if (STATS) { if (tid < 128) { s_sum[tid] = 0.f; s_ssq[tid] = 0.f; } }
  if (BMODE != 0) __syncthreads();

  f4 acc[4][4];
#pragma unroll
  for (int i = 0; i < 4; ++i)
#pragma unroll
    for (int j = 0; j < 4; ++j) { f4 z = {0.f, 0.f, 0.f, 0.f}; acc[i][j] = z; }

  const int row0 = tid >> 2;            // 0..63
  const int kp0 = (tid & 3) << 3;       // 0,8,16,24
  const u16* gA0 = A + (long)(m0 + row0) * K + kp0;
  const u16* gA1 = A + (long)(m0 + row0 + 64) * K + kp0;
  const int ch0 = tid, ch1 = tid + 256;

  const u16* gB0 = (const u16*)B0v + (long)b * strideB + (long)(n0 + row0) * K + kp0;
  const u16* gB1 = gB0 + (long)64 * K;
  const float* fB0 = (const float*)B0v + (long)b * strideB + (long)(n0 + row0) * K + kp0;
  const float* fB1 = fB0 + (long)64 * K;
  const float* eB0 = (const float*)B1v + (long)b * strideB + (long)(n0 + row0) * K + kp0;
  const float* eB1 = eB0 + (long)64 * K;

  // prologue: stage k-tile 0
  ((i4v*)sA[0])[ch0] = *(const i4v*)gA0;
  ((i4v*)sA[0])[ch1] = *(const i4v*)gA1;
  if (BMODE == 0) {
    ((i4v*)sB[0])[ch0] = *(const i4v*)gB0;
    ((i4v*)sB[0])[ch1] = *(const i4v*)gB1;
  } else if (BMODE == 1) {
    ((i4v*)sB[0])[ch0] = applyPack8(*(const f4*)fB0, *(const f4*)(fB0 + 4), scB, shB, kp0);
    ((i4v*)sB[0])[ch1] = applyPack8(*(const f4*)fB1, *(const f4*)(fB1 + 4), scB, shB, kp0);
  } else {
    ((i4v*)sB[0])[ch0] = selPack8(*(const f4*)fB0, *(const f4*)(fB0 + 4),
                                  *(const f4*)eB0, *(const f4*)(eB0 + 4), scB, shB, kp0);
    ((i4v*)sB[0])[ch1] = selPack8(*(const f4*)fB1, *(const f4*)(fB1 + 4),
                                  *(const f4*)eB1, *(const f4*)(eB1 + 4), scB, shB, kp0);
  }
  __syncthreads();

  const int KT = K >> 5;
  int cur = 0;
  for (int kk = 0; kk < KT; ++kk) {
    const bool more = (kk + 1 < KT);
    i4v ra0, ra1, rb0, rb1;
    f4 p0a, p0b, p1a, p1b, q0a, q0b, q1a, q1b;
    if (more) {
      long ko = (long)(kk + 1) * 32;
      ra0 = *(const i4v*)(gA0 + ko); ra1 = *(const i4v*)(gA1 + ko);
      if (BMODE == 0) {
        rb0 = *(const i4v*)(gB0 + ko); rb1 = *(const i4v*)(gB1 + ko);
      } else {
        p0a = *(const f4*)(fB0 + ko); p0b = *(const f4*)(fB0 + ko + 4);
        p1a = *(const f4*)(fB1 + ko); p1b = *(const f4*)(fB1 + ko + 4);
        if (BMODE == 2) {
          q0a = *(const f4*)(eB0 + ko); q0b = *(const f4*)(eB0 + ko + 4);
          q1a = *(const f4*)(eB1 + ko); q1b = *(const f4*)(eB1 + ko + 4);
        }
      }
    }
    const u16* la = sA[cur];
    const u16* lb = sB[cur];
    s8 af[4], bfr[4];
#pragma unroll
    for (int mi = 0; mi < 4; ++mi)
      af[mi] = *(const s8*)(la + (wr * 64 + mi * 16 + r15) * 32 + g8);
#pragma unroll
    for (int ni = 0; ni < 4; ++ni)
      bfr[ni] = *(const s8*)(lb + (wc * 64 + ni * 16 + r15) * 32 + g8);
#pragma unroll
    for (int mi = 0; mi < 4; ++mi)
#pragma unroll
      for (int ni = 0; ni < 4; ++ni)
        acc[mi][ni] = __builtin_amdgcn_mfma_f32_16x16x32_bf16(af[mi], bfr[ni], acc[mi][ni], 0, 0, 0);
    if (more) {
      ((i4v*)sA[cur ^ 1])[ch0] = ra0; ((i4v*)sA[cur ^ 1])[ch1] = ra1;
      if (BMODE == 0) {
        ((i4v*)sB[cur ^ 1])[ch0] = rb0; ((i4v*)sB[cur ^ 1])[ch1] = rb1;
      } else {
        const int kb = (kk + 1) * 32 + kp0;
        if (BMODE == 1) {
          ((i4v*)sB[cur ^ 1])[ch0] = applyPack8(p0a, p0b, scB, shB, kb);
          ((i4v*)sB[cur ^ 1])[ch1] = applyPack8(p1a, p1b, scB, shB, kb);
        } else {
          ((i4v*)sB[cur ^ 1])[ch0] = selPack8(p0a, p0b, q0a, q0b, scB, shB, kb);
          ((i4v*)sB[cur ^ 1])[ch1] = selPack8(p1a, p1b, q1a, q1b, scB, shB, kb);
        }
      }
    }
    __syncthreads();
    cur ^= 1;
  }
  // epilogue: D col(n)=lane&15, row(o)=(lane>>4)*4+reg
  const int og = m0 + wr * 64 + (lane >> 4) * 4;
  const int ng = n0 + wc * 64 + r15;
  if (BF16OUT) {
    u16* Yp = (u16*)Yv + (long)b * strideY;
#pragma unroll
    for (int mi = 0; mi < 4; ++mi)
#pragma unroll
      for (int ni = 0; ni < 4; ++ni) {
        f4 a = acc[mi][ni];
        u16x4 r;
#pragma unroll
        for (int q = 0; q < 4; ++q) r[q] = f2b(a[q]);
        *(u16x4*)(Yp + (long)(ng + ni * 16) * M + og + mi * 16) = r;
      }
  } else {
    float* Yp = (float*)Yv + (long)b * strideY;
#pragma unroll
    for (int mi = 0; mi < 4; ++mi)
#pragma unroll
      for (int ni = 0; ni < 4; ++ni)
        *(f4*)(Yp + (long)(ng + ni * 16) * M + og + mi * 16) = acc[mi][ni];
  }
  if (STATS) {
#pragma unroll
    for (int mi = 0; mi < 4; ++mi)
#pragma unroll
      for (int j = 0; j < 4; ++j) {
        float s = 0.f, q = 0.f;
#pragma unroll
        for (int ni = 0; ni < 4; ++ni) {
          float v = acc[mi][ni][j];
          s += v; q = fmaf(v, v, q);
        }
#pragma unroll
        for (int off = 1; off < 16; off <<= 1) {
          s += __shfl_xor(s, off);
          q += __shfl_xor(q, off);
        }
        if ((lane & 15) == 0) {
          int lc = wr * 64 + (lane >> 4) * 4 + mi * 16 + j;
          atomicAdd(&s_sum[lc], s);
          atomicAdd(&s_ssq[lc], q);
        }
      }
    __syncthreads();
    if (tid < 128) {
      atomicAdd(&gsums[m0 + tid], s_sum[tid]);
      atomicAdd(&gssq[m0 + tid], s_ssq[tid]);
    }
  }
}

// ---------------- edgeconv gather (bf16 Y2): y = Anb[idx] + Cy; max/min + stats ----------------
__global__ __launch_bounds__(256, 2) void k_edge_gather(
    const u16* __restrict__ Y2, const int* __restrict__ idx,
    float* __restrict__ Emax, float* __restrict__ Emin,
    float* __restrict__ sums, float* __restrict__ ssq)
{
  __shared__ float s_sum[256], s_ssq[256];
  const int tid = threadIdx.x, lane = tid & 63, w = tid >> 6;
  s_sum[tid] = 0.f; s_ssq[tid] = 0.f;
  __syncthreads();
  const int ptBase = blockIdx.x * 64;
  f4 lsum = {0.f, 0.f, 0.f, 0.f}, lssq = {0.f, 0.f, 0.f, 0.f};
  for (int i = 0; i < 16; ++i) {
    const int pt = ptBase + w * 16 + i;
    const int b = pt >> 13;
    u16x4 cr = *(const u16x4*)(Y2 + (long)pt * 512 + 256 + (lane << 2));
    f4 ctr; ctr[0] = b2f(cr[0]); ctr[1] = b2f(cr[1]); ctr[2] = b2f(cr[2]); ctr[3] = b2f(cr[3]);
    const int* irow = idx + (long)pt * 20;
    f4 vmax = {-3.0e38f, -3.0e38f, -3.0e38f, -3.0e38f};
    f4 vmin = {3.0e38f, 3.0e38f, 3.0e38f, 3.0e38f};
#pragma unroll 4
    for (int k = 0; k < 20; ++k) {
      int m = irow[k];
      u16x4 nr = *(const u16x4*)(Y2 + (((long)b << 13) + m) * 512 + (lane << 2));
#pragma unroll
      for (int j = 0; j < 4; ++j) {
        float y = b2f(nr[j]) + ctr[j];
        vmax[j] = fmaxf(vmax[j], y);
        vmin[j] = fminf(vmin[j], y);
        lsum[j] += y;
        lssq[j] = fmaf(y, y, lssq[j]);
      }
    }
    *(f4*)(Emax + (long)pt * 256 + (lane << 2)) = vmax;
    *(f4*)(Emin + (long)pt * 256 + (lane << 2)) = vmin;
  }
#pragma unroll
  for (int j = 0; j < 4; ++j) {
    atomicAdd(&s_sum[(lane << 2) + j], lsum[j]);
    atomicAdd(&s_ssq[(lane << 2) + j], lssq[j]);
  }
  __syncthreads();
  atomicAdd(&sums[tid], s_sum[tid]);
  atomicAdd(&ssq[tid], s_ssq[tid]);
}

// ---------------- final: apply(norm3+leaky) + 50x128 proj + bias; Y4 read ONCE ----------------
// 1 wave / 64 points; all 50 outputs in registers; weights staged [ch][56] in LDS (broadcast reads).
__global__ __launch_bounds__(64) void k_final(
    const float* __restrict__ Y4, const float* __restrict__ sums, const float* __restrict__ ssq,
    const float* __restrict__ g, const float* __restrict__ bt,
    const float* __restrict__ wf, const float* __restrict__ bf,
    float* __restrict__ out)
{
  __shared__ float swf[128][56];   // [ch][o], o padded to 56 (16B-aligned rows)
  __shared__ float sc[128], sh[128], sb[52];
  const int lane = threadIdx.x;
  if (lane < 50) {
    const float* wrow = wf + lane * 128;
#pragma unroll 8
    for (int ch = 0; ch < 128; ++ch) swf[ch][lane] = wrow[ch];
    sb[lane] = bf[lane];
  } else if (lane < 52) {
#pragma unroll 8
    for (int ch = 0; ch < 128; ++ch) swf[ch][lane] = 0.f;
    sb[lane] = 0.f;
  }
#pragma unroll
  for (int t = 0; t < 2; ++t) {
    int ch = lane + t * 64;
    float m = sums[ch] * (1.0f / 16384.0f);
    float v = ssq[ch] * (1.0f / 16384.0f) - m * m;
    float s = g[ch] / sqrtf(v + 1e-5f);
    sc[ch] = s;
    sh[ch] = bt[ch] - m * s;
  }
  __syncthreads();
  const int b = blockIdx.y;
  const int n = blockIdx.x * 64 + lane;
  const float* hp = Y4 + ((long)b * 8192 + n) * 128;
  f4 av[13];
#pragma unroll
  for (int i = 0; i < 13; ++i) { f4 z = {0.f, 0.f, 0.f, 0.f}; av[i] = z; }
#pragma unroll 4
  for (int c4 = 0; c4 < 32; ++c4) {
    f4 hv = *(const f4*)(hp + c4 * 4);
#pragma unroll
    for (int e = 0; e < 4; ++e) {
      const int ch = c4 * 4 + e;
      float z = lky(fmaf(sc[ch], hv[e], sh[ch]));
#pragma unroll
      for (int o4 = 0; o4 < 13; ++o4) {
        f4 wv = *(const f4*)&swf[ch][o4 * 4];
#pragma unroll
        for (int q = 0; q < 4; ++q) av[o4][q] = fmaf(z, wv[q], av[o4][q]);
      }
    }
  }
  float* ob = out + (((long)b * 50) << 13) + n;
#pragma unroll
  for (int o4 = 0; o4 < 13; ++o4)
#pragma unroll
    for (int q = 0; q < 4; ++q) {
      int o = o4 * 4 + q;
      if (o < 50) ob[(long)o << 13] = av[o4][q] + sb[o];
    }
}

// ---------------- launcher ----------------
extern "C" void kernel_launch(void* const* d_in, const int* in_sizes, int n_in,
                              void* d_out, int out_size, void* d_ws, size_t ws_size,
                              hipStream_t stream)
{
  if ((long)ws_size < WS_NEED) return;
  const float* x   = (const float*)d_in[0];
  const float* p   = (const float*)d_in[1];
  const float* w1  = (const float*)d_in[2];
  const float* g1w = (const float*)d_in[4];
  const float* bt1 = (const float*)d_in[5];
  const float* we  = (const float*)d_in[6];
  const float* gew = (const float*)d_in[8];
  const float* bte = (const float*)d_in[9];
  const float* w2  = (const float*)d_in[10];
  const float* g2w = (const float*)d_in[12];
  const float* bt2 = (const float*)d_in[13];
  const float* w3  = (const float*)d_in[14];
  const float* g3w = (const float*)d_in[16];
  const float* bt3 = (const float*)d_in[17];
  const float* wf  = (const float*)d_in[18];
  const float* bfi = (const float*)d_in[19];

  char* ws = (char*)d_ws;
  u16* w1b   = (u16*)(ws + OFF_W1B);
  u16* weABb = (u16*)(ws + OFF_WEAB);
  u16* w2b   = (u16*)(ws + OFF_W2B);
  u16* w3b   = (u16*)(ws + OFF_W3B);
  int* idxb  = (int*)(ws + OFF_IDX);
  u16*   XT   = (u16*)(ws + OFF_XT);
  float* Y1   = (float*)(ws + OFF_Y1);
  u16*   Y2b  = (u16*)(ws + OFF_Y2);
  float* EMAX = (float*)(ws + OFF_EMAX);
  float* EMIN = (float*)(ws + OFF_EMIN);
  float* Y3   = (float*)(ws + OFF_Y3);
  float* Y4   = (float*)(ws + OFF_Y4);
  float* st0 = (float*)(ws + OFF_STATS);
  float* st1 = (float*)(ws + OFF_STATS + 4096);
  float* st2 = (float*)(ws + OFF_STATS + 8192);
  float* st3 = (float*)(ws + OFF_STATS + 12288);

  hipMemsetAsync(ws + OFF_STATS, 0, 16384, stream);
  k_convw<<<2112, 256, 0, stream>>>(w1, we, w2, w3, w1b, weABb, w2b, w3b);
  k_knn<<<256, 512, 0, stream>>>(p, idxb);
  k_xt<<<dim3(128, 19, 2), 256, 0, stream>>>(x, XT);

  // stage 1: smlp1d(x, w1) -> Y1 f32 + stats st0
  k_gemm<0, 1, 0><<<dim3(64, 2, 2), 256, 0, stream>>>(
      w1b, XT, nullptr, nullptr, nullptr, nullptr, nullptr, 0.f,
      st0, st0 + 256, Y1, 256, 1216, (long)8192 * 1216, (long)8192 * 256);

  // edge GEMM: B = apply1(Y1) fused -> Y2 bf16 [Anb | Cy]
  k_gemm<1, 0, 1><<<dim3(64, 4, 2), 256, 0, stream>>>(
      weABb, Y1, nullptr, st0, st0 + 256, g1w, bt1, 1.0f / 16384.0f,
      nullptr, nullptr, Y2b, 512, 256, (long)8192 * 256, (long)8192 * 512);

  // gather: max/min + stats st1
  k_edge_gather<<<256, 256, 0, stream>>>(Y2b, idxb, EMAX, EMIN, st1, st1 + 256);

  // stage 2: B = apply_edge(EMAX,EMIN) fused -> Y3 f32 + stats st2
  k_gemm<2, 1, 0><<<dim3(64, 2, 2), 256, 0, stream>>>(
      w2b, EMAX, EMIN, st1, st1 + 256, gew, bte, 1.0f / 327680.0f,
      st2, st2 + 256, Y3, 256, 256, (long)8192 * 256, (long)8192 * 256);

  // stage 3: B = apply2(Y3) fused -> Y4 f32 + stats st3
  k_gemm<1, 1, 0><<<dim3(64, 1, 2), 256, 0, stream>>>(
      w3b, Y3, nullptr, st2, st2 + 256, g2w, bt2, 1.0f / 16384.0f,
      st3, st3 + 256, Y4, 128, 256, (long)8192 * 256, (long)8192 * 128);

  // final: apply3 fused + projection (Y4 read once)
  k_final<<<dim3(128, 2), 64, 0, stream>>>(Y4, st3, st3 + 256, g3w, bt3, wf, bfi, (float*)d_out);
}

// Round 11
// 259.158 us; speedup vs baseline: 3.2324x; 1.0165x over previous
//
#include <hip/hip_runtime.h>

typedef unsigned short u16;
typedef unsigned int   u32;
typedef unsigned long long u64;
typedef __attribute__((ext_vector_type(4))) float f4;
typedef __attribute__((ext_vector_type(8))) short s8;
typedef __attribute__((ext_vector_type(4))) int   i4v;
typedef __attribute__((ext_vector_type(4))) unsigned short u16x4;

#define DEV __device__ __forceinline__

DEV u16 f2b(float f) {
  u32 u = __float_as_uint(f);
  return (u16)((u + 0x7FFFu + ((u >> 16) & 1u)) >> 16);
}
DEV float b2f(u16 h) { return __uint_as_float(((u32)h) << 16); }

// ---------------- workspace layout (bytes) ----------------
#define OFF_STATS 0L
#define OFF_W1B   65536L
#define OFF_WEAB  688128L
#define OFF_W2B   950272L
#define OFF_W3B   1081344L
#define OFF_IDX   1146880L
#define OFF_PQ    2457600L      /* 256 KB: (x,y,z,|c|^2) per point */
#define OFF_XT    4194304L      /* 39.8 MB bf16, dead after GEMM1 */
#define OFF_Y1    44040192L     /* 16.8 MB f32, dead after edge GEMM */
#define OFF_Y2    4194304L      /* 16.8 MB bf16 over dead XT, dead after gather */
#define OFF_EMAX  23068672L     /* 16.8 MB f32, dead after GEMM2 */
#define OFF_EMIN  41943040L     /* 16.8 MB f32 over dead Y1 tail */
#define OFF_Y3    4194304L      /* 16.8 MB f32 over dead Y2 */
#define OFF_Y4    23068672L     /* 8.4 MB f32 over dead EMAX */
#define WS_NEED   71303168L

// ---------------- weight convert -> bf16 (w1 | weA,weB-weA | w2 | w3) ----------------
__global__ __launch_bounds__(256) void k_convw(
    const float* __restrict__ w1, const float* __restrict__ we,
    const float* __restrict__ w2, const float* __restrict__ w3,
    u16* __restrict__ w1b, u16* __restrict__ weABb,
    u16* __restrict__ w2b, u16* __restrict__ w3b)
{
  int i = blockIdx.x * 256 + threadIdx.x;
  if (i < 311296) { w1b[i] = f2b(w1[i]); return; }
  i -= 311296;
  if (i < 131072) {
    int o = i >> 8, c = i & 255;
    float v = (o < 256) ? we[o * 512 + c]
                        : we[(o - 256) * 512 + 256 + c] - we[(o - 256) * 512 + c];
    weABb[i] = f2b(v); return;
  }
  i -= 131072;
  if (i < 65536) { w2b[i] = f2b(w2[i]); return; }
  i -= 65536;
  if (i < 32768) { w3b[i] = f2b(w3[i]); }
}

// ---------------- point prep: pqg[b][n] = (x,y,z,|c|^2) ----------------
__global__ __launch_bounds__(256) void k_prep(const float* __restrict__ p, f4* __restrict__ pqg)
{
  int i = blockIdx.x * 256 + threadIdx.x;   // 16384
  int b = i >> 13, n = i & 8191;
  const float* pb = p + (long)b * 24576;
  float X = pb[n], Y = pb[8192 + n], Z = pb[16384 + n];
  f4 v; v[0] = X; v[1] = Y; v[2] = Z; v[3] = fmaf(X, X, fmaf(Y, Y, Z * Z));
  pqg[i] = v;
}

// ---------------- x transpose + bf16: (B,1216,8192)f32 -> (B,8192,1216)bf16 ----------------
__global__ __launch_bounds__(256) void k_xt(const float* __restrict__ x, u16* __restrict__ xt)
{
  __shared__ float t[64][65];
  const int b = blockIdx.z, ct = blockIdx.y, nt = blockIdx.x;
  const int tx = threadIdx.x & 63, ty = threadIdx.x >> 6;
  const float* xb = x + (long)b * 1216 * 8192;
#pragma unroll
  for (int i = 0; i < 16; ++i) {
    int c = ct * 64 + ty + i * 4;
    t[ty + i * 4][tx] = xb[(long)c * 8192 + nt * 64 + tx];
  }
  __syncthreads();
  u16* xtb = xt + (long)b * 8192 * 1216;
#pragma unroll
  for (int i = 0; i < 16; ++i) {
    int n = nt * 64 + ty + i * 4;
    xtb[(long)n * 1216 + ct * 64 + tx] = f2b(t[tx][ty + i * 4]);
  }
}

// ---------------- exact KNN top-20: 4 q/wave, 4 waves/block, 1024 blocks ----------------
// Points read from global pqg (L2-resident, 128 KB/batch). Rank-based f64 re-rank.
__global__ __launch_bounds__(256) void k_knn(const f4* __restrict__ pqg, int* __restrict__ idxOut)
{
  __shared__ u16 cand[4][4][128];      // 4 KB: [wave][q][slot]
  __shared__ double ckeyv[4][128];     // 4 KB: per-wave exact values (reused per q)
  __shared__ int scnt[4][4];
  const int tid = threadIdx.x, lane = tid & 63, w = tid >> 6;
  const int blk = blockIdx.x;          // 1024
  const int b = blk >> 9;
  const int qbase = ((blk & 511) << 4) + (w << 2);
  const f4* __restrict__ P = pqg + ((long)b << 13);
  if (lane < 4) scnt[w][lane] = 0;
  float qx2[4], qy2[4], qz2[4];
#pragma unroll
  for (int j = 0; j < 4; ++j) {
    f4 Q = P[qbase + j];
    qx2[j] = Q[0] + Q[0]; qy2[j] = Q[1] + Q[1]; qz2[j] = Q[2] + Q[2];
  }
  // phase A: per-lane max of fast metric over this lane's 128 strided points, x4 queries
  float mx[4];
#pragma unroll
  for (int j = 0; j < 4; ++j) mx[j] = -3.0e38f;
#pragma unroll 4
  for (int t = 0; t < 128; ++t) {
    f4 c = P[(t << 6) + lane];
#pragma unroll
    for (int j = 0; j < 4; ++j) {
      float v = fmaf(qx2[j], c[0], fmaf(qy2[j], c[1], fmaf(qz2[j], c[2], -c[3])));
      mx[j] = fmaxf(mx[j], v);
    }
  }
  // interleaved bitonic sorts of the 64 lane-maxima; T = 20th largest (valid lower bound)
  float sv[4];
#pragma unroll
  for (int j = 0; j < 4; ++j) sv[j] = mx[j];
#pragma unroll
  for (int k = 2; k <= 64; k <<= 1) {
#pragma unroll
    for (int s = k >> 1; s > 0; s >>= 1) {
      const bool takeMin = (((lane & k) == 0) == ((lane & s) == 0));
#pragma unroll
      for (int j = 0; j < 4; ++j) {
        float o = __shfl_xor(sv[j], s);
        sv[j] = takeMin ? fminf(sv[j], o) : fmaxf(sv[j], o);
      }
    }
  }
  float T[4];
#pragma unroll
  for (int j = 0; j < 4; ++j) T[j] = __shfl(sv[j], 44) - 1e-3f;
  asm volatile("s_waitcnt lgkmcnt(0)" ::: "memory");
  // phase B: atomic-collect candidates (order-free; rank selection is order-independent)
#pragma unroll 2
  for (int t = 0; t < 128; ++t) {
    f4 c = P[(t << 6) + lane];
#pragma unroll
    for (int j = 0; j < 4; ++j) {
      float v = fmaf(qx2[j], c[0], fmaf(qy2[j], c[1], fmaf(qz2[j], c[2], -c[3])));
      if (v >= T[j]) {
        int pos = atomicAdd(&scnt[w][j], 1);
        if (pos < 128) cand[w][j][pos] = (u16)((t << 6) + lane);
      }
    }
  }
  asm volatile("s_waitcnt lgkmcnt(0)" ::: "memory");
  // phase C: f64-exact rank selection (matches f64 gold incl. (v desc, idx asc) ties)
  for (int j = 0; j < 4; ++j) {
    int cn = scnt[w][j]; if (cn > 128) cn = 128;
    f4 Q = P[qbase + j];
    const double Qx = (double)Q[0], Qy = (double)Q[1], Qz = (double)Q[2];
    const double Qs = Qx * Qx + Qy * Qy + Qz * Qz;
    double myV[2]; int myI[2];
#pragma unroll
    for (int jj = 0; jj < 2; ++jj) {
      const int e = lane + (jj << 6);
      myV[jj] = -1.0e300; myI[jj] = 0x7FFFFFFF;
      if (e < cn) {
        const int ci = cand[w][j][e];
        f4 c = P[ci];
        double cx = (double)c[0], cy = (double)c[1], cz = (double)c[2];
        double v = 2.0 * (Qx * cx + Qy * cy + Qz * cz) - Qs - (cx * cx + cy * cy + cz * cz);
        myV[jj] = v; myI[jj] = ci;
        ckeyv[w][e] = v;
      }
    }
    asm volatile("s_waitcnt lgkmcnt(0)" ::: "memory");
    int rk0 = 0, rk1 = 0;
#pragma unroll 4
    for (int e2 = 0; e2 < cn; ++e2) {
      double ov = ckeyv[w][e2];
      int oi = (int)cand[w][j][e2];
      rk0 += ((ov > myV[0]) || (ov == myV[0] && oi < myI[0])) ? 1 : 0;
      rk1 += ((ov > myV[1]) || (ov == myV[1] && oi < myI[1])) ? 1 : 0;
    }
    int* orow = idxOut + (((long)b << 13) + qbase + j) * 20;
    if (lane < cn && rk0 < 20) orow[rk0] = myI[0];
    if (lane + 64 < cn && rk1 < 20) orow[rk1] = myI[1];
    asm volatile("s_waitcnt lgkmcnt(0)" ::: "memory");
  }
}

// ---------------- fused apply helpers ----------------
DEV float lky(float z) { return z > 0.f ? z : 0.2f * z; }

DEV i4v applyPack8(f4 a, f4 b4, const float* sc, const float* sh, int kb) {
  u16 r[8];
#pragma unroll
  for (int e = 0; e < 4; ++e) r[e] = f2b(lky(fmaf(sc[kb + e], a[e], sh[kb + e])));
#pragma unroll
  for (int e = 0; e < 4; ++e) r[4 + e] = f2b(lky(fmaf(sc[kb + 4 + e], b4[e], sh[kb + 4 + e])));
  i4v o;
#pragma unroll
  for (int e = 0; e < 4; ++e) o[e] = (int)((u32)r[2 * e] | ((u32)r[2 * e + 1] << 16));
  return o;
}

DEV i4v selPack8(f4 a, f4 b4, f4 a2, f4 b2, const float* sc, const float* sh, int kb) {
  u16 r[8];
#pragma unroll
  for (int e = 0; e < 4; ++e) {
    float s = sc[kb + e];
    float y = (s >= 0.f) ? a[e] : a2[e];
    r[e] = f2b(lky(fmaf(s, y, sh[kb + e])));
  }
#pragma unroll
  for (int e = 0; e < 4; ++e) {
    float s = sc[kb + 4 + e];
    float y = (s >= 0.f) ? b4[e] : b2[e];
    r[4 + e] = f2b(lky(fmaf(s, y, sh[kb + 4 + e])));
  }
  i4v o;
#pragma unroll
  for (int e = 0; e < 4; ++e) o[e] = (int)((u32)r[2 * e] | ((u32)r[2 * e + 1] << 16));
  return o;
}

// ---------------- bf16 MFMA GEMM: Y[b][n][o] = sum_k A[o][k]*Bapplied[b][n][k] ----------------
template<int BMODE, int STATS, int BF16OUT>
__global__ __launch_bounds__(256, 2) void k_gemm(
    const u16* __restrict__ A, const void* __restrict__ B0v, const void* __restrict__ B1v,
    const float* __restrict__ sums, const float* __restrict__ ssq,
    const float* __restrict__ g, const float* __restrict__ bt, float invCount,
    float* __restrict__ gsums, float* __restrict__ gssq,
    void* __restrict__ Yv, int M, int K, long strideB, long strideY)
{
  __shared__ u16 sA[2][4096];
  __shared__ u16 sB[2][4096];
  __shared__ float scB[256], shB[256];
  __shared__ float s_sum[128], s_ssq[128];
  const int b = blockIdx.z;
  const int m0 = blockIdx.y * 128;
  const int n0 = blockIdx.x * 128;
  const int tid = threadIdx.x, lane = tid & 63, w = tid >> 6;
  const int wr = w >> 1, wc = w & 1;
  const int r15 = lane & 15, g8 = (lane >> 4) * 8;

  if (BMODE != 0) {
    float m = sums[tid] * invCount;
    float v = ssq[tid] * invCount - m * m;
    float s = g[tid] / sqrtf(v + 1e-5f);
    scB[tid] = s;
    shB[tid] = bt[tid] - m * s;
  }
  if (STATS) { if (tid < 128) { s_sum[tid] = 0.f; s_ssq[tid] = 0.f; } }
  if (BMODE != 0) __syncthreads();

  f4 acc[4][4];
#pragma unroll
  for (int i = 0; i < 4; ++i)
#pragma unroll
    for (int j = 0; j < 4; ++j) { f4 z = {0.f, 0.f, 0.f, 0.f}; acc[i][j] = z; }

  const int row0 = tid >> 2;            // 0..63
  const int kp0 = (tid & 3) << 3;       // 0,8,16,24
  const u16* gA0 = A + (long)(m0 + row0) * K + kp0;
  const u16* gA1 = A + (long)(m0 + row0 + 64) * K + kp0;
  const int ch0 = tid, ch1 = tid + 256;

  const u16* gB0 = (const u16*)B0v + (long)b * strideB + (long)(n0 + row0) * K + kp0;
  const u16* gB1 = gB0 + (long)64 * K;
  const float* fB0 = (const float*)B0v + (long)b * strideB + (long)(n0 + row0) * K + kp0;
  const float* fB1 = fB0 + (long)64 * K;
  const float* eB0 = (const float*)B1v + (long)b * strideB + (long)(n0 + row0) * K + kp0;
  const float* eB1 = eB0 + (long)64 * K;

  // prologue: stage k-tile 0
  ((i4v*)sA[0])[ch0] = *(const i4v*)gA0;
  ((i4v*)sA[0])[ch1] = *(const i4v*)gA1;
  if (BMODE == 0) {
    ((i4v*)sB[0])[ch0] = *(const i4v*)gB0;
    ((i4v*)sB[0])[ch1] = *(const i4v*)gB1;
  } else if (BMODE == 1) {
    ((i4v*)sB[0])[ch0] = applyPack8(*(const f4*)fB0, *(const f4*)(fB0 + 4), scB, shB, kp0);
    ((i4v*)sB[0])[ch1] = applyPack8(*(const f4*)fB1, *(const f4*)(fB1 + 4), scB, shB, kp0);
  } else {
    ((i4v*)sB[0])[ch0] = selPack8(*(const f4*)fB0, *(const f4*)(fB0 + 4),
                                  *(const f4*)eB0, *(const f4*)(eB0 + 4), scB, shB, kp0);
    ((i4v*)sB[0])[ch1] = selPack8(*(const f4*)fB1, *(const f4*)(fB1 + 4),
                                  *(const f4*)eB1, *(const f4*)(eB1 + 4), scB, shB, kp0);
  }
  __syncthreads();

  const int KT = K >> 5;
  int cur = 0;
  for (int kk = 0; kk < KT; ++kk) {
    const bool more = (kk + 1 < KT);
    i4v ra0, ra1, rb0, rb1;
    f4 p0a, p0b, p1a, p1b, q0a, q0b, q1a, q1b;
    if (more) {
      long ko = (long)(kk + 1) * 32;
      ra0 = *(const i4v*)(gA0 + ko); ra1 = *(const i4v*)(gA1 + ko);
      if (BMODE == 0) {
        rb0 = *(const i4v*)(gB0 + ko); rb1 = *(const i4v*)(gB1 + ko);
      } else {
        p0a = *(const f4*)(fB0 + ko); p0b = *(const f4*)(fB0 + ko + 4);
        p1a = *(const f4*)(fB1 + ko); p1b = *(const f4*)(fB1 + ko + 4);
        if (BMODE == 2) {
          q0a = *(const f4*)(eB0 + ko); q0b = *(const f4*)(eB0 + ko + 4);
          q1a = *(const f4*)(eB1 + ko); q1b = *(const f4*)(eB1 + ko + 4);
        }
      }
    }
    const u16* la = sA[cur];
    const u16* lb = sB[cur];
    s8 af[4], bfr[4];
#pragma unroll
    for (int mi = 0; mi < 4; ++mi)
      af[mi] = *(const s8*)(la + (wr * 64 + mi * 16 + r15) * 32 + g8);
#pragma unroll
    for (int ni = 0; ni < 4; ++ni)
      bfr[ni] = *(const s8*)(lb + (wc * 64 + ni * 16 + r15) * 32 + g8);
#pragma unroll
    for (int mi = 0; mi < 4; ++mi)
#pragma unroll
      for (int ni = 0; ni < 4; ++ni)
        acc[mi][ni] = __builtin_amdgcn_mfma_f32_16x16x32_bf16(af[mi], bfr[ni], acc[mi][ni], 0, 0, 0);
    if (more) {
      ((i4v*)sA[cur ^ 1])[ch0] = ra0; ((i4v*)sA[cur ^ 1])[ch1] = ra1;
      if (BMODE == 0) {
        ((i4v*)sB[cur ^ 1])[ch0] = rb0; ((i4v*)sB[cur ^ 1])[ch1] = rb1;
      } else {
        const int kb = (kk + 1) * 32 + kp0;
        if (BMODE == 1) {
          ((i4v*)sB[cur ^ 1])[ch0] = applyPack8(p0a, p0b, scB, shB, kb);
          ((i4v*)sB[cur ^ 1])[ch1] = applyPack8(p1a, p1b, scB, shB, kb);
        } else {
          ((i4v*)sB[cur ^ 1])[ch0] = selPack8(p0a, p0b, q0a, q0b, scB, shB, kb);
          ((i4v*)sB[cur ^ 1])[ch1] = selPack8(p1a, p1b, q1a, q1b, scB, shB, kb);
        }
      }
    }
    __syncthreads();
    cur ^= 1;
  }
  // epilogue: D col(n)=lane&15, row(o)=(lane>>4)*4+reg
  const int og = m0 + wr * 64 + (lane >> 4) * 4;
  const int ng = n0 + wc * 64 + r15;
  if (BF16OUT) {
    u16* Yp = (u16*)Yv + (long)b * strideY;
#pragma unroll
    for (int mi = 0; mi < 4; ++mi)
#pragma unroll
      for (int ni = 0; ni < 4; ++ni) {
        f4 a = acc[mi][ni];
        u16x4 r;
#pragma unroll
        for (int q = 0; q < 4; ++q) r[q] = f2b(a[q]);
        *(u16x4*)(Yp + (long)(ng + ni * 16) * M + og + mi * 16) = r;
      }
  } else {
    float* Yp = (float*)Yv + (long)b * strideY;
#pragma unroll
    for (int mi = 0; mi < 4; ++mi)
#pragma unroll
      for (int ni = 0; ni < 4; ++ni)
        *(f4*)(Yp + (long)(ng + ni * 16) * M + og + mi * 16) = acc[mi][ni];
  }
  if (STATS) {
#pragma unroll
    for (int mi = 0; mi < 4; ++mi)
#pragma unroll
      for (int j = 0; j < 4; ++j) {
        float s = 0.f, q = 0.f;
#pragma unroll
        for (int ni = 0; ni < 4; ++ni) {
          float v = acc[mi][ni][j];
          s += v; q = fmaf(v, v, q);
        }
#pragma unroll
        for (int off = 1; off < 16; off <<= 1) {
          s += __shfl_xor(s, off);
          q += __shfl_xor(q, off);
        }
        if ((lane & 15) == 0) {
          int lc = wr * 64 + (lane >> 4) * 4 + mi * 16 + j;
          atomicAdd(&s_sum[lc], s);
          atomicAdd(&s_ssq[lc], q);
        }
      }
    __syncthreads();
    if (tid < 128) {
      atomicAdd(&gsums[m0 + tid], s_sum[tid]);
      atomicAdd(&gssq[m0 + tid], s_ssq[tid]);
    }
  }
}

// ---------------- edgeconv gather (bf16 Y2): y = Anb[idx] + Cy; max/min + stats ----------------
__global__ __launch_bounds__(256, 2) void k_edge_gather(
    const u16* __restrict__ Y2, const int* __restrict__ idx,
    float* __restrict__ Emax, float* __restrict__ Emin,
    float* __restrict__ sums, float* __restrict__ ssq)
{
  __shared__ float s_sum[256], s_ssq[256];
  const int tid = threadIdx.x, lane = tid & 63, w = tid >> 6;
  s_sum[tid] = 0.f; s_ssq[tid] = 0.f;
  __syncthreads();
  const int ptBase = blockIdx.x * 64;
  f4 lsum = {0.f, 0.f, 0.f, 0.f}, lssq = {0.f, 0.f, 0.f, 0.f};
  for (int i = 0; i < 16; ++i) {
    const int pt = ptBase + w * 16 + i;
    const int b = pt >> 13;
    u16x4 cr = *(const u16x4*)(Y2 + (long)pt * 512 + 256 + (lane << 2));
    f4 ctr; ctr[0] = b2f(cr[0]); ctr[1] = b2f(cr[1]); ctr[2] = b2f(cr[2]); ctr[3] = b2f(cr[3]);
    const int* irow = idx + (long)pt * 20;
    f4 vmax = {-3.0e38f, -3.0e38f, -3.0e38f, -3.0e38f};
    f4 vmin = {3.0e38f, 3.0e38f, 3.0e38f, 3.0e38f};
#pragma unroll 4
    for (int k = 0; k < 20; ++k) {
      int m = irow[k];
      u16x4 nr = *(const u16x4*)(Y2 + (((long)b << 13) + m) * 512 + (lane << 2));
#pragma unroll
      for (int j = 0; j < 4; ++j) {
        float y = b2f(nr[j]) + ctr[j];
        vmax[j] = fmaxf(vmax[j], y);
        vmin[j] = fminf(vmin[j], y);
        lsum[j] += y;
        lssq[j] = fmaf(y, y, lssq[j]);
      }
    }
    *(f4*)(Emax + (long)pt * 256 + (lane << 2)) = vmax;
    *(f4*)(Emin + (long)pt * 256 + (lane << 2)) = vmin;
  }
#pragma unroll
  for (int j = 0; j < 4; ++j) {
    atomicAdd(&s_sum[(lane << 2) + j], lsum[j]);
    atomicAdd(&s_ssq[(lane << 2) + j], lssq[j]);
  }
  __syncthreads();
  atomicAdd(&sums[tid], s_sum[tid]);
  atomicAdd(&ssq[tid], s_ssq[tid]);
}

// ---------------- final: apply(norm3+leaky) + 50x128 proj + bias; Y4 read ONCE ----------------
__global__ __launch_bounds__(64) void k_final(
    const float* __restrict__ Y4, const float* __restrict__ sums, const float* __restrict__ ssq,
    const float* __restrict__ g, const float* __restrict__ bt,
    const float* __restrict__ wf, const float* __restrict__ bf,
    float* __restrict__ out)
{
  __shared__ float swf[128][56];   // [ch][o], o padded to 56 (16B-aligned rows)
  __shared__ float sc[128], sh[128], sb[52];
  const int lane = threadIdx.x;
  if (lane < 50) {
    const float* wrow = wf + lane * 128;
#pragma unroll 8
    for (int ch = 0; ch < 128; ++ch) swf[ch][lane] = wrow[ch];
    sb[lane] = bf[lane];
  } else if (lane < 52) {
#pragma unroll 8
    for (int ch = 0; ch < 128; ++ch) swf[ch][lane] = 0.f;
    sb[lane] = 0.f;
  }
#pragma unroll
  for (int t = 0; t < 2; ++t) {
    int ch = lane + t * 64;
    float m = sums[ch] * (1.0f / 16384.0f);
    float v = ssq[ch] * (1.0f / 16384.0f) - m * m;
    float s = g[ch] / sqrtf(v + 1e-5f);
    sc[ch] = s;
    sh[ch] = bt[ch] - m * s;
  }
  __syncthreads();
  const int b = blockIdx.y;
  const int n = blockIdx.x * 64 + lane;
  const float* hp = Y4 + ((long)b * 8192 + n) * 128;
  f4 av[13];
#pragma unroll
  for (int i = 0; i < 13; ++i) { f4 z = {0.f, 0.f, 0.f, 0.f}; av[i] = z; }
#pragma unroll 4
  for (int c4 = 0; c4 < 32; ++c4) {
    f4 hv = *(const f4*)(hp + c4 * 4);
#pragma unroll
    for (int e = 0; e < 4; ++e) {
      const int ch = c4 * 4 + e;
      float z = lky(fmaf(sc[ch], hv[e], sh[ch]));
#pragma unroll
      for (int o4 = 0; o4 < 13; ++o4) {
        f4 wv = *(const f4*)&swf[ch][o4 * 4];
#pragma unroll
        for (int q = 0; q < 4; ++q) av[o4][q] = fmaf(z, wv[q], av[o4][q]);
      }
    }
  }
  float* ob = out + (((long)b * 50) << 13) + n;
#pragma unroll
  for (int o4 = 0; o4 < 13; ++o4)
#pragma unroll
    for (int q = 0; q < 4; ++q) {
      int o = o4 * 4 + q;
      if (o < 50) ob[(long)o << 13] = av[o4][q] + sb[o];
    }
}

// ---------------- launcher ----------------
extern "C" void kernel_launch(void* const* d_in, const int* in_sizes, int n_in,
                              void* d_out, int out_size, void* d_ws, size_t ws_size,
                              hipStream_t stream)
{
  if ((long)ws_size < WS_NEED) return;
  const float* x   = (const float*)d_in[0];
  const float* p   = (const float*)d_in[1];
  const float* w1  = (const float*)d_in[2];
  const float* g1w = (const float*)d_in[4];
  const float* bt1 = (const float*)d_in[5];
  const float* we  = (const float*)d_in[6];
  const float* gew = (const float*)d_in[8];
  const float* bte = (const float*)d_in[9];
  const float* w2  = (const float*)d_in[10];
  const float* g2w = (const float*)d_in[12];
  const float* bt2 = (const float*)d_in[13];
  const float* w3  = (const float*)d_in[14];
  const float* g3w = (const float*)d_in[16];
  const float* bt3 = (const float*)d_in[17];
  const float* wf  = (const float*)d_in[18];
  const float* bfi = (const float*)d_in[19];

  char* ws = (char*)d_ws;
  u16* w1b   = (u16*)(ws + OFF_W1B);
  u16* weABb = (u16*)(ws + OFF_WEAB);
  u16* w2b   = (u16*)(ws + OFF_W2B);
  u16* w3b   = (u16*)(ws + OFF_W3B);
  int* idxb  = (int*)(ws + OFF_IDX);
  f4*  pqg   = (f4*)(ws + OFF_PQ);
  u16*   XT   = (u16*)(ws + OFF_XT);
  float* Y1   = (float*)(ws + OFF_Y1);
  u16*   Y2b  = (u16*)(ws + OFF_Y2);
  float* EMAX = (float*)(ws + OFF_EMAX);
  float* EMIN = (float*)(ws + OFF_EMIN);
  float* Y3   = (float*)(ws + OFF_Y3);
  float* Y4   = (float*)(ws + OFF_Y4);
  float* st0 = (float*)(ws + OFF_STATS);
  float* st1 = (float*)(ws + OFF_STATS + 4096);
  float* st2 = (float*)(ws + OFF_STATS + 8192);
  float* st3 = (float*)(ws + OFF_STATS + 12288);

  hipMemsetAsync(ws + OFF_STATS, 0, 16384, stream);
  k_convw<<<2112, 256, 0, stream>>>(w1, we, w2, w3, w1b, weABb, w2b, w3b);
  k_prep<<<64, 256, 0, stream>>>(p, pqg);
  k_knn<<<1024, 256, 0, stream>>>(pqg, idxb);
  k_xt<<<dim3(128, 19, 2), 256, 0, stream>>>(x, XT);

  // stage 1: smlp1d(x, w1) -> Y1 f32 + stats st0
  k_gemm<0, 1, 0><<<dim3(64, 2, 2), 256, 0, stream>>>(
      w1b, XT, nullptr, nullptr, nullptr, nullptr, nullptr, 0.f,
      st0, st0 + 256, Y1, 256, 1216, (long)8192 * 1216, (long)8192 * 256);

  // edge GEMM: B = apply1(Y1) fused -> Y2 bf16 [Anb | Cy]
  k_gemm<1, 0, 1><<<dim3(64, 4, 2), 256, 0, stream>>>(
      weABb, Y1, nullptr, st0, st0 + 256, g1w, bt1, 1.0f / 16384.0f,
      nullptr, nullptr, Y2b, 512, 256, (long)8192 * 256, (long)8192 * 512);

  // gather: max/min + stats st1
  k_edge_gather<<<256, 256, 0, stream>>>(Y2b, idxb, EMAX, EMIN, st1, st1 + 256);

  // stage 2: B = apply_edge(EMAX,EMIN) fused -> Y3 f32 + stats st2
  k_gemm<2, 1, 0><<<dim3(64, 2, 2), 256, 0, stream>>>(
      w2b, EMAX, EMIN, st1, st1 + 256, gew, bte, 1.0f / 327680.0f,
      st2, st2 + 256, Y3, 256, 256, (long)8192 * 256, (long)8192 * 256);

  // stage 3: B = apply2(Y3) fused -> Y4 f32 + stats st3
  k_gemm<1, 1, 0><<<dim3(64, 1, 2), 256, 0, stream>>>(
      w3b, Y3, nullptr, st2, st2 + 256, g2w, bt2, 1.0f / 16384.0f,
      st3, st3 + 256, Y4, 128, 256, (long)8192 * 256, (long)8192 * 128);

  // final: apply3 fused + projection (Y4 read once)
  k_final<<<dim3(128, 2), 64, 0, stream>>>(Y4, st3, st3 + 256, g3w, bt3, wf, bfi, (float*)d_out);
}

// Round 12
// 235.462 us; speedup vs baseline: 3.5576x; 1.1006x over previous
//
#include <hip/hip_runtime.h>

typedef unsigned short u16;
typedef unsigned int   u32;
typedef unsigned long long u64;
typedef __attribute__((ext_vector_type(4))) float f4;
typedef __attribute__((ext_vector_type(8))) short s8;
typedef __attribute__((ext_vector_type(4))) int   i4v;
typedef __attribute__((ext_vector_type(4))) unsigned short u16x4;

#define DEV __device__ __forceinline__

DEV u16 f2b(float f) {
  u32 u = __float_as_uint(f);
  return (u16)((u + 0x7FFFu + ((u >> 16) & 1u)) >> 16);
}
DEV float b2f(u16 h) { return __uint_as_float(((u32)h) << 16); }

// ---------------- workspace layout (bytes) ----------------
#define OFF_STATS 0L
#define OFF_W1B   65536L
#define OFF_WEAB  688128L
#define OFF_W2B   950272L
#define OFF_W3B   1081344L
#define OFF_IDX   1146880L
#define OFF_PQ    2457600L      /* 256 KB: (x,y,z,|c|^2) per point */
#define OFF_XT    4194304L      /* 39.8 MB bf16, dead after GEMM1 */
#define OFF_Y1    44040192L     /* 16.8 MB f32, dead after edge GEMM */
#define OFF_Y2    4194304L      /* 16.8 MB bf16 over dead XT, dead after gather */
#define OFF_EMAX  23068672L     /* 8.4 MB bf16, dead after GEMM2 */
#define OFF_EMIN  41943040L     /* 8.4 MB bf16 */
#define OFF_Y3    4194304L      /* 16.8 MB f32 over dead Y2 */
#define OFF_Y4    23068672L     /* 8.4 MB f32 over dead EMAX */
#define WS_NEED   71303168L

// ---------------- weight convert -> bf16 (w1 | weA,weB-weA | w2 | w3) ----------------
__global__ __launch_bounds__(256) void k_convw(
    const float* __restrict__ w1, const float* __restrict__ we,
    const float* __restrict__ w2, const float* __restrict__ w3,
    u16* __restrict__ w1b, u16* __restrict__ weABb,
    u16* __restrict__ w2b, u16* __restrict__ w3b)
{
  int i = blockIdx.x * 256 + threadIdx.x;
  if (i < 311296) { w1b[i] = f2b(w1[i]); return; }
  i -= 311296;
  if (i < 131072) {
    int o = i >> 8, c = i & 255;
    float v = (o < 256) ? we[o * 512 + c]
                        : we[(o - 256) * 512 + 256 + c] - we[(o - 256) * 512 + c];
    weABb[i] = f2b(v); return;
  }
  i -= 131072;
  if (i < 65536) { w2b[i] = f2b(w2[i]); return; }
  i -= 65536;
  if (i < 32768) { w3b[i] = f2b(w3[i]); }
}

// ---------------- point prep: pqg[b][n] = (x,y,z,|c|^2) ----------------
__global__ __launch_bounds__(256) void k_prep(const float* __restrict__ p, f4* __restrict__ pqg)
{
  int i = blockIdx.x * 256 + threadIdx.x;   // 16384
  int b = i >> 13, n = i & 8191;
  const float* pb = p + (long)b * 24576;
  float X = pb[n], Y = pb[8192 + n], Z = pb[16384 + n];
  f4 v; v[0] = X; v[1] = Y; v[2] = Z; v[3] = fmaf(X, X, fmaf(Y, Y, Z * Z));
  pqg[i] = v;
}

// ---------------- x transpose + bf16: (B,1216,8192)f32 -> (B,8192,1216)bf16 ----------------
__global__ __launch_bounds__(256) void k_xt(const float* __restrict__ x, u16* __restrict__ xt)
{
  __shared__ float t[64][65];
  const int b = blockIdx.z, ct = blockIdx.y, nt = blockIdx.x;
  const int tx = threadIdx.x & 63, ty = threadIdx.x >> 6;
  const float* xb = x + (long)b * 1216 * 8192;
#pragma unroll
  for (int i = 0; i < 16; ++i) {
    int c = ct * 64 + ty + i * 4;
    t[ty + i * 4][tx] = xb[(long)c * 8192 + nt * 64 + tx];
  }
  __syncthreads();
  u16* xtb = xt + (long)b * 8192 * 1216;
#pragma unroll
  for (int i = 0; i < 16; ++i) {
    int n = nt * 64 + ty + i * 4;
    xtb[(long)n * 1216 + ct * 64 + tx] = f2b(t[tx][ty + i * 4]);
  }
}

// ---------------- exact KNN top-20: 4 q/wave, chunk-LDS shared across 4 waves ----------------
__global__ __launch_bounds__(256) void k_knn(const f4* __restrict__ pqg, int* __restrict__ idxOut)
{
  __shared__ f4 chunk[1024];           // 16 KB, shared by all 4 waves
  __shared__ u16 cand[4][4][128];      // 4 KB
  __shared__ double ckeyv[4][128];     // 4 KB
  __shared__ int scnt[4][4];
  const int tid = threadIdx.x, lane = tid & 63, w = tid >> 6;
  const int blk = blockIdx.x;          // 1024
  const int b = blk >> 9;
  const int qbase = ((blk & 511) << 4) + (w << 2);
  const f4* __restrict__ P = pqg + ((long)b << 13);
  if (lane < 4) scnt[w][lane] = 0;
  float qx2[4], qy2[4], qz2[4];
#pragma unroll
  for (int j = 0; j < 4; ++j) {
    f4 Q = P[qbase + j];
    qx2[j] = Q[0] + Q[0]; qy2[j] = Q[1] + Q[1]; qz2[j] = Q[2] + Q[2];
  }
  // phase A: chunked scan, per-lane max of fast metric, x4 queries
  float mx[4];
#pragma unroll
  for (int j = 0; j < 4; ++j) mx[j] = -3.0e38f;
  for (int c = 0; c < 8; ++c) {
    __syncthreads();
#pragma unroll
    for (int i = 0; i < 4; ++i) chunk[tid + i * 256] = P[c * 1024 + tid + i * 256];
    __syncthreads();
#pragma unroll 2
    for (int t = 0; t < 16; ++t) {
      f4 cc = chunk[(t << 6) + lane];
#pragma unroll
      for (int j = 0; j < 4; ++j) {
        float v = fmaf(qx2[j], cc[0], fmaf(qy2[j], cc[1], fmaf(qz2[j], cc[2], -cc[3])));
        mx[j] = fmaxf(mx[j], v);
      }
    }
  }
  // interleaved bitonic sorts of the 64 lane-maxima; T = 20th largest (valid lower bound)
  float sv[4];
#pragma unroll
  for (int j = 0; j < 4; ++j) sv[j] = mx[j];
#pragma unroll
  for (int k = 2; k <= 64; k <<= 1) {
#pragma unroll
    for (int s = k >> 1; s > 0; s >>= 1) {
      const bool takeMin = (((lane & k) == 0) == ((lane & s) == 0));
#pragma unroll
      for (int j = 0; j < 4; ++j) {
        float o = __shfl_xor(sv[j], s);
        sv[j] = takeMin ? fminf(sv[j], o) : fmaxf(sv[j], o);
      }
    }
  }
  float T[4];
#pragma unroll
  for (int j = 0; j < 4; ++j) T[j] = __shfl(sv[j], 44) - 1e-3f;
  // phase B: chunked atomic-collect (order-free; rank selection is order-independent)
  for (int c = 0; c < 8; ++c) {
    __syncthreads();
#pragma unroll
    for (int i = 0; i < 4; ++i) chunk[tid + i * 256] = P[c * 1024 + tid + i * 256];
    __syncthreads();
#pragma unroll 2
    for (int t = 0; t < 16; ++t) {
      f4 cc = chunk[(t << 6) + lane];
#pragma unroll
      for (int j = 0; j < 4; ++j) {
        float v = fmaf(qx2[j], cc[0], fmaf(qy2[j], cc[1], fmaf(qz2[j], cc[2], -cc[3])));
        if (v >= T[j]) {
          int pos = atomicAdd(&scnt[w][j], 1);
          if (pos < 128) cand[w][j][pos] = (u16)(c * 1024 + (t << 6) + lane);
        }
      }
    }
  }
  asm volatile("s_waitcnt lgkmcnt(0)" ::: "memory");
  // phase C: f64-exact rank selection (matches f64 gold incl. (v desc, idx asc) ties)
  for (int j = 0; j < 4; ++j) {
    int cn = scnt[w][j]; if (cn > 128) cn = 128;
    f4 Q = P[qbase + j];
    const double Qx = (double)Q[0], Qy = (double)Q[1], Qz = (double)Q[2];
    const double Qs = Qx * Qx + Qy * Qy + Qz * Qz;
    double myV[2]; int myI[2];
#pragma unroll
    for (int jj = 0; jj < 2; ++jj) {
      const int e = lane + (jj << 6);
      myV[jj] = -1.0e300; myI[jj] = 0x7FFFFFFF;
      if (e < cn) {
        const int ci = cand[w][j][e];
        f4 c = P[ci];
        double cx = (double)c[0], cy = (double)c[1], cz = (double)c[2];
        double v = 2.0 * (Qx * cx + Qy * cy + Qz * cz) - Qs - (cx * cx + cy * cy + cz * cz);
        myV[jj] = v; myI[jj] = ci;
        ckeyv[w][e] = v;
      }
    }
    asm volatile("s_waitcnt lgkmcnt(0)" ::: "memory");
    int rk0 = 0, rk1 = 0;
#pragma unroll 4
    for (int e2 = 0; e2 < cn; ++e2) {
      double ov = ckeyv[w][e2];
      int oi = (int)cand[w][j][e2];
      rk0 += ((ov > myV[0]) || (ov == myV[0] && oi < myI[0])) ? 1 : 0;
      rk1 += ((ov > myV[1]) || (ov == myV[1] && oi < myI[1])) ? 1 : 0;
    }
    int* orow = idxOut + (((long)b << 13) + qbase + j) * 20;
    if (lane < cn && rk0 < 20) orow[rk0] = myI[0];
    if (lane + 64 < cn && rk1 < 20) orow[rk1] = myI[1];
    asm volatile("s_waitcnt lgkmcnt(0)" ::: "memory");
  }
}

// ---------------- fused apply helpers ----------------
DEV float lky(float z) { return z > 0.f ? z : 0.2f * z; }

DEV i4v applyPack8(f4 a, f4 b4, const float* sc, const float* sh, int kb) {
  u16 r[8];
#pragma unroll
  for (int e = 0; e < 4; ++e) r[e] = f2b(lky(fmaf(sc[kb + e], a[e], sh[kb + e])));
#pragma unroll
  for (int e = 0; e < 4; ++e) r[4 + e] = f2b(lky(fmaf(sc[kb + 4 + e], b4[e], sh[kb + 4 + e])));
  i4v o;
#pragma unroll
  for (int e = 0; e < 4; ++e) o[e] = (int)((u32)r[2 * e] | ((u32)r[2 * e + 1] << 16));
  return o;
}

// bf16 EMAX/EMIN variant: rawM/rawN each hold 8 bf16 channels
DEV i4v selPack8b(i4v rawM, i4v rawN, const float* sc, const float* sh, int kb) {
  u16 r[8];
#pragma unroll
  for (int e = 0; e < 8; ++e) {
    u32 dM = (u32)rawM[e >> 1], dN = (u32)rawN[e >> 1];
    u16 hM = (e & 1) ? (u16)(dM >> 16) : (u16)(dM & 0xFFFFu);
    u16 hN = (e & 1) ? (u16)(dN >> 16) : (u16)(dN & 0xFFFFu);
    float s = sc[kb + e];
    float y = (s >= 0.f) ? b2f(hM) : b2f(hN);
    r[e] = f2b(lky(fmaf(s, y, sh[kb + e])));
  }
  i4v o;
#pragma unroll
  for (int e = 0; e < 4; ++e) o[e] = (int)((u32)r[2 * e] | ((u32)r[2 * e + 1] << 16));
  return o;
}

// ---------------- bf16 MFMA GEMM: Y[b][n][o] = sum_k A[o][k]*Bapplied[b][n][k] ----------------
// BMODE 0: B0 bf16 [n][K]. BMODE 1: B0 f32 [n][K] + norm/leaky (K==256).
// BMODE 2: B0=EMAX,B1=EMIN bf16 [n][K] + sign-select + norm/leaky (K==256).
template<int BMODE, int STATS, int BF16OUT>
__global__ __launch_bounds__(256, 2) void k_gemm(
    const u16* __restrict__ A, const void* __restrict__ B0v, const void* __restrict__ B1v,
    const float* __restrict__ sums, const float* __restrict__ ssq,
    const float* __restrict__ g, const float* __restrict__ bt, float invCount,
    float* __restrict__ gsums, float* __restrict__ gssq,
    void* __restrict__ Yv, int M, int K, long strideB, long strideY)
{
  __shared__ u16 sA[2][4096];
  __shared__ u16 sB[2][4096];
  __shared__ float scB[256], shB[256];
  __shared__ float s_sum[128], s_ssq[128];
  const int b = blockIdx.z;
  const int m0 = blockIdx.y * 128;
  const int n0 = blockIdx.x * 128;
  const int tid = threadIdx.x, lane = tid & 63, w = tid >> 6;
  const int wr = w >> 1, wc = w & 1;
  const int r15 = lane & 15, g8 = (lane >> 4) * 8;

  if (BMODE != 0) {
    float m = sums[tid] * invCount;
    float v = ssq[tid] * invCount - m * m;
    float s = g[tid] / sqrtf(v + 1e-5f);
    scB[tid] = s;
    shB[tid] = bt[tid] - m * s;
  }
  if (STATS) { if (tid < 128) { s_sum[tid] = 0.f; s_ssq[tid] = 0.f; } }
  if (BMODE != 0) __syncthreads();

  f4 acc[4][4];
#pragma unroll
  for (int i = 0; i < 4; ++i)
#pragma unroll
    for (int j = 0; j < 4; ++j) { f4 z = {0.f, 0.f, 0.f, 0.f}; acc[i][j] = z; }

  const int row0 = tid >> 2;            // 0..63
  const int kp0 = (tid & 3) << 3;       // 0,8,16,24
  const u16* gA0 = A + (long)(m0 + row0) * K + kp0;
  const u16* gA1 = A + (long)(m0 + row0 + 64) * K + kp0;
  const int ch0 = tid, ch1 = tid + 256;

  const u16* gB0 = (const u16*)B0v + (long)b * strideB + (long)(n0 + row0) * K + kp0;
  const u16* gB1 = gB0 + (long)64 * K;
  const float* fB0 = (const float*)B0v + (long)b * strideB + (long)(n0 + row0) * K + kp0;
  const float* fB1 = fB0 + (long)64 * K;
  const u16* nB0 = (const u16*)B1v + (long)b * strideB + (long)(n0 + row0) * K + kp0;
  const u16* nB1 = nB0 + (long)64 * K;

  // prologue: stage k-tile 0
  ((i4v*)sA[0])[ch0] = *(const i4v*)gA0;
  ((i4v*)sA[0])[ch1] = *(const i4v*)gA1;
  if (BMODE == 0) {
    ((i4v*)sB[0])[ch0] = *(const i4v*)gB0;
    ((i4v*)sB[0])[ch1] = *(const i4v*)gB1;
  } else if (BMODE == 1) {
    ((i4v*)sB[0])[ch0] = applyPack8(*(const f4*)fB0, *(const f4*)(fB0 + 4), scB, shB, kp0);
    ((i4v*)sB[0])[ch1] = applyPack8(*(const f4*)fB1, *(const f4*)(fB1 + 4), scB, shB, kp0);
  } else {
    ((i4v*)sB[0])[ch0] = selPack8b(*(const i4v*)gB0, *(const i4v*)nB0, scB, shB, kp0);
    ((i4v*)sB[0])[ch1] = selPack8b(*(const i4v*)gB1, *(const i4v*)nB1, scB, shB, kp0);
  }
  __syncthreads();

  const int KT = K >> 5;
  int cur = 0;
  for (int kk = 0; kk < KT; ++kk) {
    const bool more = (kk + 1 < KT);
    i4v ra0, ra1, rb0, rb1, rn0, rn1;
    f4 p0a, p0b, p1a, p1b;
    if (more) {
      long ko = (long)(kk + 1) * 32;
      ra0 = *(const i4v*)(gA0 + ko); ra1 = *(const i4v*)(gA1 + ko);
      if (BMODE == 0) {
        rb0 = *(const i4v*)(gB0 + ko); rb1 = *(const i4v*)(gB1 + ko);
      } else if (BMODE == 1) {
        p0a = *(const f4*)(fB0 + ko); p0b = *(const f4*)(fB0 + ko + 4);
        p1a = *(const f4*)(fB1 + ko); p1b = *(const f4*)(fB1 + ko + 4);
      } else {
        rb0 = *(const i4v*)(gB0 + ko); rb1 = *(const i4v*)(gB1 + ko);
        rn0 = *(const i4v*)(nB0 + ko); rn1 = *(const i4v*)(nB1 + ko);
      }
    }
    const u16* la = sA[cur];
    const u16* lb = sB[cur];
    s8 af[4], bfr[4];
#pragma unroll
    for (int mi = 0; mi < 4; ++mi)
      af[mi] = *(const s8*)(la + (wr * 64 + mi * 16 + r15) * 32 + g8);
#pragma unroll
    for (int ni = 0; ni < 4; ++ni)
      bfr[ni] = *(const s8*)(lb + (wc * 64 + ni * 16 + r15) * 32 + g8);
#pragma unroll
    for (int mi = 0; mi < 4; ++mi)
#pragma unroll
      for (int ni = 0; ni < 4; ++ni)
        acc[mi][ni] = __builtin_amdgcn_mfma_f32_16x16x32_bf16(af[mi], bfr[ni], acc[mi][ni], 0, 0, 0);
    if (more) {
      ((i4v*)sA[cur ^ 1])[ch0] = ra0; ((i4v*)sA[cur ^ 1])[ch1] = ra1;
      if (BMODE == 0) {
        ((i4v*)sB[cur ^ 1])[ch0] = rb0; ((i4v*)sB[cur ^ 1])[ch1] = rb1;
      } else if (BMODE == 1) {
        const int kb = (kk + 1) * 32 + kp0;
        ((i4v*)sB[cur ^ 1])[ch0] = applyPack8(p0a, p0b, scB, shB, kb);
        ((i4v*)sB[cur ^ 1])[ch1] = applyPack8(p1a, p1b, scB, shB, kb);
      } else {
        const int kb = (kk + 1) * 32 + kp0;
        ((i4v*)sB[cur ^ 1])[ch0] = selPack8b(rb0, rn0, scB, shB, kb);
        ((i4v*)sB[cur ^ 1])[ch1] = selPack8b(rb1, rn1, scB, shB, kb);
      }
    }
    __syncthreads();
    cur ^= 1;
  }
  // epilogue: D col(n)=lane&15, row(o)=(lane>>4)*4+reg
  const int og = m0 + wr * 64 + (lane >> 4) * 4;
  const int ng = n0 + wc * 64 + r15;
  if (BF16OUT) {
    u16* Yp = (u16*)Yv + (long)b * strideY;
#pragma unroll
    for (int mi = 0; mi < 4; ++mi)
#pragma unroll
      for (int ni = 0; ni < 4; ++ni) {
        f4 a = acc[mi][ni];
        u16x4 r;
#pragma unroll
        for (int q = 0; q < 4; ++q) r[q] = f2b(a[q]);
        *(u16x4*)(Yp + (long)(ng + ni * 16) * M + og + mi * 16) = r;
      }
  } else {
    float* Yp = (float*)Yv + (long)b * strideY;
#pragma unroll
    for (int mi = 0; mi < 4; ++mi)
#pragma unroll
      for (int ni = 0; ni < 4; ++ni)
        *(f4*)(Yp + (long)(ng + ni * 16) * M + og + mi * 16) = acc[mi][ni];
  }
  if (STATS) {
#pragma unroll
    for (int mi = 0; mi < 4; ++mi)
#pragma unroll
      for (int j = 0; j < 4; ++j) {
        float s = 0.f, q = 0.f;
#pragma unroll
        for (int ni = 0; ni < 4; ++ni) {
          float v = acc[mi][ni][j];
          s += v; q = fmaf(v, v, q);
        }
#pragma unroll
        for (int off = 1; off < 16; off <<= 1) {
          s += __shfl_xor(s, off);
          q += __shfl_xor(q, off);
        }
        if ((lane & 15) == 0) {
          int lc = wr * 64 + (lane >> 4) * 4 + mi * 16 + j;
          atomicAdd(&s_sum[lc], s);
          atomicAdd(&s_ssq[lc], q);
        }
      }
    __syncthreads();
    if (tid < 128) {
      atomicAdd(&gsums[m0 + tid], s_sum[tid]);
      atomicAdd(&gssq[m0 + tid], s_ssq[tid]);
    }
  }
}

// ---------------- edgeconv gather, channel-split for L2 residency ----------------
// grid (128 ptBlocks, 2 ch-halves, 2 batches); block = 64 pts x 128 ch; bf16 E out.
__global__ __launch_bounds__(256, 2) void k_edge_gather(
    const u16* __restrict__ Y2, const int* __restrict__ idx,
    u16* __restrict__ Emax, u16* __restrict__ Emin,
    float* __restrict__ sums, float* __restrict__ ssq)
{
  __shared__ float s_sum[256], s_ssq[256];
  const int tid = threadIdx.x, lane = tid & 63, w = tid >> 6;
  s_sum[tid] = 0.f; s_ssq[tid] = 0.f;
  __syncthreads();
  const int half = blockIdx.y, b = blockIdx.z;
  const int ptBase = blockIdx.x * 64 + w * 16;
  const int sub = lane >> 5;          // point within pair
  const int chOff = half * 128 + ((lane & 31) << 2);
  f4 lsum = {0.f, 0.f, 0.f, 0.f}, lssq = {0.f, 0.f, 0.f, 0.f};
  for (int i = 0; i < 8; ++i) {
    const int pt = ptBase + i * 2 + sub;
    const long gp = (long)b * 8192 + pt;
    u16x4 cr = *(const u16x4*)(Y2 + gp * 512 + 256 + chOff);
    f4 ctr; ctr[0] = b2f(cr[0]); ctr[1] = b2f(cr[1]); ctr[2] = b2f(cr[2]); ctr[3] = b2f(cr[3]);
    const int* irow = idx + gp * 20;
    f4 vmax = {-3.0e38f, -3.0e38f, -3.0e38f, -3.0e38f};
    f4 vmin = {3.0e38f, 3.0e38f, 3.0e38f, 3.0e38f};
#pragma unroll 4
    for (int k = 0; k < 20; ++k) {
      int m = irow[k];
      u16x4 nr = *(const u16x4*)(Y2 + ((long)b * 8192 + m) * 512 + chOff);
#pragma unroll
      for (int j = 0; j < 4; ++j) {
        float y = b2f(nr[j]) + ctr[j];
        vmax[j] = fmaxf(vmax[j], y);
        vmin[j] = fminf(vmin[j], y);
        lsum[j] += y;
        lssq[j] = fmaf(y, y, lssq[j]);
      }
    }
    u16x4 eM, eN;
#pragma unroll
    for (int j = 0; j < 4; ++j) { eM[j] = f2b(vmax[j]); eN[j] = f2b(vmin[j]); }
    *(u16x4*)(Emax + gp * 256 + chOff) = eM;
    *(u16x4*)(Emin + gp * 256 + chOff) = eN;
  }
#pragma unroll
  for (int j = 0; j < 4; ++j) {
    atomicAdd(&s_sum[chOff + j], lsum[j]);
    atomicAdd(&s_ssq[chOff + j], lssq[j]);
  }
  __syncthreads();
  atomicAdd(&sums[tid], s_sum[tid]);
  atomicAdd(&ssq[tid], s_ssq[tid]);
}

// ---------------- final: apply(norm3+leaky) + 50x128 proj + bias; Y4 read ONCE ----------------
__global__ __launch_bounds__(64) void k_final(
    const float* __restrict__ Y4, const float* __restrict__ sums, const float* __restrict__ ssq,
    const float* __restrict__ g, const float* __restrict__ bt,
    const float* __restrict__ wf, const float* __restrict__ bf,
    float* __restrict__ out)
{
  __shared__ float swf[128][56];   // [ch][o], o padded to 56
  __shared__ float sc[128], sh[128], sb[52];
  const int lane = threadIdx.x;
  if (lane < 50) {
    const float* wrow = wf + lane * 128;
#pragma unroll 8
    for (int ch = 0; ch < 128; ++ch) swf[ch][lane] = wrow[ch];
    sb[lane] = bf[lane];
  } else if (lane < 52) {
#pragma unroll 8
    for (int ch = 0; ch < 128; ++ch) swf[ch][lane] = 0.f;
    sb[lane] = 0.f;
  }
#pragma unroll
  for (int t = 0; t < 2; ++t) {
    int ch = lane + t * 64;
    float m = sums[ch] * (1.0f / 16384.0f);
    float v = ssq[ch] * (1.0f / 16384.0f) - m * m;
    float s = g[ch] / sqrtf(v + 1e-5f);
    sc[ch] = s;
    sh[ch] = bt[ch] - m * s;
  }
  __syncthreads();
  const int b = blockIdx.y;
  const int n = blockIdx.x * 64 + lane;
  const float* hp = Y4 + ((long)b * 8192 + n) * 128;
  f4 av[13];
#pragma unroll
  for (int i = 0; i < 13; ++i) { f4 z = {0.f, 0.f, 0.f, 0.f}; av[i] = z; }
#pragma unroll 4
  for (int c4 = 0; c4 < 32; ++c4) {
    f4 hv = *(const f4*)(hp + c4 * 4);
#pragma unroll
    for (int e = 0; e < 4; ++e) {
      const int ch = c4 * 4 + e;
      float z = lky(fmaf(sc[ch], hv[e], sh[ch]));
#pragma unroll
      for (int o4 = 0; o4 < 13; ++o4) {
        f4 wv = *(const f4*)&swf[ch][o4 * 4];
#pragma unroll
        for (int q = 0; q < 4; ++q) av[o4][q] = fmaf(z, wv[q], av[o4][q]);
      }
    }
  }
  float* ob = out + (((long)b * 50) << 13) + n;
#pragma unroll
  for (int o4 = 0; o4 < 13; ++o4)
#pragma unroll
    for (int q = 0; q < 4; ++q) {
      int o = o4 * 4 + q;
      if (o < 50) ob[(long)o << 13] = av[o4][q] + sb[o];
    }
}

// ---------------- launcher ----------------
extern "C" void kernel_launch(void* const* d_in, const int* in_sizes, int n_in,
                              void* d_out, int out_size, void* d_ws, size_t ws_size,
                              hipStream_t stream)
{
  if ((long)ws_size < WS_NEED) return;
  const float* x   = (const float*)d_in[0];
  const float* p   = (const float*)d_in[1];
  const float* w1  = (const float*)d_in[2];
  const float* g1w = (const float*)d_in[4];
  const float* bt1 = (const float*)d_in[5];
  const float* we  = (const float*)d_in[6];
  const float* gew = (const float*)d_in[8];
  const float* bte = (const float*)d_in[9];
  const float* w2  = (const float*)d_in[10];
  const float* g2w = (const float*)d_in[12];
  const float* bt2 = (const float*)d_in[13];
  const float* w3  = (const float*)d_in[14];
  const float* g3w = (const float*)d_in[16];
  const float* bt3 = (const float*)d_in[17];
  const float* wf  = (const float*)d_in[18];
  const float* bfi = (const float*)d_in[19];

  char* ws = (char*)d_ws;
  u16* w1b   = (u16*)(ws + OFF_W1B);
  u16* weABb = (u16*)(ws + OFF_WEAB);
  u16* w2b   = (u16*)(ws + OFF_W2B);
  u16* w3b   = (u16*)(ws + OFF_W3B);
  int* idxb  = (int*)(ws + OFF_IDX);
  f4*  pqg   = (f4*)(ws + OFF_PQ);
  u16*   XT   = (u16*)(ws + OFF_XT);
  float* Y1   = (float*)(ws + OFF_Y1);
  u16*   Y2b  = (u16*)(ws + OFF_Y2);
  u16*   EMAX = (u16*)(ws + OFF_EMAX);
  u16*   EMIN = (u16*)(ws + OFF_EMIN);
  float* Y3   = (float*)(ws + OFF_Y3);
  float* Y4   = (float*)(ws + OFF_Y4);
  float* st0 = (float*)(ws + OFF_STATS);
  float* st1 = (float*)(ws + OFF_STATS + 4096);
  float* st2 = (float*)(ws + OFF_STATS + 8192);
  float* st3 = (float*)(ws + OFF_STATS + 12288);

  hipMemsetAsync(ws + OFF_STATS, 0, 16384, stream);
  k_convw<<<2112, 256, 0, stream>>>(w1, we, w2, w3, w1b, weABb, w2b, w3b);
  k_prep<<<64, 256, 0, stream>>>(p, pqg);
  k_knn<<<1024, 256, 0, stream>>>(pqg, idxb);
  k_xt<<<dim3(128, 19, 2), 256, 0, stream>>>(x, XT);

  // stage 1: smlp1d(x, w1) -> Y1 f32 + stats st0
  k_gemm<0, 1, 0><<<dim3(64, 2, 2), 256, 0, stream>>>(
      w1b, XT, nullptr, nullptr, nullptr, nullptr, nullptr, 0.f,
      st0, st0 + 256, Y1, 256, 1216, (long)8192 * 1216, (long)8192 * 256);

  // edge GEMM: B = apply1(Y1) fused -> Y2 bf16 [Anb | Cy]
  k_gemm<1, 0, 1><<<dim3(64, 4, 2), 256, 0, stream>>>(
      weABb, Y1, nullptr, st0, st0 + 256, g1w, bt1, 1.0f / 16384.0f,
      nullptr, nullptr, Y2b, 512, 256, (long)8192 * 256, (long)8192 * 512);

  // gather: channel-split, bf16 E out, stats st1
  k_edge_gather<<<dim3(128, 2, 2), 256, 0, stream>>>(Y2b, idxb, EMAX, EMIN, st1, st1 + 256);

  // stage 2: B = sel(EMAX,EMIN) bf16 fused -> Y3 f32 + stats st2
  k_gemm<2, 1, 0><<<dim3(64, 2, 2), 256, 0, stream>>>(
      w2b, EMAX, EMIN, st1, st1 + 256, gew, bte, 1.0f / 327680.0f,
      st2, st2 + 256, Y3, 256, 256, (long)8192 * 256, (long)8192 * 256);

  // stage 3: B = apply2(Y3) fused -> Y4 f32 + stats st3
  k_gemm<1, 1, 0><<<dim3(64, 1, 2), 256, 0, stream>>>(
      w3b, Y3, nullptr, st2, st2 + 256, g2w, bt2, 1.0f / 16384.0f,
      st3, st3 + 256, Y4, 128, 256, (long)8192 * 256, (long)8192 * 128);

  // final: apply3 fused + projection (Y4 read once)
  k_final<<<dim3(128, 2), 64, 0, stream>>>(Y4, st3, st3 + 256, g3w, bt3, wf, bfi, (float*)d_out);
}

// Round 14
// 223.039 us; speedup vs baseline: 3.7558x; 1.0557x over previous
//
#include <hip/hip_runtime.h>

typedef unsigned short u16;
typedef unsigned int   u32;
typedef unsigned long long u64;
typedef __attribute__((ext_vector_type(4))) float f4;
typedef __attribute__((ext_vector_type(8))) short s8;
typedef __attribute__((ext_vector_type(4))) int   i4v;
typedef __attribute__((ext_vector_type(4))) unsigned short u16x4;

#define DEV __device__ __forceinline__

DEV u16 f2b(float f) {
  u32 u = __float_as_uint(f);
  return (u16)((u + 0x7FFFu + ((u >> 16) & 1u)) >> 16);
}
DEV float b2f(u16 h) { return __uint_as_float(((u32)h) << 16); }

// ---------------- workspace layout (bytes) ----------------
#define OFF_STATS 0L
#define OFF_W1B   65536L
#define OFF_WEAB  688128L
#define OFF_W2B   950272L
#define OFF_W3B   1081344L
#define OFF_IDX   1146880L
#define OFF_PQ    2457600L      /* 256 KB: (x,y,z,|c|^2) per point */
#define OFF_Y1    44040192L     /* 16.8 MB f32, dead after edge GEMM */
#define OFF_Y2    4194304L      /* 16.8 MB bf16, dead after gather */
#define OFF_EMAX  23068672L     /* 8.4 MB bf16, dead after GEMM2 */
#define OFF_EMIN  41943040L     /* 8.4 MB bf16 */
#define OFF_Y3    4194304L      /* 16.8 MB f32 over dead Y2 */
#define OFF_Y4    23068672L     /* 8.4 MB f32 over dead EMAX */
#define WS_NEED   71303168L

// ---------------- weight convert -> bf16 + point prep ----------------
__global__ __launch_bounds__(256) void k_convw(
    const float* __restrict__ w1, const float* __restrict__ we,
    const float* __restrict__ w2, const float* __restrict__ w3,
    const float* __restrict__ p,
    u16* __restrict__ w1b, u16* __restrict__ weABb,
    u16* __restrict__ w2b, u16* __restrict__ w3b, f4* __restrict__ pqg)
{
  int i = blockIdx.x * 256 + threadIdx.x;
  if (i < 311296) { w1b[i] = f2b(w1[i]); return; }
  i -= 311296;
  if (i < 131072) {
    int o = i >> 8, c = i & 255;
    float v = (o < 256) ? we[o * 512 + c]
                        : we[(o - 256) * 512 + 256 + c] - we[(o - 256) * 512 + c];
    weABb[i] = f2b(v); return;
  }
  i -= 131072;
  if (i < 65536) { w2b[i] = f2b(w2[i]); return; }
  i -= 65536;
  if (i < 32768) { w3b[i] = f2b(w3[i]); return; }
  i -= 32768;
  if (i < 16384) {
    int b = i >> 13, n = i & 8191;
    const float* pb = p + (long)b * 24576;
    float X = pb[n], Y = pb[8192 + n], Z = pb[16384 + n];
    f4 v; v[0] = X; v[1] = Y; v[2] = Z; v[3] = fmaf(X, X, fmaf(Y, Y, Z * Z));
    pqg[i] = v;
  }
}

// ---------------- exact KNN top-20: 4 q/wave, chunk-LDS shared across 4 waves ----------------
__global__ __launch_bounds__(256) void k_knn(const f4* __restrict__ pqg, int* __restrict__ idxOut)
{
  __shared__ f4 chunk[1024];           // 16 KB
  __shared__ u16 cand[4][4][128];      // 4 KB
  __shared__ double ckeyv[4][128];     // 4 KB
  __shared__ int scnt[4][4];
  const int tid = threadIdx.x, lane = tid & 63, w = tid >> 6;
  const int blk = blockIdx.x;          // 1024
  const int b = blk >> 9;
  const int qbase = ((blk & 511) << 4) + (w << 2);
  const f4* __restrict__ P = pqg + ((long)b << 13);
  if (lane < 4) scnt[w][lane] = 0;
  float qx2[4], qy2[4], qz2[4];
#pragma unroll
  for (int j = 0; j < 4; ++j) {
    f4 Q = P[qbase + j];
    qx2[j] = Q[0] + Q[0]; qy2[j] = Q[1] + Q[1]; qz2[j] = Q[2] + Q[2];
  }
  float mx[4];
#pragma unroll
  for (int j = 0; j < 4; ++j) mx[j] = -3.0e38f;
  for (int c = 0; c < 8; ++c) {
    __syncthreads();
#pragma unroll
    for (int i = 0; i < 4; ++i) chunk[tid + i * 256] = P[c * 1024 + tid + i * 256];
    __syncthreads();
#pragma unroll 2
    for (int t = 0; t < 16; ++t) {
      f4 cc = chunk[(t << 6) + lane];
#pragma unroll
      for (int j = 0; j < 4; ++j) {
        float v = fmaf(qx2[j], cc[0], fmaf(qy2[j], cc[1], fmaf(qz2[j], cc[2], -cc[3])));
        mx[j] = fmaxf(mx[j], v);
      }
    }
  }
  float sv[4];
#pragma unroll
  for (int j = 0; j < 4; ++j) sv[j] = mx[j];
#pragma unroll
  for (int k = 2; k <= 64; k <<= 1) {
#pragma unroll
    for (int s = k >> 1; s > 0; s >>= 1) {
      const bool takeMin = (((lane & k) == 0) == ((lane & s) == 0));
#pragma unroll
      for (int j = 0; j < 4; ++j) {
        float o = __shfl_xor(sv[j], s);
        sv[j] = takeMin ? fminf(sv[j], o) : fmaxf(sv[j], o);
      }
    }
  }
  float T[4];
#pragma unroll
  for (int j = 0; j < 4; ++j) T[j] = __shfl(sv[j], 44) - 1e-3f;
  for (int c = 0; c < 8; ++c) {
    __syncthreads();
#pragma unroll
    for (int i = 0; i < 4; ++i) chunk[tid + i * 256] = P[c * 1024 + tid + i * 256];
    __syncthreads();
#pragma unroll 2
    for (int t = 0; t < 16; ++t) {
      f4 cc = chunk[(t << 6) + lane];
#pragma unroll
      for (int j = 0; j < 4; ++j) {
        float v = fmaf(qx2[j], cc[0], fmaf(qy2[j], cc[1], fmaf(qz2[j], cc[2], -cc[3])));
        if (v >= T[j]) {
          int pos = atomicAdd(&scnt[w][j], 1);
          if (pos < 128) cand[w][j][pos] = (u16)(c * 1024 + (t << 6) + lane);
        }
      }
    }
  }
  asm volatile("s_waitcnt lgkmcnt(0)" ::: "memory");
  for (int j = 0; j < 4; ++j) {
    int cn = scnt[w][j]; if (cn > 128) cn = 128;
    f4 Q = P[qbase + j];
    const double Qx = (double)Q[0], Qy = (double)Q[1], Qz = (double)Q[2];
    const double Qs = Qx * Qx + Qy * Qy + Qz * Qz;
    double myV[2]; int myI[2];
#pragma unroll
    for (int jj = 0; jj < 2; ++jj) {
      const int e = lane + (jj << 6);
      myV[jj] = -1.0e300; myI[jj] = 0x7FFFFFFF;
      if (e < cn) {
        const int ci = cand[w][j][e];
        f4 c = P[ci];
        double cx = (double)c[0], cy = (double)c[1], cz = (double)c[2];
        double v = 2.0 * (Qx * cx + Qy * cy + Qz * cz) - Qs - (cx * cx + cy * cy + cz * cz);
        myV[jj] = v; myI[jj] = ci;
        ckeyv[w][e] = v;
      }
    }
    asm volatile("s_waitcnt lgkmcnt(0)" ::: "memory");
    int rk0 = 0, rk1 = 0;
#pragma unroll 4
    for (int e2 = 0; e2 < cn; ++e2) {
      double ov = ckeyv[w][e2];
      int oi = (int)cand[w][j][e2];
      rk0 += ((ov > myV[0]) || (ov == myV[0] && oi < myI[0])) ? 1 : 0;
      rk1 += ((ov > myV[1]) || (ov == myV[1] && oi < myI[1])) ? 1 : 0;
    }
    int* orow = idxOut + (((long)b << 13) + qbase + j) * 20;
    if (lane < cn && rk0 < 20) orow[rk0] = myI[0];
    if (lane + 64 < cn && rk1 < 20) orow[rk1] = myI[1];
    asm volatile("s_waitcnt lgkmcnt(0)" ::: "memory");
  }
}

// ---------------- fused apply helpers ----------------
DEV float lky(float z) { return z > 0.f ? z : 0.2f * z; }

DEV i4v applyPack8(f4 a, f4 b4, const float* sc, const float* sh, int kb) {
  u16 r[8];
#pragma unroll
  for (int e = 0; e < 4; ++e) r[e] = f2b(lky(fmaf(sc[kb + e], a[e], sh[kb + e])));
#pragma unroll
  for (int e = 0; e < 4; ++e) r[4 + e] = f2b(lky(fmaf(sc[kb + 4 + e], b4[e], sh[kb + 4 + e])));
  i4v o;
#pragma unroll
  for (int e = 0; e < 4; ++e) o[e] = (int)((u32)r[2 * e] | ((u32)r[2 * e + 1] << 16));
  return o;
}

DEV i4v selPack8b(i4v rawM, i4v rawN, const float* sc, const float* sh, int kb) {
  u16 r[8];
#pragma unroll
  for (int e = 0; e < 8; ++e) {
    u32 dM = (u32)rawM[e >> 1], dN = (u32)rawN[e >> 1];
    u16 hM = (e & 1) ? (u16)(dM >> 16) : (u16)(dM & 0xFFFFu);
    u16 hN = (e & 1) ? (u16)(dN >> 16) : (u16)(dN & 0xFFFFu);
    float s = sc[kb + e];
    float y = (s >= 0.f) ? b2f(hM) : b2f(hN);
    r[e] = f2b(lky(fmaf(s, y, sh[kb + e])));
  }
  i4v o;
#pragma unroll
  for (int e = 0; e < 4; ++e) o[e] = (int)((u32)r[2 * e] | ((u32)r[2 * e + 1] << 16));
  return o;
}

// pack a B-fragment from an f32 LDS tile sBf[32][130]: k = kb..kb+7, col nl (0..127)
#define XSTRIDE 130
DEV s8 packFrag(const float* __restrict__ sBf, int kb, int nl) {
  union { u16 u[8]; s8 v; } r;
#pragma unroll
  for (int i = 0; i < 8; ++i) r.u[i] = f2b(sBf[(kb + i) * XSTRIDE + nl]);
  return r.v;
}

// ---------------- bf16 MFMA GEMM: Y[b][n][o] = sum_k A[o][k]*Bapplied[b][n][k] ----------------
// BMODE 0: B0 bf16 [n][K]. BMODE 1: B0 f32 [n][K] + norm/leaky (K==256).
// BMODE 2: B0=EMAX,B1=EMIN bf16 [n][K] + sign-select + norm/leaky (K==256).
// BMODE 3: B0 = x f32 in [k][8192] layout; transpose + bf16 in staging (GEMM1).
template<int BMODE, int STATS, int BF16OUT>
__global__ __launch_bounds__(256, 2) void k_gemm(
    const u16* __restrict__ A, const void* __restrict__ B0v, const void* __restrict__ B1v,
    const float* __restrict__ sums, const float* __restrict__ ssq,
    const float* __restrict__ g, const float* __restrict__ bt, float invCount,
    float* __restrict__ gsums, float* __restrict__ gssq,
    void* __restrict__ Yv, int M, int K, long strideB, long strideY)
{
  __shared__ u16 sA[2][4096];
  // modes 0-2: u16[4096] (8 KB). mode 3: float[32][130] (16640 B).
  __shared__ __align__(16) char sBr[2][(BMODE == 3) ? 16640 : 8192];
  __shared__ float scB[256], shB[256];
  __shared__ float s_sum[128], s_ssq[128];
  const int b = blockIdx.z;
  const int m0 = blockIdx.y * 128;
  const int n0 = blockIdx.x * 128;
  const int tid = threadIdx.x, lane = tid & 63, w = tid >> 6;
  const int wr = w >> 1, wc = w & 1;
  const int r15 = lane & 15, g8 = (lane >> 4) * 8;

  if (BMODE == 1 || BMODE == 2) {
    float m = sums[tid] * invCount;
    float v = ssq[tid] * invCount - m * m;
    float s = g[tid] / sqrtf(v + 1e-5f);
    scB[tid] = s;
    shB[tid] = bt[tid] - m * s;
  }
  if (STATS) { if (tid < 128) { s_sum[tid] = 0.f; s_ssq[tid] = 0.f; } }
  if (BMODE == 1 || BMODE == 2) __syncthreads();

  f4 acc[4][4];
#pragma unroll
  for (int i = 0; i < 4; ++i)
#pragma unroll
    for (int j = 0; j < 4; ++j) { f4 z = {0.f, 0.f, 0.f, 0.f}; acc[i][j] = z; }

  const int row0 = tid >> 2;            // 0..63
  const int kp0 = (tid & 3) << 3;       // 0,8,16,24
  const u16* gA0 = A + (long)(m0 + row0) * K + kp0;
  const u16* gA1 = A + (long)(m0 + row0 + 64) * K + kp0;
  const int ch0 = tid, ch1 = tid + 256;

  const u16* gB0 = (const u16*)B0v + (long)b * strideB + (long)(n0 + row0) * K + kp0;
  const u16* gB1 = gB0 + (long)64 * K;
  const float* fB0 = (const float*)B0v + (long)b * strideB + (long)(n0 + row0) * K + kp0;
  const float* fB1 = fB0 + (long)64 * K;
  const u16* nB0 = (const u16*)B1v + (long)b * strideB + (long)(n0 + row0) * K + kp0;
  const u16* nB1 = nB0 + (long)64 * K;
  // mode 3: thread covers k-row kS (0..31), n-quads nS, nS+32, nS+64, nS+96
  const float* xB = (const float*)B0v + (long)b * strideB;
  const int kS = tid >> 3, nS = (tid & 7) << 2;
  const float* gX = xB + (long)kS * 8192 + n0 + nS;

  // prologue: stage k-tile 0
  ((i4v*)sA[0])[ch0] = *(const i4v*)gA0;
  ((i4v*)sA[0])[ch1] = *(const i4v*)gA1;
  if (BMODE == 0) {
    ((i4v*)sBr[0])[ch0] = *(const i4v*)gB0;
    ((i4v*)sBr[0])[ch1] = *(const i4v*)gB1;
  } else if (BMODE == 1) {
    ((i4v*)sBr[0])[ch0] = applyPack8(*(const f4*)fB0, *(const f4*)(fB0 + 4), scB, shB, kp0);
    ((i4v*)sBr[0])[ch1] = applyPack8(*(const f4*)fB1, *(const f4*)(fB1 + 4), scB, shB, kp0);
  } else if (BMODE == 2) {
    ((i4v*)sBr[0])[ch0] = selPack8b(*(const i4v*)gB0, *(const i4v*)nB0, scB, shB, kp0);
    ((i4v*)sBr[0])[ch1] = selPack8b(*(const i4v*)gB1, *(const i4v*)nB1, scB, shB, kp0);
  } else {
    float* sBf0 = (float*)sBr[0];
#pragma unroll
    for (int it = 0; it < 4; ++it) {
      f4 v = *(const f4*)(gX + it * 32);
      float* dst = sBf0 + kS * XSTRIDE + nS + it * 32;
      ((float2*)dst)[0] = make_float2(v[0], v[1]);
      ((float2*)dst)[1] = make_float2(v[2], v[3]);
    }
  }
  __syncthreads();

  const int KT = K >> 5;
  int cur = 0;
  for (int kk = 0; kk < KT; ++kk) {
    const bool more = (kk + 1 < KT);
    i4v ra0, ra1, rb0, rb1, rn0, rn1;
    f4 p0a, p0b, p1a, p1b;
    f4 xv[4];
    if (more) {
      long ko = (long)(kk + 1) * 32;
      ra0 = *(const i4v*)(gA0 + ko); ra1 = *(const i4v*)(gA1 + ko);
      if (BMODE == 0) {
        rb0 = *(const i4v*)(gB0 + ko); rb1 = *(const i4v*)(gB1 + ko);
      } else if (BMODE == 1) {
        p0a = *(const f4*)(fB0 + ko); p0b = *(const f4*)(fB0 + ko + 4);
        p1a = *(const f4*)(fB1 + ko); p1b = *(const f4*)(fB1 + ko + 4);
      } else if (BMODE == 2) {
        rb0 = *(const i4v*)(gB0 + ko); rb1 = *(const i4v*)(gB1 + ko);
        rn0 = *(const i4v*)(nB0 + ko); rn1 = *(const i4v*)(nB1 + ko);
      } else {
        const float* gx = gX + ko * 8192;
#pragma unroll
        for (int it = 0; it < 4; ++it) xv[it] = *(const f4*)(gx + it * 32);
      }
    }
    const u16* la = sA[cur];
    s8 af[4], bfr[4];
#pragma unroll
    for (int mi = 0; mi < 4; ++mi)
      af[mi] = *(const s8*)(la + (wr * 64 + mi * 16 + r15) * 32 + g8);
    if (BMODE == 3) {
      const float* sBfc = (const float*)sBr[cur];
#pragma unroll
      for (int ni = 0; ni < 4; ++ni)
        bfr[ni] = packFrag(sBfc, g8, wc * 64 + ni * 16 + r15);
    } else {
      const u16* lb = (const u16*)sBr[cur];
#pragma unroll
      for (int ni = 0; ni < 4; ++ni)
        bfr[ni] = *(const s8*)(lb + (wc * 64 + ni * 16 + r15) * 32 + g8);
    }
#pragma unroll
    for (int mi = 0; mi < 4; ++mi)
#pragma unroll
      for (int ni = 0; ni < 4; ++ni)
        acc[mi][ni] = __builtin_amdgcn_mfma_f32_16x16x32_bf16(af[mi], bfr[ni], acc[mi][ni], 0, 0, 0);
    if (more) {
      ((i4v*)sA[cur ^ 1])[ch0] = ra0; ((i4v*)sA[cur ^ 1])[ch1] = ra1;
      if (BMODE == 0) {
        ((i4v*)sBr[cur ^ 1])[ch0] = rb0; ((i4v*)sBr[cur ^ 1])[ch1] = rb1;
      } else if (BMODE == 1) {
        const int kb = (kk + 1) * 32 + kp0;
        ((i4v*)sBr[cur ^ 1])[ch0] = applyPack8(p0a, p0b, scB, shB, kb);
        ((i4v*)sBr[cur ^ 1])[ch1] = applyPack8(p1a, p1b, scB, shB, kb);
      } else if (BMODE == 2) {
        const int kb = (kk + 1) * 32 + kp0;
        ((i4v*)sBr[cur ^ 1])[ch0] = selPack8b(rb0, rn0, scB, shB, kb);
        ((i4v*)sBr[cur ^ 1])[ch1] = selPack8b(rb1, rn1, scB, shB, kb);
      } else {
        float* sBfn = (float*)sBr[cur ^ 1];
#pragma unroll
        for (int it = 0; it < 4; ++it) {
          float* dst = sBfn + kS * XSTRIDE + nS + it * 32;
          ((float2*)dst)[0] = make_float2(xv[it][0], xv[it][1]);
          ((float2*)dst)[1] = make_float2(xv[it][2], xv[it][3]);
        }
      }
    }
    __syncthreads();
    cur ^= 1;
  }
  // epilogue: D col(n)=lane&15, row(o)=(lane>>4)*4+reg
  const int og = m0 + wr * 64 + (lane >> 4) * 4;
  const int ng = n0 + wc * 64 + r15;
  if (BF16OUT) {
    u16* Yp = (u16*)Yv + (long)b * strideY;
#pragma unroll
    for (int mi = 0; mi < 4; ++mi)
#pragma unroll
      for (int ni = 0; ni < 4; ++ni) {
        f4 a = acc[mi][ni];
        u16x4 r;
#pragma unroll
        for (int q = 0; q < 4; ++q) r[q] = f2b(a[q]);
        *(u16x4*)(Yp + (long)(ng + ni * 16) * M + og + mi * 16) = r;
      }
  } else {
    float* Yp = (float*)Yv + (long)b * strideY;
#pragma unroll
    for (int mi = 0; mi < 4; ++mi)
#pragma unroll
      for (int ni = 0; ni < 4; ++ni)
        *(f4*)(Yp + (long)(ng + ni * 16) * M + og + mi * 16) = acc[mi][ni];
  }
  if (STATS) {
#pragma unroll
    for (int mi = 0; mi < 4; ++mi)
#pragma unroll
      for (int j = 0; j < 4; ++j) {
        float s = 0.f, q = 0.f;
#pragma unroll
        for (int ni = 0; ni < 4; ++ni) {
          float v = acc[mi][ni][j];
          s += v; q = fmaf(v, v, q);
        }
#pragma unroll
        for (int off = 1; off < 16; off <<= 1) {
          s += __shfl_xor(s, off);
          q += __shfl_xor(q, off);
        }
        if ((lane & 15) == 0) {
          int lc = wr * 64 + (lane >> 4) * 4 + mi * 16 + j;
          atomicAdd(&s_sum[lc], s);
          atomicAdd(&s_ssq[lc], q);
        }
      }
    __syncthreads();
    if (tid < 128) {
      atomicAdd(&gsums[m0 + tid], s_sum[tid]);
      atomicAdd(&gssq[m0 + tid], s_ssq[tid]);
    }
  }
}

// ---------------- edgeconv gather, channel-split for L2 residency ----------------
__global__ __launch_bounds__(256, 2) void k_edge_gather(
    const u16* __restrict__ Y2, const int* __restrict__ idx,
    u16* __restrict__ Emax, u16* __restrict__ Emin,
    float* __restrict__ sums, float* __restrict__ ssq)
{
  __shared__ float s_sum[256], s_ssq[256];
  const int tid = threadIdx.x, lane = tid & 63, w = tid >> 6;
  s_sum[tid] = 0.f; s_ssq[tid] = 0.f;
  __syncthreads();
  const int half = blockIdx.y, b = blockIdx.z;
  const int ptBase = blockIdx.x * 64 + w * 16;
  const int sub = lane >> 5;
  const int chOff = half * 128 + ((lane & 31) << 2);
  f4 lsum = {0.f, 0.f, 0.f, 0.f}, lssq = {0.f, 0.f, 0.f, 0.f};
  for (int i = 0; i < 8; ++i) {
    const int pt = ptBase + i * 2 + sub;
    const long gp = (long)b * 8192 + pt;
    u16x4 cr = *(const u16x4*)(Y2 + gp * 512 + 256 + chOff);
    f4 ctr; ctr[0] = b2f(cr[0]); ctr[1] = b2f(cr[1]); ctr[2] = b2f(cr[2]); ctr[3] = b2f(cr[3]);
    const int* irow = idx + gp * 20;
    f4 vmax = {-3.0e38f, -3.0e38f, -3.0e38f, -3.0e38f};
    f4 vmin = {3.0e38f, 3.0e38f, 3.0e38f, 3.0e38f};
#pragma unroll 4
    for (int k = 0; k < 20; ++k) {
      int m = irow[k];
      u16x4 nr = *(const u16x4*)(Y2 + ((long)b * 8192 + m) * 512 + chOff);
#pragma unroll
      for (int j = 0; j < 4; ++j) {
        float y = b2f(nr[j]) + ctr[j];
        vmax[j] = fmaxf(vmax[j], y);
        vmin[j] = fminf(vmin[j], y);
        lsum[j] += y;
        lssq[j] = fmaf(y, y, lssq[j]);
      }
    }
    u16x4 eM, eN;
#pragma unroll
    for (int j = 0; j < 4; ++j) { eM[j] = f2b(vmax[j]); eN[j] = f2b(vmin[j]); }
    *(u16x4*)(Emax + gp * 256 + chOff) = eM;
    *(u16x4*)(Emin + gp * 256 + chOff) = eN;
  }
#pragma unroll
  for (int j = 0; j < 4; ++j) {
    atomicAdd(&s_sum[chOff + j], lsum[j]);
    atomicAdd(&s_ssq[chOff + j], lssq[j]);
  }
  __syncthreads();
  atomicAdd(&sums[tid], s_sum[tid]);
  atomicAdd(&ssq[tid], s_ssq[tid]);
}

// ---------------- final: apply(norm3+leaky) + 50x128 proj + bias; Y4 read ONCE ----------------
__global__ __launch_bounds__(64) void k_final(
    const float* __restrict__ Y4, const float* __restrict__ sums, const float* __restrict__ ssq,
    const float* __restrict__ g, const float* __restrict__ bt,
    const float* __restrict__ wf, const float* __restrict__ bf,
    float* __restrict__ out)
{
  __shared__ float swf[128][56];
  __shared__ float sc[128], sh[128], sb[52];
  const int lane = threadIdx.x;
  if (lane < 50) {
    const float* wrow = wf + lane * 128;
#pragma unroll 8
    for (int ch = 0; ch < 128; ++ch) swf[ch][lane] = wrow[ch];
    sb[lane] = bf[lane];
  } else if (lane < 52) {
#pragma unroll 8
    for (int ch = 0; ch < 128; ++ch) swf[ch][lane] = 0.f;
    sb[lane] = 0.f;
  }
#pragma unroll
  for (int t = 0; t < 2; ++t) {
    int ch = lane + t * 64;
    float m = sums[ch] * (1.0f / 16384.0f);
    float v = ssq[ch] * (1.0f / 16384.0f) - m * m;
    float s = g[ch] / sqrtf(v + 1e-5f);
    sc[ch] = s;
    sh[ch] = bt[ch] - m * s;
  }
  __syncthreads();
  const int b = blockIdx.y;
  const int n = blockIdx.x * 64 + lane;
  const float* hp = Y4 + ((long)b * 8192 + n) * 128;
  f4 av[13];
#pragma unroll
  for (int i = 0; i < 13; ++i) { f4 z = {0.f, 0.f, 0.f, 0.f}; av[i] = z; }
#pragma unroll 4
  for (int c4 = 0; c4 < 32; ++c4) {
    f4 hv = *(const f4*)(hp + c4 * 4);
#pragma unroll
    for (int e = 0; e < 4; ++e) {
      const int ch = c4 * 4 + e;
      float z = lky(fmaf(sc[ch], hv[e], sh[ch]));
#pragma unroll
      for (int o4 = 0; o4 < 13; ++o4) {
        f4 wv = *(const f4*)&swf[ch][o4 * 4];
#pragma unroll
        for (int q = 0; q < 4; ++q) av[o4][q] = fmaf(z, wv[q], av[o4][q]);
      }
    }
  }
  float* ob = out + (((long)b * 50) << 13) + n;
#pragma unroll
  for (int o4 = 0; o4 < 13; ++o4)
#pragma unroll
    for (int q = 0; q < 4; ++q) {
      int o = o4 * 4 + q;
      if (o < 50) ob[(long)o << 13] = av[o4][q] + sb[o];
    }
}

// ---------------- launcher ----------------
extern "C" void kernel_launch(void* const* d_in, const int* in_sizes, int n_in,
                              void* d_out, int out_size, void* d_ws, size_t ws_size,
                              hipStream_t stream)
{
  if ((long)ws_size < WS_NEED) return;
  const float* x   = (const float*)d_in[0];
  const float* p   = (const float*)d_in[1];
  const float* w1  = (const float*)d_in[2];
  const float* g1w = (const float*)d_in[4];
  const float* bt1 = (const float*)d_in[5];
  const float* we  = (const float*)d_in[6];
  const float* gew = (const float*)d_in[8];
  const float* bte = (const float*)d_in[9];
  const float* w2  = (const float*)d_in[10];
  const float* g2w = (const float*)d_in[12];
  const float* bt2 = (const float*)d_in[13];
  const float* w3  = (const float*)d_in[14];
  const float* g3w = (const float*)d_in[16];
  const float* bt3 = (const float*)d_in[17];
  const float* wf  = (const float*)d_in[18];
  const float* bfi = (const float*)d_in[19];

  char* ws = (char*)d_ws;
  u16* w1b   = (u16*)(ws + OFF_W1B);
  u16* weABb = (u16*)(ws + OFF_WEAB);
  u16* w2b   = (u16*)(ws + OFF_W2B);
  u16* w3b   = (u16*)(ws + OFF_W3B);
  int* idxb  = (int*)(ws + OFF_IDX);
  f4*  pqg   = (f4*)(ws + OFF_PQ);
  float* Y1   = (float*)(ws + OFF_Y1);
  u16*   Y2b  = (u16*)(ws + OFF_Y2);
  u16*   EMAX = (u16*)(ws + OFF_EMAX);
  u16*   EMIN = (u16*)(ws + OFF_EMIN);
  float* Y3   = (float*)(ws + OFF_Y3);
  float* Y4   = (float*)(ws + OFF_Y4);
  float* st0 = (float*)(ws + OFF_STATS);
  float* st1 = (float*)(ws + OFF_STATS + 4096);
  float* st2 = (float*)(ws + OFF_STATS + 8192);
  float* st3 = (float*)(ws + OFF_STATS + 12288);

  hipMemsetAsync(ws + OFF_STATS, 0, 16384, stream);
  k_convw<<<2176, 256, 0, stream>>>(w1, we, w2, w3, p, w1b, weABb, w2b, w3b, pqg);
  k_knn<<<1024, 256, 0, stream>>>(pqg, idxb);

  // stage 1: smlp1d(x, w1) -> Y1 f32 + stats st0; B staged straight from x (fused transpose)
  k_gemm<3, 1, 0><<<dim3(64, 2, 2), 256, 0, stream>>>(
      w1b, x, nullptr, nullptr, nullptr, nullptr, nullptr, 0.f,
      st0, st0 + 256, Y1, 256, 1216, (long)1216 * 8192, (long)8192 * 256);

  // edge GEMM: B = apply1(Y1) fused -> Y2 bf16 [Anb | Cy]
  k_gemm<1, 0, 1><<<dim3(64, 4, 2), 256, 0, stream>>>(
      weABb, Y1, nullptr, st0, st0 + 256, g1w, bt1, 1.0f / 16384.0f,
      nullptr, nullptr, Y2b, 512, 256, (long)8192 * 256, (long)8192 * 512);

  // gather: channel-split, bf16 E out, stats st1
  k_edge_gather<<<dim3(128, 2, 2), 256, 0, stream>>>(Y2b, idxb, EMAX, EMIN, st1, st1 + 256);

  // stage 2: B = sel(EMAX,EMIN) bf16 fused -> Y3 f32 + stats st2
  k_gemm<2, 1, 0><<<dim3(64, 2, 2), 256, 0, stream>>>(
      w2b, EMAX, EMIN, st1, st1 + 256, gew, bte, 1.0f / 327680.0f,
      st2, st2 + 256, Y3, 256, 256, (long)8192 * 256, (long)8192 * 256);

  // stage 3: B = apply2(Y3) fused -> Y4 f32 + stats st3
  k_gemm<1, 1, 0><<<dim3(64, 1, 2), 256, 0, stream>>>(
      w3b, Y3, nullptr, st2, st2 + 256, g2w, bt2, 1.0f / 16384.0f,
      st3, st3 + 256, Y4, 128, 256, (long)8192 * 256, (long)8192 * 128);

  // final: apply3 fused + projection (Y4 read once)
  k_final<<<dim3(128, 2), 64, 0, stream>>>(Y4, st3, st3 + 256, g3w, bt3, wf, bfi, (float*)d_out);
}

// Round 15
// 216.076 us; speedup vs baseline: 3.8768x; 1.0322x over previous
//
#include <hip/hip_runtime.h>

typedef unsigned short u16;
typedef unsigned int   u32;
typedef unsigned long long u64;
typedef __attribute__((ext_vector_type(4))) float f4;
typedef __attribute__((ext_vector_type(8))) short s8;
typedef __attribute__((ext_vector_type(4))) int   i4v;
typedef __attribute__((ext_vector_type(4))) unsigned short u16x4;

#define DEV __device__ __forceinline__

// native bf16 cast (HW v_cvt_pk_bf16_f32, RNE — bit-identical to manual round-to-nearest-even)
DEV u16 f2b(float f) {
  union { __bf16 b; u16 u; } c; c.b = (__bf16)f; return c.u;
}
DEV float b2f(u16 h) { return __uint_as_float(((u32)h) << 16); }

// ---------------- workspace layout (bytes) ----------------
#define OFF_STATS 0L
#define OFF_W1B   65536L
#define OFF_WEAB  688128L
#define OFF_W2B   950272L
#define OFF_W3B   1081344L
#define OFF_IDX   1146880L
#define OFF_PQ    2457600L      /* 256 KB: (x,y,z,|c|^2) per point */
#define OFF_Y1    44040192L     /* 8.4 MB bf16, dead after edge GEMM */
#define OFF_Y2    4194304L      /* 16.8 MB bf16, dead after gather */
#define OFF_EMAX  23068672L     /* 8.4 MB bf16, dead after GEMM2 */
#define OFF_EMIN  41943040L     /* 8.4 MB bf16 */
#define OFF_Y3    4194304L      /* 8.4 MB bf16 over dead Y2 */
#define OFF_Y4    23068672L     /* 8.4 MB f32 over dead EMAX */
#define WS_NEED   71303168L

// ---------------- weight convert -> bf16 + point prep ----------------
__global__ __launch_bounds__(256) void k_convw(
    const float* __restrict__ w1, const float* __restrict__ we,
    const float* __restrict__ w2, const float* __restrict__ w3,
    const float* __restrict__ p,
    u16* __restrict__ w1b, u16* __restrict__ weABb,
    u16* __restrict__ w2b, u16* __restrict__ w3b, f4* __restrict__ pqg)
{
  int i = blockIdx.x * 256 + threadIdx.x;
  if (i < 311296) { w1b[i] = f2b(w1[i]); return; }
  i -= 311296;
  if (i < 131072) {
    int o = i >> 8, c = i & 255;
    float v = (o < 256) ? we[o * 512 + c]
                        : we[(o - 256) * 512 + 256 + c] - we[(o - 256) * 512 + c];
    weABb[i] = f2b(v); return;
  }
  i -= 131072;
  if (i < 65536) { w2b[i] = f2b(w2[i]); return; }
  i -= 65536;
  if (i < 32768) { w3b[i] = f2b(w3[i]); return; }
  i -= 32768;
  if (i < 16384) {
    int b = i >> 13, n = i & 8191;
    const float* pb = p + (long)b * 24576;
    float X = pb[n], Y = pb[8192 + n], Z = pb[16384 + n];
    f4 v; v[0] = X; v[1] = Y; v[2] = Z; v[3] = fmaf(X, X, fmaf(Y, Y, Z * Z));
    pqg[i] = v;
  }
}

// ---------------- exact KNN top-20: 4 q/wave, chunk-LDS shared across 4 waves ----------------
__global__ __launch_bounds__(256) void k_knn(const f4* __restrict__ pqg, int* __restrict__ idxOut)
{
  __shared__ f4 chunk[1024];           // 16 KB
  __shared__ u16 cand[4][4][128];      // 4 KB
  __shared__ double ckeyv[4][128];     // 4 KB
  __shared__ int scnt[4][4];
  const int tid = threadIdx.x, lane = tid & 63, w = tid >> 6;
  const int blk = blockIdx.x;          // 1024
  const int b = blk >> 9;
  const int qbase = ((blk & 511) << 4) + (w << 2);
  const f4* __restrict__ P = pqg + ((long)b << 13);
  if (lane < 4) scnt[w][lane] = 0;
  float qx2[4], qy2[4], qz2[4];
#pragma unroll
  for (int j = 0; j < 4; ++j) {
    f4 Q = P[qbase + j];
    qx2[j] = Q[0] + Q[0]; qy2[j] = Q[1] + Q[1]; qz2[j] = Q[2] + Q[2];
  }
  float mx[4];
#pragma unroll
  for (int j = 0; j < 4; ++j) mx[j] = -3.0e38f;
  for (int c = 0; c < 8; ++c) {
    __syncthreads();
#pragma unroll
    for (int i = 0; i < 4; ++i) chunk[tid + i * 256] = P[c * 1024 + tid + i * 256];
    __syncthreads();
#pragma unroll 2
    for (int t = 0; t < 16; ++t) {
      f4 cc = chunk[(t << 6) + lane];
#pragma unroll
      for (int j = 0; j < 4; ++j) {
        float v = fmaf(qx2[j], cc[0], fmaf(qy2[j], cc[1], fmaf(qz2[j], cc[2], -cc[3])));
        mx[j] = fmaxf(mx[j], v);
      }
    }
  }
  float sv[4];
#pragma unroll
  for (int j = 0; j < 4; ++j) sv[j] = mx[j];
#pragma unroll
  for (int k = 2; k <= 64; k <<= 1) {
#pragma unroll
    for (int s = k >> 1; s > 0; s >>= 1) {
      const bool takeMin = (((lane & k) == 0) == ((lane & s) == 0));
#pragma unroll
      for (int j = 0; j < 4; ++j) {
        float o = __shfl_xor(sv[j], s);
        sv[j] = takeMin ? fminf(sv[j], o) : fmaxf(sv[j], o);
      }
    }
  }
  float T[4];
#pragma unroll
  for (int j = 0; j < 4; ++j) T[j] = __shfl(sv[j], 44) - 1e-3f;
  for (int c = 0; c < 8; ++c) {
    __syncthreads();
#pragma unroll
    for (int i = 0; i < 4; ++i) chunk[tid + i * 256] = P[c * 1024 + tid + i * 256];
    __syncthreads();
#pragma unroll 2
    for (int t = 0; t < 16; ++t) {
      f4 cc = chunk[(t << 6) + lane];
#pragma unroll
      for (int j = 0; j < 4; ++j) {
        float v = fmaf(qx2[j], cc[0], fmaf(qy2[j], cc[1], fmaf(qz2[j], cc[2], -cc[3])));
        if (v >= T[j]) {
          int pos = atomicAdd(&scnt[w][j], 1);
          if (pos < 128) cand[w][j][pos] = (u16)(c * 1024 + (t << 6) + lane);
        }
      }
    }
  }
  asm volatile("s_waitcnt lgkmcnt(0)" ::: "memory");
  for (int j = 0; j < 4; ++j) {
    int cn = scnt[w][j]; if (cn > 128) cn = 128;
    f4 Q = P[qbase + j];
    const double Qx = (double)Q[0], Qy = (double)Q[1], Qz = (double)Q[2];
    const double Qs = Qx * Qx + Qy * Qy + Qz * Qz;
    double myV[2]; int myI[2];
#pragma unroll
    for (int jj = 0; jj < 2; ++jj) {
      const int e = lane + (jj << 6);
      myV[jj] = -1.0e300; myI[jj] = 0x7FFFFFFF;
      if (e < cn) {
        const int ci = cand[w][j][e];
        f4 c = P[ci];
        double cx = (double)c[0], cy = (double)c[1], cz = (double)c[2];
        double v = 2.0 * (Qx * cx + Qy * cy + Qz * cz) - Qs - (cx * cx + cy * cy + cz * cz);
        myV[jj] = v; myI[jj] = ci;
        ckeyv[w][e] = v;
      }
    }
    asm volatile("s_waitcnt lgkmcnt(0)" ::: "memory");
    int rk0 = 0, rk1 = 0;
#pragma unroll 4
    for (int e2 = 0; e2 < cn; ++e2) {
      double ov = ckeyv[w][e2];
      int oi = (int)cand[w][j][e2];
      rk0 += ((ov > myV[0]) || (ov == myV[0] && oi < myI[0])) ? 1 : 0;
      rk1 += ((ov > myV[1]) || (ov == myV[1] && oi < myI[1])) ? 1 : 0;
    }
    int* orow = idxOut + (((long)b << 13) + qbase + j) * 20;
    if (lane < cn && rk0 < 20) orow[rk0] = myI[0];
    if (lane + 64 < cn && rk1 < 20) orow[rk1] = myI[1];
    asm volatile("s_waitcnt lgkmcnt(0)" ::: "memory");
  }
}

// ---------------- fused apply helpers ----------------
DEV float lky(float z) { return z > 0.f ? z : 0.2f * z; }

// raw = 8 bf16 (pre-norm); apply norm+leaky, repack bf16
DEV i4v applyPack8(i4v raw, const float* sc, const float* sh, int kb) {
  u16 r[8];
#pragma unroll
  for (int e = 0; e < 8; ++e) {
    u32 dw = (u32)raw[e >> 1];
    u16 h = (e & 1) ? (u16)(dw >> 16) : (u16)(dw & 0xFFFFu);
    r[e] = f2b(lky(fmaf(sc[kb + e], b2f(h), sh[kb + e])));
  }
  i4v o;
#pragma unroll
  for (int e = 0; e < 4; ++e) o[e] = (int)((u32)r[2 * e] | ((u32)r[2 * e + 1] << 16));
  return o;
}

DEV i4v selPack8b(i4v rawM, i4v rawN, const float* sc, const float* sh, int kb) {
  u16 r[8];
#pragma unroll
  for (int e = 0; e < 8; ++e) {
    u32 dM = (u32)rawM[e >> 1], dN = (u32)rawN[e >> 1];
    u16 hM = (e & 1) ? (u16)(dM >> 16) : (u16)(dM & 0xFFFFu);
    u16 hN = (e & 1) ? (u16)(dN >> 16) : (u16)(dN & 0xFFFFu);
    float s = sc[kb + e];
    float y = (s >= 0.f) ? b2f(hM) : b2f(hN);
    r[e] = f2b(lky(fmaf(s, y, sh[kb + e])));
  }
  i4v o;
#pragma unroll
  for (int e = 0; e < 4; ++e) o[e] = (int)((u32)r[2 * e] | ((u32)r[2 * e + 1] << 16));
  return o;
}

// pack a B-fragment from an f32 LDS tile sBf[32][130]: k = kb..kb+7, col nl (0..127)
#define XSTRIDE 130
DEV s8 packFrag(const float* __restrict__ sBf, int kb, int nl) {
  union { u16 u[8]; s8 v; } r;
#pragma unroll
  for (int i = 0; i < 8; ++i) r.u[i] = f2b(sBf[(kb + i) * XSTRIDE + nl]);
  return r.v;
}

// ---------------- bf16 MFMA GEMM: Y[b][n][o] = sum_k A[o][k]*Bapplied[b][n][k] ----------------
// BMODE 0: B0 bf16 [n][K] pre-applied. BMODE 1: B0 bf16 raw [n][K] + norm/leaky (K==256).
// BMODE 2: B0=EMAX,B1=EMIN bf16 [n][K] + sign-select + norm/leaky (K==256).
// BMODE 3: B0 = x f32 in [k][8192] layout; transpose + bf16 in staging (GEMM1).
template<int BMODE, int STATS, int BF16OUT>
__global__ __launch_bounds__(256, 2) void k_gemm(
    const u16* __restrict__ A, const void* __restrict__ B0v, const void* __restrict__ B1v,
    const float* __restrict__ sums, const float* __restrict__ ssq,
    const float* __restrict__ g, const float* __restrict__ bt, float invCount,
    float* __restrict__ gsums, float* __restrict__ gssq,
    void* __restrict__ Yv, int M, int K, long strideB, long strideY)
{
  __shared__ u16 sA[2][4096];
  // modes 0-2: u16[4096] (8 KB). mode 3: float[32][130] (16640 B).
  __shared__ __align__(16) char sBr[2][(BMODE == 3) ? 16640 : 8192];
  __shared__ float scB[256], shB[256];
  __shared__ float s_sum[128], s_ssq[128];
  const int b = blockIdx.z;
  const int m0 = blockIdx.y * 128;
  const int n0 = blockIdx.x * 128;
  const int tid = threadIdx.x, lane = tid & 63, w = tid >> 6;
  const int wr = w >> 1, wc = w & 1;
  const int r15 = lane & 15, g8 = (lane >> 4) * 8;

  if (BMODE == 1 || BMODE == 2) {
    float m = sums[tid] * invCount;
    float v = ssq[tid] * invCount - m * m;
    float s = g[tid] / sqrtf(v + 1e-5f);
    scB[tid] = s;
    shB[tid] = bt[tid] - m * s;
  }
  if (STATS) { if (tid < 128) { s_sum[tid] = 0.f; s_ssq[tid] = 0.f; } }
  if (BMODE == 1 || BMODE == 2) __syncthreads();

  f4 acc[4][4];
#pragma unroll
  for (int i = 0; i < 4; ++i)
#pragma unroll
    for (int j = 0; j < 4; ++j) { f4 z = {0.f, 0.f, 0.f, 0.f}; acc[i][j] = z; }

  const int row0 = tid >> 2;            // 0..63
  const int kp0 = (tid & 3) << 3;       // 0,8,16,24
  const u16* gA0 = A + (long)(m0 + row0) * K + kp0;
  const u16* gA1 = A + (long)(m0 + row0 + 64) * K + kp0;
  const int ch0 = tid, ch1 = tid + 256;

  const u16* gB0 = (const u16*)B0v + (long)b * strideB + (long)(n0 + row0) * K + kp0;
  const u16* gB1 = gB0 + (long)64 * K;
  const u16* nB0 = (const u16*)B1v + (long)b * strideB + (long)(n0 + row0) * K + kp0;
  const u16* nB1 = nB0 + (long)64 * K;
  // mode 3: thread covers k-row kS (0..31), n-quads nS, nS+32, nS+64, nS+96
  const float* xB = (const float*)B0v + (long)b * strideB;
  const int kS = tid >> 3, nS = (tid & 7) << 2;
  const float* gX = xB + (long)kS * 8192 + n0 + nS;

  // prologue: stage k-tile 0
  ((i4v*)sA[0])[ch0] = *(const i4v*)gA0;
  ((i4v*)sA[0])[ch1] = *(const i4v*)gA1;
  if (BMODE == 0) {
    ((i4v*)sBr[0])[ch0] = *(const i4v*)gB0;
    ((i4v*)sBr[0])[ch1] = *(const i4v*)gB1;
  } else if (BMODE == 1) {
    ((i4v*)sBr[0])[ch0] = applyPack8(*(const i4v*)gB0, scB, shB, kp0);
    ((i4v*)sBr[0])[ch1] = applyPack8(*(const i4v*)gB1, scB, shB, kp0);
  } else if (BMODE == 2) {
    ((i4v*)sBr[0])[ch0] = selPack8b(*(const i4v*)gB0, *(const i4v*)nB0, scB, shB, kp0);
    ((i4v*)sBr[0])[ch1] = selPack8b(*(const i4v*)gB1, *(const i4v*)nB1, scB, shB, kp0);
  } else {
    float* sBf0 = (float*)sBr[0];
#pragma unroll
    for (int it = 0; it < 4; ++it) {
      f4 v = *(const f4*)(gX + it * 32);
      float* dst = sBf0 + kS * XSTRIDE + nS + it * 32;
      ((float2*)dst)[0] = make_float2(v[0], v[1]);
      ((float2*)dst)[1] = make_float2(v[2], v[3]);
    }
  }
  __syncthreads();

  const int KT = K >> 5;
  int cur = 0;
  for (int kk = 0; kk < KT; ++kk) {
    const bool more = (kk + 1 < KT);
    i4v ra0, ra1, rb0, rb1, rn0, rn1;
    f4 xv[4];
    if (more) {
      long ko = (long)(kk + 1) * 32;
      ra0 = *(const i4v*)(gA0 + ko); ra1 = *(const i4v*)(gA1 + ko);
      if (BMODE == 0 || BMODE == 1) {
        rb0 = *(const i4v*)(gB0 + ko); rb1 = *(const i4v*)(gB1 + ko);
      } else if (BMODE == 2) {
        rb0 = *(const i4v*)(gB0 + ko); rb1 = *(const i4v*)(gB1 + ko);
        rn0 = *(const i4v*)(nB0 + ko); rn1 = *(const i4v*)(nB1 + ko);
      } else {
        const float* gx = gX + ko * 8192;
#pragma unroll
        for (int it = 0; it < 4; ++it) xv[it] = *(const f4*)(gx + it * 32);
      }
    }
    const u16* la = sA[cur];
    s8 af[4], bfr[4];
#pragma unroll
    for (int mi = 0; mi < 4; ++mi)
      af[mi] = *(const s8*)(la + (wr * 64 + mi * 16 + r15) * 32 + g8);
    if (BMODE == 3) {
      const float* sBfc = (const float*)sBr[cur];
#pragma unroll
      for (int ni = 0; ni < 4; ++ni)
        bfr[ni] = packFrag(sBfc, g8, wc * 64 + ni * 16 + r15);
    } else {
      const u16* lb = (const u16*)sBr[cur];
#pragma unroll
      for (int ni = 0; ni < 4; ++ni)
        bfr[ni] = *(const s8*)(lb + (wc * 64 + ni * 16 + r15) * 32 + g8);
    }
#pragma unroll
    for (int mi = 0; mi < 4; ++mi)
#pragma unroll
      for (int ni = 0; ni < 4; ++ni)
        acc[mi][ni] = __builtin_amdgcn_mfma_f32_16x16x32_bf16(af[mi], bfr[ni], acc[mi][ni], 0, 0, 0);
    if (more) {
      ((i4v*)sA[cur ^ 1])[ch0] = ra0; ((i4v*)sA[cur ^ 1])[ch1] = ra1;
      if (BMODE == 0) {
        ((i4v*)sBr[cur ^ 1])[ch0] = rb0; ((i4v*)sBr[cur ^ 1])[ch1] = rb1;
      } else if (BMODE == 1) {
        const int kb = (kk + 1) * 32 + kp0;
        ((i4v*)sBr[cur ^ 1])[ch0] = applyPack8(rb0, scB, shB, kb);
        ((i4v*)sBr[cur ^ 1])[ch1] = applyPack8(rb1, scB, shB, kb);
      } else if (BMODE == 2) {
        const int kb = (kk + 1) * 32 + kp0;
        ((i4v*)sBr[cur ^ 1])[ch0] = selPack8b(rb0, rn0, scB, shB, kb);
        ((i4v*)sBr[cur ^ 1])[ch1] = selPack8b(rb1, rn1, scB, shB, kb);
      } else {
        float* sBfn = (float*)sBr[cur ^ 1];
#pragma unroll
        for (int it = 0; it < 4; ++it) {
          float* dst = sBfn + kS * XSTRIDE + nS + it * 32;
          ((float2*)dst)[0] = make_float2(xv[it][0], xv[it][1]);
          ((float2*)dst)[1] = make_float2(xv[it][2], xv[it][3]);
        }
      }
    }
    __syncthreads();
    cur ^= 1;
  }
  // epilogue: D col(n)=lane&15, row(o)=(lane>>4)*4+reg
  const int og = m0 + wr * 64 + (lane >> 4) * 4;
  const int ng = n0 + wc * 64 + r15;
  if (BF16OUT) {
    u16* Yp = (u16*)Yv + (long)b * strideY;
#pragma unroll
    for (int mi = 0; mi < 4; ++mi)
#pragma unroll
      for (int ni = 0; ni < 4; ++ni) {
        f4 a = acc[mi][ni];
        u16x4 r;
#pragma unroll
        for (int q = 0; q < 4; ++q) r[q] = f2b(a[q]);
        *(u16x4*)(Yp + (long)(ng + ni * 16) * M + og + mi * 16) = r;
      }
  } else {
    float* Yp = (float*)Yv + (long)b * strideY;
#pragma unroll
    for (int mi = 0; mi < 4; ++mi)
#pragma unroll
      for (int ni = 0; ni < 4; ++ni)
        *(f4*)(Yp + (long)(ng + ni * 16) * M + og + mi * 16) = acc[mi][ni];
  }
  if (STATS) {
#pragma unroll
    for (int mi = 0; mi < 4; ++mi)
#pragma unroll
      for (int j = 0; j < 4; ++j) {
        float s = 0.f, q = 0.f;
#pragma unroll
        for (int ni = 0; ni < 4; ++ni) {
          float v = acc[mi][ni][j];
          s += v; q = fmaf(v, v, q);
        }
#pragma unroll
        for (int off = 1; off < 16; off <<= 1) {
          s += __shfl_xor(s, off);
          q += __shfl_xor(q, off);
        }
        if ((lane & 15) == 0) {
          int lc = wr * 64 + (lane >> 4) * 4 + mi * 16 + j;
          atomicAdd(&s_sum[lc], s);
          atomicAdd(&s_ssq[lc], q);
        }
      }
    __syncthreads();
    if (tid < 128) {
      atomicAdd(&gsums[m0 + tid], s_sum[tid]);
      atomicAdd(&gssq[m0 + tid], s_ssq[tid]);
    }
  }
}

// ---------------- edgeconv gather, channel-split for L2 residency ----------------
__global__ __launch_bounds__(256, 2) void k_edge_gather(
    const u16* __restrict__ Y2, const int* __restrict__ idx,
    u16* __restrict__ Emax, u16* __restrict__ Emin,
    float* __restrict__ sums, float* __restrict__ ssq)
{
  __shared__ float s_sum[256], s_ssq[256];
  const int tid = threadIdx.x, lane = tid & 63, w = tid >> 6;
  s_sum[tid] = 0.f; s_ssq[tid] = 0.f;
  __syncthreads();
  const int half = blockIdx.y, b = blockIdx.z;
  const int ptBase = blockIdx.x * 64 + w * 16;
  const int sub = lane >> 5;
  const int chOff = half * 128 + ((lane & 31) << 2);
  f4 lsum = {0.f, 0.f, 0.f, 0.f}, lssq = {0.f, 0.f, 0.f, 0.f};
  for (int i = 0; i < 8; ++i) {
    const int pt = ptBase + i * 2 + sub;
    const long gp = (long)b * 8192 + pt;
    u16x4 cr = *(const u16x4*)(Y2 + gp * 512 + 256 + chOff);
    f4 ctr; ctr[0] = b2f(cr[0]); ctr[1] = b2f(cr[1]); ctr[2] = b2f(cr[2]); ctr[3] = b2f(cr[3]);
    const int* irow = idx + gp * 20;
    f4 vmax = {-3.0e38f, -3.0e38f, -3.0e38f, -3.0e38f};
    f4 vmin = {3.0e38f, 3.0e38f, 3.0e38f, 3.0e38f};
#pragma unroll 4
    for (int k = 0; k < 20; ++k) {
      int m = irow[k];
      u16x4 nr = *(const u16x4*)(Y2 + ((long)b * 8192 + m) * 512 + chOff);
#pragma unroll
      for (int j = 0; j < 4; ++j) {
        float y = b2f(nr[j]) + ctr[j];
        vmax[j] = fmaxf(vmax[j], y);
        vmin[j] = fminf(vmin[j], y);
        lsum[j] += y;
        lssq[j] = fmaf(y, y, lssq[j]);
      }
    }
    u16x4 eM, eN;
#pragma unroll
    for (int j = 0; j < 4; ++j) { eM[j] = f2b(vmax[j]); eN[j] = f2b(vmin[j]); }
    *(u16x4*)(Emax + gp * 256 + chOff) = eM;
    *(u16x4*)(Emin + gp * 256 + chOff) = eN;
  }
#pragma unroll
  for (int j = 0; j < 4; ++j) {
    atomicAdd(&s_sum[chOff + j], lsum[j]);
    atomicAdd(&s_ssq[chOff + j], lssq[j]);
  }
  __syncthreads();
  atomicAdd(&sums[tid], s_sum[tid]);
  atomicAdd(&ssq[tid], s_ssq[tid]);
}

// ---------------- final: apply(norm3+leaky) + 50x128 proj + bias; Y4 read ONCE ----------------
__global__ __launch_bounds__(64) void k_final(
    const float* __restrict__ Y4, const float* __restrict__ sums, const float* __restrict__ ssq,
    const float* __restrict__ g, const float* __restrict__ bt,
    const float* __restrict__ wf, const float* __restrict__ bf,
    float* __restrict__ out)
{
  __shared__ float swf[128][56];
  __shared__ float sc[128], sh[128], sb[52];
  const int lane = threadIdx.x;
  if (lane < 50) {
    const float* wrow = wf + lane * 128;
#pragma unroll 8
    for (int ch = 0; ch < 128; ++ch) swf[ch][lane] = wrow[ch];
    sb[lane] = bf[lane];
  } else if (lane < 52) {
#pragma unroll 8
    for (int ch = 0; ch < 128; ++ch) swf[ch][lane] = 0.f;
    sb[lane] = 0.f;
  }
#pragma unroll
  for (int t = 0; t < 2; ++t) {
    int ch = lane + t * 64;
    float m = sums[ch] * (1.0f / 16384.0f);
    float v = ssq[ch] * (1.0f / 16384.0f) - m * m;
    float s = g[ch] / sqrtf(v + 1e-5f);
    sc[ch] = s;
    sh[ch] = bt[ch] - m * s;
  }
  __syncthreads();
  const int b = blockIdx.y;
  const int n = blockIdx.x * 64 + lane;
  const float* hp = Y4 + ((long)b * 8192 + n) * 128;
  f4 av[13];
#pragma unroll
  for (int i = 0; i < 13; ++i) { f4 z = {0.f, 0.f, 0.f, 0.f}; av[i] = z; }
#pragma unroll 4
  for (int c4 = 0; c4 < 32; ++c4) {
    f4 hv = *(const f4*)(hp + c4 * 4);
#pragma unroll
    for (int e = 0; e < 4; ++e) {
      const int ch = c4 * 4 + e;
      float z = lky(fmaf(sc[ch], hv[e], sh[ch]));
#pragma unroll
      for (int o4 = 0; o4 < 13; ++o4) {
        f4 wv = *(const f4*)&swf[ch][o4 * 4];
#pragma unroll
        for (int q = 0; q < 4; ++q) av[o4][q] = fmaf(z, wv[q], av[o4][q]);
      }
    }
  }
  float* ob = out + (((long)b * 50) << 13) + n;
#pragma unroll
  for (int o4 = 0; o4 < 13; ++o4)
#pragma unroll
    for (int q = 0; q < 4; ++q) {
      int o = o4 * 4 + q;
      if (o < 50) ob[(long)o << 13] = av[o4][q] + sb[o];
    }
}

// ---------------- launcher ----------------
extern "C" void kernel_launch(void* const* d_in, const int* in_sizes, int n_in,
                              void* d_out, int out_size, void* d_ws, size_t ws_size,
                              hipStream_t stream)
{
  if ((long)ws_size < WS_NEED) return;
  const float* x   = (const float*)d_in[0];
  const float* p   = (const float*)d_in[1];
  const float* w1  = (const float*)d_in[2];
  const float* g1w = (const float*)d_in[4];
  const float* bt1 = (const float*)d_in[5];
  const float* we  = (const float*)d_in[6];
  const float* gew = (const float*)d_in[8];
  const float* bte = (const float*)d_in[9];
  const float* w2  = (const float*)d_in[10];
  const float* g2w = (const float*)d_in[12];
  const float* bt2 = (const float*)d_in[13];
  const float* w3  = (const float*)d_in[14];
  const float* g3w = (const float*)d_in[16];
  const float* bt3 = (const float*)d_in[17];
  const float* wf  = (const float*)d_in[18];
  const float* bfi = (const float*)d_in[19];

  char* ws = (char*)d_ws;
  u16* w1b   = (u16*)(ws + OFF_W1B);
  u16* weABb = (u16*)(ws + OFF_WEAB);
  u16* w2b   = (u16*)(ws + OFF_W2B);
  u16* w3b   = (u16*)(ws + OFF_W3B);
  int* idxb  = (int*)(ws + OFF_IDX);
  f4*  pqg   = (f4*)(ws + OFF_PQ);
  u16*   Y1b  = (u16*)(ws + OFF_Y1);
  u16*   Y2b  = (u16*)(ws + OFF_Y2);
  u16*   EMAX = (u16*)(ws + OFF_EMAX);
  u16*   EMIN = (u16*)(ws + OFF_EMIN);
  u16*   Y3b  = (u16*)(ws + OFF_Y3);
  float* Y4   = (float*)(ws + OFF_Y4);
  float* st0 = (float*)(ws + OFF_STATS);
  float* st1 = (float*)(ws + OFF_STATS + 4096);
  float* st2 = (float*)(ws + OFF_STATS + 8192);
  float* st3 = (float*)(ws + OFF_STATS + 12288);

  hipMemsetAsync(ws + OFF_STATS, 0, 16384, stream);
  k_convw<<<2176, 256, 0, stream>>>(w1, we, w2, w3, p, w1b, weABb, w2b, w3b, pqg);
  k_knn<<<1024, 256, 0, stream>>>(pqg, idxb);

  // stage 1: smlp1d(x, w1) -> Y1 bf16 raw + stats st0; B staged straight from x (fused transpose)
  k_gemm<3, 1, 1><<<dim3(64, 2, 2), 256, 0, stream>>>(
      w1b, x, nullptr, nullptr, nullptr, nullptr, nullptr, 0.f,
      st0, st0 + 256, Y1b, 256, 1216, (long)1216 * 8192, (long)8192 * 256);

  // edge GEMM: B = apply1(Y1 bf16) fused -> Y2 bf16 [Anb | Cy]
  k_gemm<1, 0, 1><<<dim3(64, 4, 2), 256, 0, stream>>>(
      weABb, Y1b, nullptr, st0, st0 + 256, g1w, bt1, 1.0f / 16384.0f,
      nullptr, nullptr, Y2b, 512, 256, (long)8192 * 256, (long)8192 * 512);

  // gather: channel-split, bf16 E out, stats st1
  k_edge_gather<<<dim3(128, 2, 2), 256, 0, stream>>>(Y2b, idxb, EMAX, EMIN, st1, st1 + 256);

  // stage 2: B = sel(EMAX,EMIN) bf16 fused -> Y3 bf16 raw + stats st2
  k_gemm<2, 1, 1><<<dim3(64, 2, 2), 256, 0, stream>>>(
      w2b, EMAX, EMIN, st1, st1 + 256, gew, bte, 1.0f / 327680.0f,
      st2, st2 + 256, Y3b, 256, 256, (long)8192 * 256, (long)8192 * 256);

  // stage 3: B = apply2(Y3 bf16) fused -> Y4 f32 + stats st3
  k_gemm<1, 1, 0><<<dim3(64, 1, 2), 256, 0, stream>>>(
      w3b, Y3b, nullptr, st2, st2 + 256, g2w, bt2, 1.0f / 16384.0f,
      st3, st3 + 256, Y4, 128, 256, (long)8192 * 256, (long)8192 * 128);

  // final: apply3 fused + projection (Y4 read once)
  k_final<<<dim3(128, 2), 64, 0, stream>>>(Y4, st3, st3 + 256, g3w, bt3, wf, bfi, (float*)d_out);
}